// Round 2
// baseline (899.663 us; speedup 1.0000x reference)
//
#include <hip/hip_runtime.h>
#include <hip/hip_bf16.h>

typedef __hip_bfloat16 bf16;

#define S_LEN 4096
#define Hn 8
#define DHn 64
#define Lc 128
#define HL 1024

__device__ __forceinline__ float b2f(bf16 x) { return __bfloat162float(x); }

// ---------------- dtype probe: flag=1 if inputs are f32, 0 if bf16 ----------------
__global__ void probe_dtype(const void* __restrict__ X, int* __restrict__ flag)
{
    const int t = threadIdx.x;
    const bf16* xb = (const bf16*)X;
    int bad = 0;
    for (int i = t; i < 4096; i += 64) {
        const float f = b2f(xb[i]);
        if (f != f || fabsf(f) > 1e4f) bad = 1;
    }
    const unsigned long long any = __ballot(bad);
    if (t == 0) *flag = (any != 0ull) ? 1 : 0;
}

// ---------------- GEMM from raw inputs: out = A(MxK)@W(KxN) + bias ----------------
// mode 0: f32 row-major out; mode 1: f32 (B,H,S,DH) out with scale
__global__ __launch_bounds__(256) void gemm_in(const void* __restrict__ A,
    const void* __restrict__ W, const void* __restrict__ bias, float* __restrict__ outp,
    int M, int N, int K, int mode, float scale, const int* __restrict__ flag)
{
    __shared__ float As[16][68];
    __shared__ float Bs[16][68];
    const int t = threadIdx.x;
    const int tx = t & 15, ty = t >> 4;
    const int n0 = blockIdx.x * 64, m0 = blockIdx.y * 64;
    const bool f32in = (*flag) != 0;
    float c[4][4] = {};
    for (int kk = 0; kk < K; kk += 16) {
        if (f32in) {
            const float* Af = (const float*)A;
            const float* Wf = (const float*)W;
#pragma unroll
            for (int i = 0; i < 4; ++i) {
                const int m = (t >> 4) + i * 16;
                As[t & 15][m] = Af[(size_t)(m0 + m) * K + kk + (t & 15)];
            }
#pragma unroll
            for (int i = 0; i < 4; ++i) {
                const int k = (t >> 6) + i * 4;
                Bs[k][t & 63] = Wf[(size_t)(kk + k) * N + n0 + (t & 63)];
            }
        } else {
            const bf16* Ab = (const bf16*)A;
            const bf16* Wb = (const bf16*)W;
#pragma unroll
            for (int i = 0; i < 4; ++i) {
                const int m = (t >> 4) + i * 16;
                As[t & 15][m] = b2f(Ab[(size_t)(m0 + m) * K + kk + (t & 15)]);
            }
#pragma unroll
            for (int i = 0; i < 4; ++i) {
                const int k = (t >> 6) + i * 4;
                Bs[k][t & 63] = b2f(Wb[(size_t)(kk + k) * N + n0 + (t & 63)]);
            }
        }
        __syncthreads();
#pragma unroll
        for (int k = 0; k < 16; ++k) {
            const float4 a4 = *(const float4*)&As[k][ty * 4];
            const float4 b4 = *(const float4*)&Bs[k][tx * 4];
            const float ar[4] = {a4.x, a4.y, a4.z, a4.w};
            const float br[4] = {b4.x, b4.y, b4.z, b4.w};
#pragma unroll
            for (int ii = 0; ii < 4; ++ii)
#pragma unroll
                for (int jj = 0; jj < 4; ++jj)
                    c[ii][jj] = fmaf(ar[ii], br[jj], c[ii][jj]);
        }
        __syncthreads();
    }
#pragma unroll
    for (int ii = 0; ii < 4; ++ii) {
        const int m = m0 + ty * 4 + ii;
#pragma unroll
        for (int jj = 0; jj < 4; ++jj) {
            const int n = n0 + tx * 4 + jj;
            float bv;
            if (f32in) bv = ((const float*)bias)[n];
            else       bv = b2f(((const bf16*)bias)[n]);
            float v = c[ii][jj] + bv;
            if (mode == 0) {
                outp[(size_t)m * N + n] = v;
            } else {
                v *= scale;
                const int bb = m >> 12, s = m & 4095, hh = n >> 6, d = n & 63;
                outp[((size_t)(bb * Hn + hh) * S_LEN + s) * DHn + d] = v;
            }
        }
    }
}

// ---------------- final GEMM: A f32 scratch, W/bias raw, out per flag ----------------
__global__ __launch_bounds__(256) void gemm_out(const float* __restrict__ A,
    const void* __restrict__ W, const void* __restrict__ bias, void* __restrict__ outp,
    int M, int N, int K, const int* __restrict__ flag)
{
    __shared__ float As[16][68];
    __shared__ float Bs[16][68];
    const int t = threadIdx.x;
    const int tx = t & 15, ty = t >> 4;
    const int n0 = blockIdx.x * 64, m0 = blockIdx.y * 64;
    const bool f32in = (*flag) != 0;
    float c[4][4] = {};
    for (int kk = 0; kk < K; kk += 16) {
#pragma unroll
        for (int i = 0; i < 4; ++i) {
            const int m = (t >> 4) + i * 16;
            As[t & 15][m] = A[(size_t)(m0 + m) * K + kk + (t & 15)];
        }
        if (f32in) {
            const float* Wf = (const float*)W;
#pragma unroll
            for (int i = 0; i < 4; ++i) {
                const int k = (t >> 6) + i * 4;
                Bs[k][t & 63] = Wf[(size_t)(kk + k) * N + n0 + (t & 63)];
            }
        } else {
            const bf16* Wb = (const bf16*)W;
#pragma unroll
            for (int i = 0; i < 4; ++i) {
                const int k = (t >> 6) + i * 4;
                Bs[k][t & 63] = b2f(Wb[(size_t)(kk + k) * N + n0 + (t & 63)]);
            }
        }
        __syncthreads();
#pragma unroll
        for (int k = 0; k < 16; ++k) {
            const float4 a4 = *(const float4*)&As[k][ty * 4];
            const float4 b4 = *(const float4*)&Bs[k][tx * 4];
            const float ar[4] = {a4.x, a4.y, a4.z, a4.w};
            const float br[4] = {b4.x, b4.y, b4.z, b4.w};
#pragma unroll
            for (int ii = 0; ii < 4; ++ii)
#pragma unroll
                for (int jj = 0; jj < 4; ++jj)
                    c[ii][jj] = fmaf(ar[ii], br[jj], c[ii][jj]);
        }
        __syncthreads();
    }
#pragma unroll
    for (int ii = 0; ii < 4; ++ii) {
        const int m = m0 + ty * 4 + ii;
#pragma unroll
        for (int jj = 0; jj < 4; ++jj) {
            const int n = n0 + tx * 4 + jj;
            float bv;
            if (f32in) bv = ((const float*)bias)[n];
            else       bv = b2f(((const bf16*)bias)[n]);
            const float v = c[ii][jj] + bv;
            if (f32in) ((float*)outp)[(size_t)m * N + n] = v;
            else       ((bf16*)outp)[(size_t)m * N + n] = __float2bfloat16(v);
        }
    }
}

// ---------------- LayerNorm over 512 per row, write (B,H,S,DH) ----------------
__global__ __launch_bounds__(256) void ln_rows(const float* __restrict__ src,
    const void* __restrict__ g, const void* __restrict__ beta, float* __restrict__ dst,
    const int* __restrict__ flag)
{
    const int row = blockIdx.x, t = threadIdx.x;
    const bool f32in = (*flag) != 0;
    const float x0 = src[(size_t)row * 512 + t];
    const float x1 = src[(size_t)row * 512 + t + 256];
    float s = x0 + x1, ss = x0 * x0 + x1 * x1;
#pragma unroll
    for (int off = 32; off >= 1; off >>= 1) { s += __shfl_xor(s, off); ss += __shfl_xor(ss, off); }
    __shared__ float red[2][4];
    if ((t & 63) == 0) { red[0][t >> 6] = s; red[1][t >> 6] = ss; }
    __syncthreads();
    s = red[0][0] + red[0][1] + red[0][2] + red[0][3];
    ss = red[1][0] + red[1][1] + red[1][2] + red[1][3];
    const float mu = s * (1.f / 512.f);
    const float r = rsqrtf(ss * (1.f / 512.f) - mu * mu + 1e-5f);
    const int bb = row >> 12, sidx = row & 4095;
#pragma unroll
    for (int half = 0; half < 2; ++half) {
        const int cidx = t + half * 256;
        const float x = half ? x1 : x0;
        float gv, bv;
        if (f32in) { gv = ((const float*)g)[cidx]; bv = ((const float*)beta)[cidx]; }
        else       { gv = b2f(((const bf16*)g)[cidx]); bv = b2f(((const bf16*)beta)[cidx]); }
        const int hh = cidx >> 6, d = cidx & 63;
        dst[((size_t)(bb * Hn + hh) * S_LEN + sidx) * DHn + d] = (x - mu) * r * gv + bv;
    }
}

// ---------------- column softmax over S: partial online max/sum ----------------
__global__ __launch_bounds__(256) void colsm_partial(const float* __restrict__ Dlog,
    float* __restrict__ pM, float* __restrict__ pZ)
{
    const int t = threadIdx.x;
    const int cidx = blockIdx.x * 256 + t;
    const int chunk = blockIdx.y, b = blockIdx.z;
    const int s0 = chunk * 128;
    float m = -1e30f, z = 0.f;
#pragma unroll 4
    for (int s = 0; s < 128; ++s) {
        const float x = Dlog[((size_t)b * S_LEN + s0 + s) * HL + cidx];
        const float mn = fmaxf(m, x);
        z = z * __expf(m - mn) + __expf(x - mn);
        m = mn;
    }
    pM[((size_t)b * HL + cidx) * 32 + chunk] = m;
    pZ[((size_t)b * HL + cidx) * 32 + chunk] = z;
}

__global__ __launch_bounds__(256) void colsm_combine(const float* __restrict__ pM,
    const float* __restrict__ pZ, float* __restrict__ colM, float* __restrict__ colInvZ)
{
    const int idx = blockIdx.x * 256 + threadIdx.x; // 0 .. B*HL-1
    float M = -1e30f;
#pragma unroll
    for (int i = 0; i < 32; ++i) M = fmaxf(M, pM[(size_t)idx * 32 + i]);
    float Z = 0.f;
#pragma unroll
    for (int i = 0; i < 32; ++i) Z += pZ[(size_t)idx * 32 + i] * __expf(pM[(size_t)idx * 32 + i] - M);
    colM[idx] = M;
    colInvZ[idx] = 1.f / Z;
}

__global__ __launch_bounds__(256) void zero2(float* __restrict__ p)
{
    *(float4*)&p[((size_t)blockIdx.x * 256 + threadIdx.x) * 4] = make_float4(0.f, 0.f, 0.f, 0.f);
}

// ---------------- Kc/Vc landmark einsum with folded softmax normalization ----------------
__global__ __launch_bounds__(256) void kcvc(const float* __restrict__ Dlog,
    const float* __restrict__ colM, const float* __restrict__ colInvZ,
    const float* __restrict__ Kl, const float* __restrict__ Vl,
    float* __restrict__ KcRaw, float* __restrict__ VcRaw)
{
    const int t = threadIdx.x;
    const int chunk = blockIdx.x, h = blockIdx.y, b = blockIdx.z;
    const int s0 = chunk * 256;
    __shared__ float Mh[128], iZ[128];
    __shared__ float aa[8][128];
    __shared__ float kk[8][64], vv[8][64];
    if (t < 128) {
        Mh[t] = colM[b * HL + h * Lc + t];
        iZ[t] = colInvZ[b * HL + h * Lc + t];
    }
    __syncthreads();
    const int lg = t >> 3, dg = t & 7;
    const int l0 = lg * 4, d0 = dg * 8;
    float aK[4][8] = {}, aV[4][8] = {};
    for (int so = 0; so < 32; ++so) {
        const int sbase = s0 + so * 8;
#pragma unroll
        for (int i = 0; i < 4; ++i) {
            const int e = i * 256 + t;
            const int si = e >> 7, li = e & 127;
            aa[si][li] = __expf(Dlog[((size_t)b * S_LEN + sbase + si) * HL + h * Lc + li] - Mh[li]) * iZ[li];
        }
#pragma unroll
        for (int i = 0; i < 2; ++i) {
            const int e = i * 256 + t;
            const int si = e >> 6, d = e & 63;
            kk[si][d] = Kl[((size_t)(b * Hn + h) * S_LEN + sbase + si) * DHn + d];
            vv[si][d] = Vl[((size_t)(b * Hn + h) * S_LEN + sbase + si) * DHn + d];
        }
        __syncthreads();
#pragma unroll
        for (int si = 0; si < 8; ++si) {
            const float4 a4 = *(const float4*)&aa[si][l0];
            const float a[4] = {a4.x, a4.y, a4.z, a4.w};
            const float4 k0 = *(const float4*)&kk[si][d0];
            const float4 k1 = *(const float4*)&kk[si][d0 + 4];
            const float4 v0 = *(const float4*)&vv[si][d0];
            const float4 v1 = *(const float4*)&vv[si][d0 + 4];
            const float k8[8] = {k0.x, k0.y, k0.z, k0.w, k1.x, k1.y, k1.z, k1.w};
            const float v8[8] = {v0.x, v0.y, v0.z, v0.w, v1.x, v1.y, v1.z, v1.w};
#pragma unroll
            for (int i = 0; i < 4; ++i)
#pragma unroll
                for (int j = 0; j < 8; ++j) {
                    aK[i][j] = fmaf(a[i], k8[j], aK[i][j]);
                    aV[i][j] = fmaf(a[i], v8[j], aV[i][j]);
                }
        }
        __syncthreads();
    }
#pragma unroll
    for (int i = 0; i < 4; ++i)
#pragma unroll
        for (int j = 0; j < 8; ++j) {
            const size_t o = ((size_t)(b * Hn + h) * Lc + l0 + i) * DHn + d0 + j;
            atomicAdd(&KcRaw[o], aK[i][j]);
            atomicAdd(&VcRaw[o], aV[i][j]);
        }
}

// ---------------- LN over heads for Kc/Vc: per (b,l), 512 = H*DH elems ----------------
__global__ __launch_bounds__(256) void ln_s(const float* __restrict__ KcRaw,
    const float* __restrict__ VcRaw, const void* __restrict__ g, const void* __restrict__ beta,
    float* __restrict__ KcLn, float* __restrict__ VcLn, const int* __restrict__ flag)
{
    const int l = blockIdx.x, b = blockIdx.y, t = threadIdx.x;
    const bool f32in = (*flag) != 0;
    __shared__ float red[2][4];
    for (int p = 0; p < 2; ++p) {
        const float* src = p ? VcRaw : KcRaw;
        float* dst = p ? VcLn : KcLn;
        const int c0 = t, c1 = t + 256;
        const size_t i0 = ((size_t)(b * Hn + (c0 >> 6)) * Lc + l) * DHn + (c0 & 63);
        const size_t i1 = ((size_t)(b * Hn + (c1 >> 6)) * Lc + l) * DHn + (c1 & 63);
        const float x0 = src[i0], x1 = src[i1];
        float s = x0 + x1, ss = x0 * x0 + x1 * x1;
#pragma unroll
        for (int off = 32; off >= 1; off >>= 1) { s += __shfl_xor(s, off); ss += __shfl_xor(ss, off); }
        if ((t & 63) == 0) { red[0][t >> 6] = s; red[1][t >> 6] = ss; }
        __syncthreads();
        s = red[0][0] + red[0][1] + red[0][2] + red[0][3];
        ss = red[1][0] + red[1][1] + red[1][2] + red[1][3];
        const float mu = s * (1.f / 512.f);
        const float r = rsqrtf(ss * (1.f / 512.f) - mu * mu + 1e-5f);
        float g0, b0, g1, b1;
        if (f32in) {
            g0 = ((const float*)g)[c0]; b0 = ((const float*)beta)[c0];
            g1 = ((const float*)g)[c1]; b1 = ((const float*)beta)[c1];
        } else {
            g0 = b2f(((const bf16*)g)[c0]); b0 = b2f(((const bf16*)beta)[c0]);
            g1 = b2f(((const bf16*)g)[c1]); b1 = b2f(((const bf16*)beta)[c1]);
        }
        dst[i0] = (x0 - mu) * r * g0 + b0;
        dst[i1] = (x1 - mu) * r * g1 + b1;
        __syncthreads();
    }
}

// ---------------- fused attention: compressed (L) + window (WIN) keys ----------------
__global__ __launch_bounds__(256) void attn(const float* __restrict__ Qs,
    const float* __restrict__ Kl, const float* __restrict__ Vl,
    const float* __restrict__ KcLn, const float* __restrict__ VcLn,
    const int* __restrict__ mask, float* __restrict__ C)
{
    const int t = threadIdx.x;
    const int qt = blockIdx.x, h = blockIdx.y, b = blockIdx.z;
    const int q0 = qt * 64, gg = qt >> 1;
    __shared__ float Qt[64][68];   // [d][q]
    __shared__ float KV[64][68];   // K phase: [d][j]; V phase: [j][d]
    __shared__ float Sc[64][68];   // [q][j]
    __shared__ float vbias[64];
    const size_t bh = (size_t)(b * Hn + h);

    // stage Q transposed
#pragma unroll
    for (int i = 0; i < 4; ++i) {
        const int e = i * 1024 + t * 4;
        const int q = e >> 6, d0 = e & 63;
        const float4 v = *(const float4*)&Qs[(bh * S_LEN + q0 + q) * DHn + d0];
        Qt[d0 + 0][q] = v.x; Qt[d0 + 1][q] = v.y; Qt[d0 + 2][q] = v.z; Qt[d0 + 3][q] = v.w;
    }
    const int qg = t & 15, jg = t >> 4;
    const int qb = t >> 2, part = t & 3;
    float m = -1e30f, l = 0.f;
    float acc[16];
#pragma unroll
    for (int i = 0; i < 16; ++i) acc[i] = 0.f;

    for (int cc = 0; cc < 6; ++cc) {
        __syncthreads();  // previous PV done
        if (t < 64) {
            float vb = 0.f;
            if (cc >= 2) {
                const int sk = gg * 128 - 64 + (cc - 2) * 64 + t;
                if (sk < 0 || sk >= S_LEN || mask[b * S_LEN + sk] == 0) vb = -1e30f;
            }
            vbias[t] = vb;
        }
        // stage K chunk transposed [d][j]
#pragma unroll
        for (int i = 0; i < 4; ++i) {
            const int e = i * 1024 + t * 4;
            const int j = e >> 6, d0 = e & 63;
            float4 kv;
            if (cc < 2) {
                kv = *(const float4*)&KcLn[(bh * Lc + cc * 64 + j) * DHn + d0];
            } else {
                const int sk = gg * 128 - 64 + (cc - 2) * 64 + j;
                if (sk >= 0 && sk < S_LEN) kv = *(const float4*)&Kl[(bh * S_LEN + sk) * DHn + d0];
                else kv = make_float4(0.f, 0.f, 0.f, 0.f);
            }
            KV[d0 + 0][j] = kv.x; KV[d0 + 1][j] = kv.y; KV[d0 + 2][j] = kv.z; KV[d0 + 3][j] = kv.w;
        }
        __syncthreads();
        // scores: 4q x 4j per thread
        float c4[4][4] = {};
#pragma unroll
        for (int d = 0; d < 64; ++d) {
            const float4 a4 = *(const float4*)&Qt[d][qg * 4];
            const float4 b4 = *(const float4*)&KV[d][jg * 4];
            const float ar[4] = {a4.x, a4.y, a4.z, a4.w};
            const float br[4] = {b4.x, b4.y, b4.z, b4.w};
#pragma unroll
            for (int ii = 0; ii < 4; ++ii)
#pragma unroll
                for (int jj = 0; jj < 4; ++jj)
                    c4[ii][jj] = fmaf(ar[ii], br[jj], c4[ii][jj]);
        }
#pragma unroll
        for (int ii = 0; ii < 4; ++ii) {
            float4 s4;
            s4.x = c4[ii][0] + vbias[jg * 4 + 0];
            s4.y = c4[ii][1] + vbias[jg * 4 + 1];
            s4.z = c4[ii][2] + vbias[jg * 4 + 2];
            s4.w = c4[ii][3] + vbias[jg * 4 + 3];
            *(float4*)&Sc[qg * 4 + ii][jg * 4] = s4;
        }
        __syncthreads();  // scores visible; KV free for V
        // stage V chunk [j][d]
#pragma unroll
        for (int i = 0; i < 4; ++i) {
            const int e = i * 1024 + t * 4;
            const int j = e >> 6, d0 = e & 63;
            float4 vv4;
            if (cc < 2) {
                vv4 = *(const float4*)&VcLn[(bh * Lc + cc * 64 + j) * DHn + d0];
            } else {
                const int sk = gg * 128 - 64 + (cc - 2) * 64 + j;
                if (sk >= 0 && sk < S_LEN) vv4 = *(const float4*)&Vl[(bh * S_LEN + sk) * DHn + d0];
                else vv4 = make_float4(0.f, 0.f, 0.f, 0.f);
            }
            *(float4*)&KV[j][d0] = vv4;
        }
        // online-softmax update (row qb owned by 4 consecutive lanes of one wave)
        float p[16];
        {
            const float4 r0 = *(const float4*)&Sc[qb][part * 16 + 0];
            const float4 r1 = *(const float4*)&Sc[qb][part * 16 + 4];
            const float4 r2 = *(const float4*)&Sc[qb][part * 16 + 8];
            const float4 r3 = *(const float4*)&Sc[qb][part * 16 + 12];
            p[0] = r0.x; p[1] = r0.y; p[2] = r0.z; p[3] = r0.w;
            p[4] = r1.x; p[5] = r1.y; p[6] = r1.z; p[7] = r1.w;
            p[8] = r2.x; p[9] = r2.y; p[10] = r2.z; p[11] = r2.w;
            p[12] = r3.x; p[13] = r3.y; p[14] = r3.z; p[15] = r3.w;
        }
        float mloc = p[0];
#pragma unroll
        for (int i = 1; i < 16; ++i) mloc = fmaxf(mloc, p[i]);
        mloc = fmaxf(mloc, __shfl_xor(mloc, 1));
        mloc = fmaxf(mloc, __shfl_xor(mloc, 2));
        const float mnew = fmaxf(m, mloc);
        const float alpha = __expf(m - mnew);
        float sum = 0.f;
#pragma unroll
        for (int i = 0; i < 16; ++i) { p[i] = __expf(p[i] - mnew); sum += p[i]; }
        {
            float4 w0 = {p[0], p[1], p[2], p[3]};
            float4 w1 = {p[4], p[5], p[6], p[7]};
            float4 w2 = {p[8], p[9], p[10], p[11]};
            float4 w3 = {p[12], p[13], p[14], p[15]};
            *(float4*)&Sc[qb][part * 16 + 0] = w0;
            *(float4*)&Sc[qb][part * 16 + 4] = w1;
            *(float4*)&Sc[qb][part * 16 + 8] = w2;
            *(float4*)&Sc[qb][part * 16 + 12] = w3;
        }
        sum += __shfl_xor(sum, 1);
        sum += __shfl_xor(sum, 2);
        l = l * alpha + sum;
        m = mnew;
#pragma unroll
        for (int i = 0; i < 16; ++i) acc[i] *= alpha;
        __syncthreads();  // V staged + exp'd P visible
        // PV: thread owns (q=qb, d = part*16..part*16+15)
#pragma unroll 8
        for (int j = 0; j < 64; ++j) {
            const float pj = Sc[qb][j];
            const float4 v0 = *(const float4*)&KV[j][part * 16 + 0];
            const float4 v1 = *(const float4*)&KV[j][part * 16 + 4];
            const float4 v2 = *(const float4*)&KV[j][part * 16 + 8];
            const float4 v3 = *(const float4*)&KV[j][part * 16 + 12];
            acc[0] = fmaf(pj, v0.x, acc[0]);  acc[1] = fmaf(pj, v0.y, acc[1]);
            acc[2] = fmaf(pj, v0.z, acc[2]);  acc[3] = fmaf(pj, v0.w, acc[3]);
            acc[4] = fmaf(pj, v1.x, acc[4]);  acc[5] = fmaf(pj, v1.y, acc[5]);
            acc[6] = fmaf(pj, v1.z, acc[6]);  acc[7] = fmaf(pj, v1.w, acc[7]);
            acc[8] = fmaf(pj, v2.x, acc[8]);  acc[9] = fmaf(pj, v2.y, acc[9]);
            acc[10] = fmaf(pj, v2.z, acc[10]); acc[11] = fmaf(pj, v2.w, acc[11]);
            acc[12] = fmaf(pj, v3.x, acc[12]); acc[13] = fmaf(pj, v3.y, acc[13]);
            acc[14] = fmaf(pj, v3.z, acc[14]); acc[15] = fmaf(pj, v3.w, acc[15]);
        }
    }
    const int q = q0 + qb;
    const float rl = (mask[b * S_LEN + q] == 0) ? 0.f : (1.f / l);
    const size_t ob = ((size_t)b * S_LEN + q) * 512 + h * 64 + part * 16;
#pragma unroll
    for (int i = 0; i < 16; ++i) C[ob + i] = acc[i] * rl;
}

extern "C" void kernel_launch(void* const* d_in, const int* in_sizes, int n_in,
                              void* d_out, int out_size, void* d_ws, size_t ws_size,
                              hipStream_t stream) {
    (void)in_sizes; (void)n_in; (void)out_size; (void)ws_size;
    const void* X    = d_in[0];
    const int*  mask = (const int*)d_in[1];
    const void* Wq = d_in[2];  const void* bq = d_in[3];
    const void* Wk = d_in[4];  const void* bk = d_in[5];
    const void* Wv = d_in[6];  const void* bv = d_in[7];
    const void* Wo = d_in[8];  const void* bo = d_in[9];
    const void* lnlg = d_in[10]; const void* lnlb = d_in[11];
    const void* lnsg = d_in[12]; const void* lnsb = d_in[13];
    const void* Wd = d_in[14]; const void* bd = d_in[15];

    float* ws = (float*)d_ws;
    float* Qs      = ws;                  // 4,194,304  (B,H,S,DH) f32, pre-scaled
    float* Kl      = Qs + 4194304;        // 4,194,304
    float* Vl      = Kl + 4194304;        // 4,194,304
    float* tmp     = Vl + 4194304;        // 4,194,304  (K/V pre-LN f32; later C f32)
    float* Dlog    = tmp + 4194304;       // 8,388,608
    float* pM      = Dlog + 8388608;      // 65,536
    float* pZ      = pM + 65536;          // 65,536
    float* colM    = pZ + 65536;          // 2,048
    float* colInvZ = colM + 2048;         // 2,048
    float* KcRaw   = colInvZ + 2048;      // 131,072
    float* VcRaw   = KcRaw + 131072;      // 131,072 (contiguous after KcRaw)
    float* KcLn    = VcRaw + 131072;      // 131,072
    float* VcLn    = KcLn + 131072;       // 131,072
    int*   flag    = (int*)(VcLn + 131072); // dtype flag

    const dim3 blk(256);
    probe_dtype<<<1, 64, 0, stream>>>(X, flag);
    // projections
    gemm_in<<<dim3(8, 128), blk, 0, stream>>>(X, Wq, bq, Qs, 8192, 512, 512, 1, 0.125f, flag);
    gemm_in<<<dim3(8, 128), blk, 0, stream>>>(X, Wk, bk, tmp, 8192, 512, 512, 0, 1.f, flag);
    ln_rows<<<8192, blk, 0, stream>>>(tmp, lnlg, lnlb, Kl, flag);
    gemm_in<<<dim3(8, 128), blk, 0, stream>>>(X, Wv, bv, tmp, 8192, 512, 512, 0, 1.f, flag);
    ln_rows<<<8192, blk, 0, stream>>>(tmp, lnlg, lnlb, Vl, flag);
    gemm_in<<<dim3(16, 128), blk, 0, stream>>>(X, Wd, bd, Dlog, 8192, 1024, 512, 0, 1.f, flag);
    // column softmax (over S) for dynamic projection
    colsm_partial<<<dim3(4, 32, 2), blk, 0, stream>>>(Dlog, pM, pZ);
    colsm_combine<<<8, blk, 0, stream>>>(pM, pZ, colM, colInvZ);
    // landmark Kc/Vc
    zero2<<<256, blk, 0, stream>>>(KcRaw);  // zeroes KcRaw+VcRaw (contiguous 262144 floats)
    kcvc<<<dim3(16, 8, 2), blk, 0, stream>>>(Dlog, colM, colInvZ, Kl, Vl, KcRaw, VcRaw);
    ln_s<<<dim3(128, 2), blk, 0, stream>>>(KcRaw, VcRaw, lnsg, lnsb, KcLn, VcLn, flag);
    // fused attention -> C (f32, in tmp)
    attn<<<dim3(64, 8, 2), blk, 0, stream>>>(Qs, Kl, Vl, KcLn, VcLn, mask, tmp);
    // output projection
    gemm_out<<<dim3(8, 128), blk, 0, stream>>>(tmp, Wo, bo, d_out, 8192, 512, 512, flag);
}

// Round 3
// 392.189 us; speedup vs baseline: 2.2940x; 2.2940x over previous
//
#include <hip/hip_runtime.h>
#include <hip/hip_bf16.h>

#define S_LEN 4096
#define Hn 8
#define DHn 64
#define Lc 128
#define HL 1024
#define KD 512   // inner dim of all GEMMs

typedef __attribute__((ext_vector_type(8))) short bshort8;
typedef __attribute__((ext_vector_type(4))) float f32x4;

__device__ __forceinline__ short f2bs(float f) {
    union { float f; unsigned u; } x; x.f = f;
    const unsigned r = x.u + 0x7FFFu + ((x.u >> 16) & 1u);
    return (short)(r >> 16);
}
__device__ __forceinline__ float bs2f(short s) {
    union { unsigned u; float f; } x; x.u = ((unsigned)(unsigned short)s) << 16;
    return x.f;
}

// async global(bf16 bits as short) -> LDS, 16B per lane
__device__ __forceinline__ void gl16(const short* g, short* l) {
    __builtin_amdgcn_global_load_lds((const __attribute__((address_space(1))) void*)g,
                                     (__attribute__((address_space(3))) void*)l, 16, 0, 0);
}

// ---------------- f32 -> bf16 convert (8 elems/thread) ----------------
__global__ __launch_bounds__(256) void cvt_bf(const float* __restrict__ src, short* __restrict__ dst)
{
    const int i = (blockIdx.x * 256 + threadIdx.x) * 8;
    const float4 a = *(const float4*)&src[i];
    const float4 b = *(const float4*)&src[i + 4];
    bshort8 o;
    o[0] = f2bs(a.x); o[1] = f2bs(a.y); o[2] = f2bs(a.z); o[3] = f2bs(a.w);
    o[4] = f2bs(b.x); o[5] = f2bs(b.y); o[6] = f2bs(b.z); o[7] = f2bs(b.w);
    *(bshort8*)&dst[i] = o;
}

// ---------------- transpose + convert: W (KD x N f32) -> out (N x KD bf16) ----------------
__global__ __launch_bounds__(256) void wtrans(const float* __restrict__ W, short* __restrict__ out, int N)
{
    __shared__ float Tl[32][33];
    const int tx = threadIdx.x, ty = threadIdx.y;
    const int n0 = blockIdx.x * 32, k0 = blockIdx.y * 32;
#pragma unroll
    for (int i = ty; i < 32; i += 8)
        Tl[i][tx] = W[(size_t)(k0 + i) * N + n0 + tx];
    __syncthreads();
#pragma unroll
    for (int i = ty; i < 32; i += 8)
        out[(size_t)(n0 + i) * KD + k0 + tx] = f2bs(Tl[tx][i]);
}

// ---------------- fused projection GEMM (MFMA): X(8192x512) @ [Wq|Wk|Wv|Wd] ----------------
// WT: concatenated transposed weights, rows: [0,512)=Q [512,1024)=K [1024,1536)=V [1536,2560)=D
__global__ __launch_bounds__(256) void gemm_proj(const short* __restrict__ Xbf,
    const short* __restrict__ WT,
    const float* __restrict__ bq, const float* __restrict__ bk,
    const float* __restrict__ bv, const float* __restrict__ bd,
    float* __restrict__ Qs, float* __restrict__ Kb, float* __restrict__ Vb,
    short* __restrict__ DlogBf)
{
    __shared__ short A_s[128 * 32];
    __shared__ short B_s[128 * 32];
    const int t = threadIdx.x;
    const int n0 = blockIdx.x * 128, m0 = blockIdx.y * 128;
    const int lane = t & 63, wave = t >> 6;
    const int wm = wave >> 1, wn = wave & 1;
    const int quad = lane >> 4, r15 = lane & 15;
    const int eOff = t * 8;                 // staging elem offset, round 0
    const int am = eOff >> 5, ak = eOff & 31;
    f32x4 acc[4][4];
#pragma unroll
    for (int i = 0; i < 4; ++i)
#pragma unroll
        for (int j = 0; j < 4; ++j) acc[i][j] = (f32x4){0.f, 0.f, 0.f, 0.f};

    for (int kk = 0; kk < KD; kk += 32) {
        gl16(&Xbf[(size_t)(m0 + am) * KD + kk + ak],      &A_s[eOff]);
        gl16(&Xbf[(size_t)(m0 + 64 + am) * KD + kk + ak], &A_s[2048 + eOff]);
        gl16(&WT[(size_t)(n0 + am) * KD + kk + ak],       &B_s[eOff]);
        gl16(&WT[(size_t)(n0 + 64 + am) * KD + kk + ak],  &B_s[2048 + eOff]);
        __syncthreads();
        bshort8 af[4], bfr[4];
#pragma unroll
        for (int i = 0; i < 4; ++i) af[i]  = *(const bshort8*)&A_s[(wm * 64 + i * 16 + r15) * 32 + quad * 8];
#pragma unroll
        for (int j = 0; j < 4; ++j) bfr[j] = *(const bshort8*)&B_s[(wn * 64 + j * 16 + r15) * 32 + quad * 8];
#pragma unroll
        for (int i = 0; i < 4; ++i)
#pragma unroll
            for (int j = 0; j < 4; ++j)
                acc[i][j] = __builtin_amdgcn_mfma_f32_16x16x32_bf16(af[i], bfr[j], acc[i][j], 0, 0, 0);
        __syncthreads();
    }
    const int seg = (n0 >= 1536) ? 3 : (n0 >> 9);   // block-uniform
#pragma unroll
    for (int i = 0; i < 4; ++i)
#pragma unroll
        for (int j = 0; j < 4; ++j)
#pragma unroll
            for (int r = 0; r < 4; ++r) {
                const int gm = m0 + wm * 64 + i * 16 + quad * 4 + r;
                const int gn = n0 + wn * 64 + j * 16 + r15;
                float v = acc[i][j][r];
                if (seg == 0) {
                    v = (v + bq[gn]) * 0.125f;
                    const int bb = gm >> 12, s = gm & 4095, hh = gn >> 6, d = gn & 63;
                    Qs[((size_t)(bb * Hn + hh) * S_LEN + s) * DHn + d] = v;
                } else if (seg == 1) {
                    Kb[(size_t)gm * 512 + (gn - 512)] = v + bk[gn - 512];
                } else if (seg == 2) {
                    Vb[(size_t)gm * 512 + (gn - 1024)] = v + bv[gn - 1024];
                } else {
                    DlogBf[(size_t)gm * 1024 + (gn - 1536)] = f2bs(v + bd[gn - 1536]);
                }
            }
}

// ---------------- output GEMM (MFMA): Cbf(8192x512) @ WoT -> out f32 ----------------
__global__ __launch_bounds__(256) void gemm_out(const short* __restrict__ Abf,
    const short* __restrict__ WT, const float* __restrict__ bias, float* __restrict__ outp)
{
    __shared__ short A_s[128 * 32];
    __shared__ short B_s[128 * 32];
    const int t = threadIdx.x;
    const int n0 = blockIdx.x * 128, m0 = blockIdx.y * 128;
    const int lane = t & 63, wave = t >> 6;
    const int wm = wave >> 1, wn = wave & 1;
    const int quad = lane >> 4, r15 = lane & 15;
    const int eOff = t * 8;
    const int am = eOff >> 5, ak = eOff & 31;
    f32x4 acc[4][4];
#pragma unroll
    for (int i = 0; i < 4; ++i)
#pragma unroll
        for (int j = 0; j < 4; ++j) acc[i][j] = (f32x4){0.f, 0.f, 0.f, 0.f};

    for (int kk = 0; kk < KD; kk += 32) {
        gl16(&Abf[(size_t)(m0 + am) * KD + kk + ak],      &A_s[eOff]);
        gl16(&Abf[(size_t)(m0 + 64 + am) * KD + kk + ak], &A_s[2048 + eOff]);
        gl16(&WT[(size_t)(n0 + am) * KD + kk + ak],       &B_s[eOff]);
        gl16(&WT[(size_t)(n0 + 64 + am) * KD + kk + ak],  &B_s[2048 + eOff]);
        __syncthreads();
        bshort8 af[4], bfr[4];
#pragma unroll
        for (int i = 0; i < 4; ++i) af[i]  = *(const bshort8*)&A_s[(wm * 64 + i * 16 + r15) * 32 + quad * 8];
#pragma unroll
        for (int j = 0; j < 4; ++j) bfr[j] = *(const bshort8*)&B_s[(wn * 64 + j * 16 + r15) * 32 + quad * 8];
#pragma unroll
        for (int i = 0; i < 4; ++i)
#pragma unroll
            for (int j = 0; j < 4; ++j)
                acc[i][j] = __builtin_amdgcn_mfma_f32_16x16x32_bf16(af[i], bfr[j], acc[i][j], 0, 0, 0);
        __syncthreads();
    }
#pragma unroll
    for (int i = 0; i < 4; ++i)
#pragma unroll
        for (int j = 0; j < 4; ++j)
#pragma unroll
            for (int r = 0; r < 4; ++r) {
                const int gm = m0 + wm * 64 + i * 16 + quad * 4 + r;
                const int gn = n0 + wn * 64 + j * 16 + r15;
                outp[(size_t)gm * 512 + gn] = acc[i][j][r] + bias[gn];
            }
}

// ---------------- in-place row LayerNorm over 512 (row-major) ----------------
__global__ __launch_bounds__(256) void ln_ip(float* __restrict__ Kb, float* __restrict__ Vb,
    const float* __restrict__ g, const float* __restrict__ beta)
{
    float* buf = blockIdx.y ? Vb : Kb;
    const int row = blockIdx.x, t = threadIdx.x;
    const size_t base = (size_t)row * 512;
    const float x0 = buf[base + t];
    const float x1 = buf[base + t + 256];
    float s = x0 + x1, ss = x0 * x0 + x1 * x1;
#pragma unroll
    for (int off = 32; off >= 1; off >>= 1) { s += __shfl_xor(s, off); ss += __shfl_xor(ss, off); }
    __shared__ float red[2][4];
    if ((t & 63) == 0) { red[0][t >> 6] = s; red[1][t >> 6] = ss; }
    __syncthreads();
    s = red[0][0] + red[0][1] + red[0][2] + red[0][3];
    ss = red[1][0] + red[1][1] + red[1][2] + red[1][3];
    const float mu = s * (1.f / 512.f);
    const float r = rsqrtf(ss * (1.f / 512.f) - mu * mu + 1e-5f);
    buf[base + t]       = (x0 - mu) * r * g[t] + beta[t];
    buf[base + t + 256] = (x1 - mu) * r * g[t + 256] + beta[t + 256];
}

// ---------------- column softmax over S: partial online max/sum (bf16 src) ----------------
__global__ __launch_bounds__(256) void colsm_partial(const short* __restrict__ Dlog,
    float* __restrict__ pM, float* __restrict__ pZ)
{
    const int t = threadIdx.x;
    const int cidx = blockIdx.x * 256 + t;
    const int chunk = blockIdx.y, b = blockIdx.z;
    const int s0 = chunk * 128;
    float m = -1e30f, z = 0.f;
#pragma unroll 4
    for (int s = 0; s < 128; ++s) {
        const float x = bs2f(Dlog[((size_t)b * S_LEN + s0 + s) * HL + cidx]);
        const float mn = fmaxf(m, x);
        z = z * __expf(m - mn) + __expf(x - mn);
        m = mn;
    }
    pM[((size_t)b * HL + cidx) * 32 + chunk] = m;
    pZ[((size_t)b * HL + cidx) * 32 + chunk] = z;
}

__global__ __launch_bounds__(256) void colsm_combine(const float* __restrict__ pM,
    const float* __restrict__ pZ, float* __restrict__ colM, float* __restrict__ colInvZ)
{
    const int idx = blockIdx.x * 256 + threadIdx.x;
    float M = -1e30f;
#pragma unroll
    for (int i = 0; i < 32; ++i) M = fmaxf(M, pM[(size_t)idx * 32 + i]);
    float Z = 0.f;
#pragma unroll
    for (int i = 0; i < 32; ++i) Z += pZ[(size_t)idx * 32 + i] * __expf(pM[(size_t)idx * 32 + i] - M);
    colM[idx] = M;
    colInvZ[idx] = 1.f / Z;
}

// ---------------- Kc/Vc stage 1: per-(chunk,h,b) partial einsum, bf16 partial out ----------------
__global__ __launch_bounds__(256) void kcvc_s1(const short* __restrict__ Dlog,
    const float* __restrict__ colM, const float* __restrict__ colInvZ,
    const float* __restrict__ Kb, const float* __restrict__ Vb,
    short* __restrict__ partK, short* __restrict__ partV)
{
    const int t = threadIdx.x;
    const int chunk = blockIdx.x, h = blockIdx.y, b = blockIdx.z;
    const int s0 = chunk * 128;
    __shared__ float Mh[128], iZ[128];
    __shared__ float aa[8][128];
    __shared__ float kk[8][64], vv[8][64];
    if (t < 128) {
        Mh[t] = colM[b * HL + h * Lc + t];
        iZ[t] = colInvZ[b * HL + h * Lc + t];
    }
    __syncthreads();
    const int lg = t >> 3, dg = t & 7;
    const int l0 = lg * 4, d0 = dg * 8;
    float aK[4][8] = {}, aV[4][8] = {};
    for (int so = 0; so < 16; ++so) {
        const int sbase = s0 + so * 8;
#pragma unroll
        for (int i = 0; i < 4; ++i) {
            const int e = i * 256 + t;
            const int si = e >> 7, li = e & 127;
            aa[si][li] = __expf(bs2f(Dlog[((size_t)b * S_LEN + sbase + si) * HL + h * Lc + li]) - Mh[li]) * iZ[li];
        }
#pragma unroll
        for (int i = 0; i < 2; ++i) {
            const int e = i * 256 + t;
            const int si = e >> 6, d = e & 63;
            kk[si][d] = Kb[((size_t)(b * S_LEN + sbase + si)) * 512 + h * 64 + d];
            vv[si][d] = Vb[((size_t)(b * S_LEN + sbase + si)) * 512 + h * 64 + d];
        }
        __syncthreads();
#pragma unroll
        for (int si = 0; si < 8; ++si) {
            const float4 a4 = *(const float4*)&aa[si][l0];
            const float a[4] = {a4.x, a4.y, a4.z, a4.w};
            const float4 k0 = *(const float4*)&kk[si][d0];
            const float4 k1 = *(const float4*)&kk[si][d0 + 4];
            const float4 v0 = *(const float4*)&vv[si][d0];
            const float4 v1 = *(const float4*)&vv[si][d0 + 4];
            const float k8[8] = {k0.x, k0.y, k0.z, k0.w, k1.x, k1.y, k1.z, k1.w};
            const float v8[8] = {v0.x, v0.y, v0.z, v0.w, v1.x, v1.y, v1.z, v1.w};
#pragma unroll
            for (int i = 0; i < 4; ++i)
#pragma unroll
                for (int j = 0; j < 8; ++j) {
                    aK[i][j] = fmaf(a[i], k8[j], aK[i][j]);
                    aV[i][j] = fmaf(a[i], v8[j], aV[i][j]);
                }
        }
        __syncthreads();
    }
#pragma unroll
    for (int i = 0; i < 4; ++i) {
        const size_t o = (((size_t)(b * Lc + l0 + i)) * 32 + chunk) * 512 + h * 64 + d0;
        bshort8 ok, ov;
#pragma unroll
        for (int j = 0; j < 8; ++j) { ok[j] = f2bs(aK[i][j]); ov[j] = f2bs(aV[i][j]); }
        *(bshort8*)&partK[o] = ok;
        *(bshort8*)&partV[o] = ov;
    }
}

// ---------------- Kc/Vc stage 2: reduce chunks + LN over 512, write (B,H,L,DH) ----------------
__global__ __launch_bounds__(256) void kcvc_s2(const short* __restrict__ partK,
    const short* __restrict__ partV, const float* __restrict__ g, const float* __restrict__ beta,
    float* __restrict__ KcLn, float* __restrict__ VcLn)
{
    const int l = blockIdx.x, b = blockIdx.y, t = threadIdx.x;
    const size_t base = ((size_t)(b * Lc + l)) * 32 * 512;
    float k0 = 0.f, k1 = 0.f, v0 = 0.f, v1 = 0.f;
    for (int ch = 0; ch < 32; ++ch) {
        const size_t o = base + (size_t)ch * 512;
        k0 += bs2f(partK[o + t]);       k1 += bs2f(partK[o + t + 256]);
        v0 += bs2f(partV[o + t]);       v1 += bs2f(partV[o + t + 256]);
    }
    float sk = k0 + k1, ssk = k0 * k0 + k1 * k1;
    float sv = v0 + v1, ssv = v0 * v0 + v1 * v1;
#pragma unroll
    for (int off = 32; off >= 1; off >>= 1) {
        sk += __shfl_xor(sk, off); ssk += __shfl_xor(ssk, off);
        sv += __shfl_xor(sv, off); ssv += __shfl_xor(ssv, off);
    }
    __shared__ float red[4][4];
    if ((t & 63) == 0) {
        red[0][t >> 6] = sk; red[1][t >> 6] = ssk;
        red[2][t >> 6] = sv; red[3][t >> 6] = ssv;
    }
    __syncthreads();
    sk = red[0][0] + red[0][1] + red[0][2] + red[0][3];
    ssk = red[1][0] + red[1][1] + red[1][2] + red[1][3];
    sv = red[2][0] + red[2][1] + red[2][2] + red[2][3];
    ssv = red[3][0] + red[3][1] + red[3][2] + red[3][3];
    const float muK = sk * (1.f / 512.f);
    const float rK = rsqrtf(ssk * (1.f / 512.f) - muK * muK + 1e-5f);
    const float muV = sv * (1.f / 512.f);
    const float rV = rsqrtf(ssv * (1.f / 512.f) - muV * muV + 1e-5f);
#pragma unroll
    for (int half = 0; half < 2; ++half) {
        const int c = t + half * 256;
        const float xk = half ? k1 : k0;
        const float xv = half ? v1 : v0;
        const size_t o = ((size_t)(b * Hn + (c >> 6)) * Lc + l) * DHn + (c & 63);
        KcLn[o] = (xk - muK) * rK * g[c] + beta[c];
        VcLn[o] = (xv - muV) * rV * g[c] + beta[c];
    }
}

// ---------------- fused attention: compressed (L) + window (WIN) keys ----------------
__global__ __launch_bounds__(256) void attn(const float* __restrict__ Qs,
    const float* __restrict__ Kb, const float* __restrict__ Vb,
    const float* __restrict__ KcLn, const float* __restrict__ VcLn,
    const int* __restrict__ mask, short* __restrict__ C)
{
    const int t = threadIdx.x;
    const int qt = blockIdx.x, h = blockIdx.y, b = blockIdx.z;
    const int q0 = qt * 64, gg = qt >> 1;
    __shared__ float Qt[64][68];   // [d][q]
    __shared__ float KV[64][68];   // K phase: [d][j]; V phase: [j][d]
    __shared__ float Sc[64][68];   // [q][j]
    __shared__ float vbias[64];
    const size_t bh = (size_t)(b * Hn + h);

#pragma unroll
    for (int i = 0; i < 4; ++i) {
        const int e = i * 1024 + t * 4;
        const int q = e >> 6, d0 = e & 63;
        const float4 v = *(const float4*)&Qs[(bh * S_LEN + q0 + q) * DHn + d0];
        Qt[d0 + 0][q] = v.x; Qt[d0 + 1][q] = v.y; Qt[d0 + 2][q] = v.z; Qt[d0 + 3][q] = v.w;
    }
    const int qg = t & 15, jg = t >> 4;
    const int qb = t >> 2, part = t & 3;
    float m = -1e30f, l = 0.f;
    float acc[16];
#pragma unroll
    for (int i = 0; i < 16; ++i) acc[i] = 0.f;

    for (int cc = 0; cc < 6; ++cc) {
        __syncthreads();
        if (t < 64) {
            float vb = 0.f;
            if (cc >= 2) {
                const int sk = gg * 128 - 64 + (cc - 2) * 64 + t;
                if (sk < 0 || sk >= S_LEN || mask[b * S_LEN + sk] == 0) vb = -1e30f;
            }
            vbias[t] = vb;
        }
#pragma unroll
        for (int i = 0; i < 4; ++i) {
            const int e = i * 1024 + t * 4;
            const int j = e >> 6, d0 = e & 63;
            float4 kv;
            if (cc < 2) {
                kv = *(const float4*)&KcLn[(bh * Lc + cc * 64 + j) * DHn + d0];
            } else {
                const int sk = gg * 128 - 64 + (cc - 2) * 64 + j;
                if (sk >= 0 && sk < S_LEN) kv = *(const float4*)&Kb[((size_t)b * S_LEN + sk) * 512 + h * 64 + d0];
                else kv = make_float4(0.f, 0.f, 0.f, 0.f);
            }
            KV[d0 + 0][j] = kv.x; KV[d0 + 1][j] = kv.y; KV[d0 + 2][j] = kv.z; KV[d0 + 3][j] = kv.w;
        }
        __syncthreads();
        float c4[4][4] = {};
#pragma unroll
        for (int d = 0; d < 64; ++d) {
            const float4 a4 = *(const float4*)&Qt[d][qg * 4];
            const float4 b4 = *(const float4*)&KV[d][jg * 4];
            const float ar[4] = {a4.x, a4.y, a4.z, a4.w};
            const float br[4] = {b4.x, b4.y, b4.z, b4.w};
#pragma unroll
            for (int ii = 0; ii < 4; ++ii)
#pragma unroll
                for (int jj = 0; jj < 4; ++jj)
                    c4[ii][jj] = fmaf(ar[ii], br[jj], c4[ii][jj]);
        }
#pragma unroll
        for (int ii = 0; ii < 4; ++ii) {
            float4 s4;
            s4.x = c4[ii][0] + vbias[jg * 4 + 0];
            s4.y = c4[ii][1] + vbias[jg * 4 + 1];
            s4.z = c4[ii][2] + vbias[jg * 4 + 2];
            s4.w = c4[ii][3] + vbias[jg * 4 + 3];
            *(float4*)&Sc[qg * 4 + ii][jg * 4] = s4;
        }
        __syncthreads();
#pragma unroll
        for (int i = 0; i < 4; ++i) {
            const int e = i * 1024 + t * 4;
            const int j = e >> 6, d0 = e & 63;
            float4 vv4;
            if (cc < 2) {
                vv4 = *(const float4*)&VcLn[(bh * Lc + cc * 64 + j) * DHn + d0];
            } else {
                const int sk = gg * 128 - 64 + (cc - 2) * 64 + j;
                if (sk >= 0 && sk < S_LEN) vv4 = *(const float4*)&Vb[((size_t)b * S_LEN + sk) * 512 + h * 64 + d0];
                else vv4 = make_float4(0.f, 0.f, 0.f, 0.f);
            }
            *(float4*)&KV[j][d0] = vv4;
        }
        float p[16];
        {
            const float4 r0 = *(const float4*)&Sc[qb][part * 16 + 0];
            const float4 r1 = *(const float4*)&Sc[qb][part * 16 + 4];
            const float4 r2 = *(const float4*)&Sc[qb][part * 16 + 8];
            const float4 r3 = *(const float4*)&Sc[qb][part * 16 + 12];
            p[0] = r0.x; p[1] = r0.y; p[2] = r0.z; p[3] = r0.w;
            p[4] = r1.x; p[5] = r1.y; p[6] = r1.z; p[7] = r1.w;
            p[8] = r2.x; p[9] = r2.y; p[10] = r2.z; p[11] = r2.w;
            p[12] = r3.x; p[13] = r3.y; p[14] = r3.z; p[15] = r3.w;
        }
        float mloc = p[0];
#pragma unroll
        for (int i = 1; i < 16; ++i) mloc = fmaxf(mloc, p[i]);
        mloc = fmaxf(mloc, __shfl_xor(mloc, 1));
        mloc = fmaxf(mloc, __shfl_xor(mloc, 2));
        const float mnew = fmaxf(m, mloc);
        const float alpha = __expf(m - mnew);
        float sum = 0.f;
#pragma unroll
        for (int i = 0; i < 16; ++i) { p[i] = __expf(p[i] - mnew); sum += p[i]; }
        {
            float4 w0 = {p[0], p[1], p[2], p[3]};
            float4 w1 = {p[4], p[5], p[6], p[7]};
            float4 w2 = {p[8], p[9], p[10], p[11]};
            float4 w3 = {p[12], p[13], p[14], p[15]};
            *(float4*)&Sc[qb][part * 16 + 0] = w0;
            *(float4*)&Sc[qb][part * 16 + 4] = w1;
            *(float4*)&Sc[qb][part * 16 + 8] = w2;
            *(float4*)&Sc[qb][part * 16 + 12] = w3;
        }
        sum += __shfl_xor(sum, 1);
        sum += __shfl_xor(sum, 2);
        l = l * alpha + sum;
        m = mnew;
#pragma unroll
        for (int i = 0; i < 16; ++i) acc[i] *= alpha;
        __syncthreads();
#pragma unroll 8
        for (int j = 0; j < 64; ++j) {
            const float pj = Sc[qb][j];
            const float4 v0 = *(const float4*)&KV[j][part * 16 + 0];
            const float4 v1 = *(const float4*)&KV[j][part * 16 + 4];
            const float4 v2 = *(const float4*)&KV[j][part * 16 + 8];
            const float4 v3 = *(const float4*)&KV[j][part * 16 + 12];
            acc[0] = fmaf(pj, v0.x, acc[0]);  acc[1] = fmaf(pj, v0.y, acc[1]);
            acc[2] = fmaf(pj, v0.z, acc[2]);  acc[3] = fmaf(pj, v0.w, acc[3]);
            acc[4] = fmaf(pj, v1.x, acc[4]);  acc[5] = fmaf(pj, v1.y, acc[5]);
            acc[6] = fmaf(pj, v1.z, acc[6]);  acc[7] = fmaf(pj, v1.w, acc[7]);
            acc[8] = fmaf(pj, v2.x, acc[8]);  acc[9] = fmaf(pj, v2.y, acc[9]);
            acc[10] = fmaf(pj, v2.z, acc[10]); acc[11] = fmaf(pj, v2.w, acc[11]);
            acc[12] = fmaf(pj, v3.x, acc[12]); acc[13] = fmaf(pj, v3.y, acc[13]);
            acc[14] = fmaf(pj, v3.z, acc[14]); acc[15] = fmaf(pj, v3.w, acc[15]);
        }
    }
    const int q = q0 + qb;
    const float rl = (mask[b * S_LEN + q] == 0) ? 0.f : (1.f / l);
    const size_t ob = ((size_t)b * S_LEN + q) * 512 + h * 64 + part * 16;
    bshort8 o0, o1;
#pragma unroll
    for (int i = 0; i < 8; ++i) { o0[i] = f2bs(acc[i] * rl); o1[i] = f2bs(acc[8 + i] * rl); }
    *(bshort8*)&C[ob] = o0;
    *(bshort8*)&C[ob + 8] = o1;
}

extern "C" void kernel_launch(void* const* d_in, const int* in_sizes, int n_in,
                              void* d_out, int out_size, void* d_ws, size_t ws_size,
                              hipStream_t stream) {
    (void)in_sizes; (void)n_in; (void)out_size; (void)ws_size;
    const float* X    = (const float*)d_in[0];
    const int*   mask = (const int*)d_in[1];
    const float* Wq = (const float*)d_in[2];  const float* bq = (const float*)d_in[3];
    const float* Wk = (const float*)d_in[4];  const float* bk = (const float*)d_in[5];
    const float* Wv = (const float*)d_in[6];  const float* bv = (const float*)d_in[7];
    const float* Wo = (const float*)d_in[8];  const float* bo = (const float*)d_in[9];
    const float* lnlg = (const float*)d_in[10]; const float* lnlb = (const float*)d_in[11];
    const float* lnsg = (const float*)d_in[12]; const float* lnsb = (const float*)d_in[13];
    const float* Wd = (const float*)d_in[14]; const float* bd = (const float*)d_in[15];

    float* ws = (float*)d_ws;
    float* Qs      = ws;                       // 4,194,304 f32  (B,H,S,DH), pre-scaled
    float* Kb      = Qs + 4194304;             // 4,194,304 f32  row-major, LN'd in place
    float* Vb      = Kb + 4194304;             // 4,194,304 f32
    short* DlogBf  = (short*)(Vb + 4194304);   // 8,388,608 bf16 (4,194,304 slots)
    short* Xbf     = (short*)(Vb + 8388608);   // 4,194,304 bf16 (2,097,152 slots)
    short* WTall   = (short*)(Vb + 10485760);  // 1,310,720 bf16 (655,360 slots)
    short* WoT     = (short*)(Vb + 11141120);  // 262,144 bf16 (131,072 slots)
    float* pM      = Vb + 11272192;            // 65,536
    float* pZ      = pM + 65536;               // 65,536
    float* colM    = pZ + 65536;               // 2,048
    float* colInvZ = colM + 2048;              // 2,048
    float* KcLn    = colInvZ + 2048;           // 131,072
    float* VcLn    = KcLn + 131072;            // 131,072
    short* partK   = (short*)(VcLn + 131072);  // 4,194,304 bf16 (2,097,152 slots)
    short* partV   = partK + 4194304;          // 4,194,304 bf16 (2,097,152 slots)
    short* Cbf     = partK;                    // reuse partK region after kcvc_s2
    // end ≈ 97.0 MB

    const dim3 blk(256);
    // prep: convert X, transpose+convert weights
    cvt_bf<<<2048, blk, 0, stream>>>(X, Xbf);
    wtrans<<<dim3(16, 16), dim3(32, 8), 0, stream>>>(Wq, WTall, 512);
    wtrans<<<dim3(16, 16), dim3(32, 8), 0, stream>>>(Wk, WTall + 512 * 512, 512);
    wtrans<<<dim3(16, 16), dim3(32, 8), 0, stream>>>(Wv, WTall + 1024 * 512, 512);
    wtrans<<<dim3(32, 16), dim3(32, 8), 0, stream>>>(Wd, WTall + 1536 * 512, 1024);
    wtrans<<<dim3(16, 16), dim3(32, 8), 0, stream>>>(Wo, WoT, 512);
    // fused Q/K/V/D projection GEMM (MFMA)
    gemm_proj<<<dim3(20, 64), blk, 0, stream>>>(Xbf, WTall, bq, bk, bv, bd, Qs, Kb, Vb, DlogBf);
    // LN K/V in place
    ln_ip<<<dim3(8192, 2), blk, 0, stream>>>(Kb, Vb, lnlg, lnlb);
    // column softmax of D-logits
    colsm_partial<<<dim3(4, 32, 2), blk, 0, stream>>>(DlogBf, pM, pZ);
    colsm_combine<<<8, blk, 0, stream>>>(pM, pZ, colM, colInvZ);
    // landmark Kc/Vc: partials then reduce+LN
    kcvc_s1<<<dim3(32, 8, 2), blk, 0, stream>>>(DlogBf, colM, colInvZ, Kb, Vb, partK, partV);
    kcvc_s2<<<dim3(128, 2), blk, 0, stream>>>(partK, partV, lnsg, lnsb, KcLn, VcLn);
    // fused attention -> C (bf16)
    attn<<<dim3(64, 8, 2), blk, 0, stream>>>(Qs, Kb, Vb, KcLn, VcLn, mask, Cbf);
    // output projection (MFMA)
    gemm_out<<<dim3(4, 64), blk, 0, stream>>>(Cbf, WoT, bo, (float*)d_out);
}

// Round 4
// 285.851 us; speedup vs baseline: 3.1473x; 1.3720x over previous
//
#include <hip/hip_runtime.h>
#include <hip/hip_bf16.h>

#define S_LEN 4096
#define Hn 8
#define DHn 64
#define Lc 128
#define HL 1024
#define KD 512   // inner dim of all GEMMs

typedef __attribute__((ext_vector_type(8))) short bshort8;
typedef __attribute__((ext_vector_type(4))) float f32x4;

__device__ __forceinline__ short f2bs(float f) {
    union { float f; unsigned u; } x; x.f = f;
    const unsigned r = x.u + 0x7FFFu + ((x.u >> 16) & 1u);
    return (short)(r >> 16);
}
__device__ __forceinline__ float bs2f(short s) {
    union { unsigned u; float f; } x; x.u = ((unsigned)(unsigned short)s) << 16;
    return x.f;
}

// async global(bf16 bits as short) -> LDS, 16B per lane
__device__ __forceinline__ void gl16(const short* g, short* l) {
    __builtin_amdgcn_global_load_lds((const __attribute__((address_space(1))) void*)g,
                                     (__attribute__((address_space(3))) void*)l, 16, 0, 0);
}

// ---------------- f32 -> bf16 convert (8 elems/thread) ----------------
__global__ __launch_bounds__(256) void cvt_bf(const float* __restrict__ src, short* __restrict__ dst)
{
    const int i = (blockIdx.x * 256 + threadIdx.x) * 8;
    const float4 a = *(const float4*)&src[i];
    const float4 b = *(const float4*)&src[i + 4];
    bshort8 o;
    o[0] = f2bs(a.x); o[1] = f2bs(a.y); o[2] = f2bs(a.z); o[3] = f2bs(a.w);
    o[4] = f2bs(b.x); o[5] = f2bs(b.y); o[6] = f2bs(b.z); o[7] = f2bs(b.w);
    *(bshort8*)&dst[i] = o;
}

// ---------------- transpose + convert: W (KD x N f32) -> out (N x KD bf16) ----------------
__global__ __launch_bounds__(256) void wtrans(const float* __restrict__ W, short* __restrict__ out, int N)
{
    __shared__ float Tl[32][33];
    const int tx = threadIdx.x, ty = threadIdx.y;
    const int n0 = blockIdx.x * 32, k0 = blockIdx.y * 32;
#pragma unroll
    for (int i = ty; i < 32; i += 8)
        Tl[i][tx] = W[(size_t)(k0 + i) * N + n0 + tx];
    __syncthreads();
#pragma unroll
    for (int i = ty; i < 32; i += 8)
        out[(size_t)(n0 + i) * KD + k0 + tx] = f2bs(Tl[tx][i]);
}

// ---------------- fused projection GEMM (MFMA): X(8192x512) @ [Wq|Wk|Wv|Wd] ----------------
__global__ __launch_bounds__(256) void gemm_proj(const short* __restrict__ Xbf,
    const short* __restrict__ WT,
    const float* __restrict__ bq, const float* __restrict__ bk,
    const float* __restrict__ bv, const float* __restrict__ bd,
    short* __restrict__ Qbf, float* __restrict__ Kb, float* __restrict__ Vb,
    short* __restrict__ DlogBf)
{
    __shared__ __align__(16) short A_s[128 * 32];
    __shared__ __align__(16) short B_s[128 * 32];
    const int t = threadIdx.x;
    const int n0 = blockIdx.x * 128, m0 = blockIdx.y * 128;
    const int lane = t & 63, wave = t >> 6;
    const int wm = wave >> 1, wn = wave & 1;
    const int quad = lane >> 4, r15 = lane & 15;
    const int eOff = t * 8;
    const int am = eOff >> 5, ak = eOff & 31;
    f32x4 acc[4][4];
#pragma unroll
    for (int i = 0; i < 4; ++i)
#pragma unroll
        for (int j = 0; j < 4; ++j) acc[i][j] = (f32x4){0.f, 0.f, 0.f, 0.f};

    for (int kk = 0; kk < KD; kk += 32) {
        gl16(&Xbf[(size_t)(m0 + am) * KD + kk + ak],      &A_s[eOff]);
        gl16(&Xbf[(size_t)(m0 + 64 + am) * KD + kk + ak], &A_s[2048 + eOff]);
        gl16(&WT[(size_t)(n0 + am) * KD + kk + ak],       &B_s[eOff]);
        gl16(&WT[(size_t)(n0 + 64 + am) * KD + kk + ak],  &B_s[2048 + eOff]);
        __syncthreads();
        bshort8 af[4], bfr[4];
#pragma unroll
        for (int i = 0; i < 4; ++i) af[i]  = *(const bshort8*)&A_s[(wm * 64 + i * 16 + r15) * 32 + quad * 8];
#pragma unroll
        for (int j = 0; j < 4; ++j) bfr[j] = *(const bshort8*)&B_s[(wn * 64 + j * 16 + r15) * 32 + quad * 8];
#pragma unroll
        for (int i = 0; i < 4; ++i)
#pragma unroll
            for (int j = 0; j < 4; ++j)
                acc[i][j] = __builtin_amdgcn_mfma_f32_16x16x32_bf16(af[i], bfr[j], acc[i][j], 0, 0, 0);
        __syncthreads();
    }
    const int seg = (n0 >= 1536) ? 3 : (n0 >> 9);   // block-uniform
#pragma unroll
    for (int i = 0; i < 4; ++i)
#pragma unroll
        for (int j = 0; j < 4; ++j)
#pragma unroll
            for (int r = 0; r < 4; ++r) {
                const int gm = m0 + wm * 64 + i * 16 + quad * 4 + r;
                const int gn = n0 + wn * 64 + j * 16 + r15;
                float v = acc[i][j][r];
                if (seg == 0) {
                    v = (v + bq[gn]) * 0.125f;
                    const int bb = gm >> 12, s = gm & 4095, hh = gn >> 6, d = gn & 63;
                    Qbf[((size_t)(bb * Hn + hh) * S_LEN + s) * DHn + d] = f2bs(v);
                } else if (seg == 1) {
                    Kb[(size_t)gm * 512 + (gn - 512)] = v + bk[gn - 512];
                } else if (seg == 2) {
                    Vb[(size_t)gm * 512 + (gn - 1024)] = v + bv[gn - 1024];
                } else {
                    DlogBf[(size_t)gm * 1024 + (gn - 1536)] = f2bs(v + bd[gn - 1536]);
                }
            }
}

// ---------------- output GEMM (MFMA): Cbf(8192x512) @ WoT -> out f32 ----------------
__global__ __launch_bounds__(256) void gemm_out(const short* __restrict__ Abf,
    const short* __restrict__ WT, const float* __restrict__ bias, float* __restrict__ outp)
{
    __shared__ __align__(16) short A_s[128 * 32];
    __shared__ __align__(16) short B_s[128 * 32];
    const int t = threadIdx.x;
    const int n0 = blockIdx.x * 128, m0 = blockIdx.y * 128;
    const int lane = t & 63, wave = t >> 6;
    const int wm = wave >> 1, wn = wave & 1;
    const int quad = lane >> 4, r15 = lane & 15;
    const int eOff = t * 8;
    const int am = eOff >> 5, ak = eOff & 31;
    f32x4 acc[4][4];
#pragma unroll
    for (int i = 0; i < 4; ++i)
#pragma unroll
        for (int j = 0; j < 4; ++j) acc[i][j] = (f32x4){0.f, 0.f, 0.f, 0.f};

    for (int kk = 0; kk < KD; kk += 32) {
        gl16(&Abf[(size_t)(m0 + am) * KD + kk + ak],      &A_s[eOff]);
        gl16(&Abf[(size_t)(m0 + 64 + am) * KD + kk + ak], &A_s[2048 + eOff]);
        gl16(&WT[(size_t)(n0 + am) * KD + kk + ak],       &B_s[eOff]);
        gl16(&WT[(size_t)(n0 + 64 + am) * KD + kk + ak],  &B_s[2048 + eOff]);
        __syncthreads();
        bshort8 af[4], bfr[4];
#pragma unroll
        for (int i = 0; i < 4; ++i) af[i]  = *(const bshort8*)&A_s[(wm * 64 + i * 16 + r15) * 32 + quad * 8];
#pragma unroll
        for (int j = 0; j < 4; ++j) bfr[j] = *(const bshort8*)&B_s[(wn * 64 + j * 16 + r15) * 32 + quad * 8];
#pragma unroll
        for (int i = 0; i < 4; ++i)
#pragma unroll
            for (int j = 0; j < 4; ++j)
                acc[i][j] = __builtin_amdgcn_mfma_f32_16x16x32_bf16(af[i], bfr[j], acc[i][j], 0, 0, 0);
        __syncthreads();
    }
#pragma unroll
    for (int i = 0; i < 4; ++i)
#pragma unroll
        for (int j = 0; j < 4; ++j)
#pragma unroll
            for (int r = 0; r < 4; ++r) {
                const int gm = m0 + wm * 64 + i * 16 + quad * 4 + r;
                const int gn = n0 + wn * 64 + j * 16 + r15;
                outp[(size_t)gm * 512 + gn] = acc[i][j][r] + bias[gn];
            }
}

// ---------------- in-place row LayerNorm over 512 + bf16 (B,H,S,DH) copy ----------------
__global__ __launch_bounds__(256) void ln_ip(float* __restrict__ Kb, float* __restrict__ Vb,
    const float* __restrict__ g, const float* __restrict__ beta,
    short* __restrict__ Kbf, short* __restrict__ Vbf)
{
    float* buf = blockIdx.y ? Vb : Kb;
    short* bfo = blockIdx.y ? Vbf : Kbf;
    const int row = blockIdx.x, t = threadIdx.x;
    const size_t base = (size_t)row * 512;
    const float x0 = buf[base + t];
    const float x1 = buf[base + t + 256];
    float s = x0 + x1, ss = x0 * x0 + x1 * x1;
#pragma unroll
    for (int off = 32; off >= 1; off >>= 1) { s += __shfl_xor(s, off); ss += __shfl_xor(ss, off); }
    __shared__ float red[2][4];
    if ((t & 63) == 0) { red[0][t >> 6] = s; red[1][t >> 6] = ss; }
    __syncthreads();
    s = red[0][0] + red[0][1] + red[0][2] + red[0][3];
    ss = red[1][0] + red[1][1] + red[1][2] + red[1][3];
    const float mu = s * (1.f / 512.f);
    const float r = rsqrtf(ss * (1.f / 512.f) - mu * mu + 1e-5f);
    const int bb = row >> 12, sidx = row & 4095;
#pragma unroll
    for (int half = 0; half < 2; ++half) {
        const int c = t + half * 256;
        const float x = half ? x1 : x0;
        const float v = (x - mu) * r * g[c] + beta[c];
        buf[base + c] = v;
        bfo[((size_t)(bb * Hn + (c >> 6)) * S_LEN + sidx) * DHn + (c & 63)] = f2bs(v);
    }
}

// ---------------- column softmax over S: partial online max/sum (bf16 src) ----------------
__global__ __launch_bounds__(256) void colsm_partial(const short* __restrict__ Dlog,
    float* __restrict__ pM, float* __restrict__ pZ)
{
    const int t = threadIdx.x;
    const int cidx = blockIdx.x * 256 + t;
    const int chunk = blockIdx.y, b = blockIdx.z;
    const int s0 = chunk * 128;
    float m = -1e30f, z = 0.f;
#pragma unroll 4
    for (int s = 0; s < 128; ++s) {
        const float x = bs2f(Dlog[((size_t)b * S_LEN + s0 + s) * HL + cidx]);
        const float mn = fmaxf(m, x);
        z = z * __expf(m - mn) + __expf(x - mn);
        m = mn;
    }
    pM[((size_t)b * HL + cidx) * 32 + chunk] = m;
    pZ[((size_t)b * HL + cidx) * 32 + chunk] = z;
}

__global__ __launch_bounds__(256) void colsm_combine(const float* __restrict__ pM,
    const float* __restrict__ pZ, float* __restrict__ colM, float* __restrict__ colInvZ)
{
    const int idx = blockIdx.x * 256 + threadIdx.x;
    float M = -1e30f;
#pragma unroll
    for (int i = 0; i < 32; ++i) M = fmaxf(M, pM[(size_t)idx * 32 + i]);
    float Z = 0.f;
#pragma unroll
    for (int i = 0; i < 32; ++i) Z += pZ[(size_t)idx * 32 + i] * __expf(pM[(size_t)idx * 32 + i] - M);
    colM[idx] = M;
    colInvZ[idx] = 1.f / Z;
}

// ---------------- Kc/Vc stage 1: per-(chunk,h,b) partial einsum, bf16 partial out ----------------
__global__ __launch_bounds__(256) void kcvc_s1(const short* __restrict__ Dlog,
    const float* __restrict__ colM, const float* __restrict__ colInvZ,
    const float* __restrict__ Kb, const float* __restrict__ Vb,
    short* __restrict__ partK, short* __restrict__ partV)
{
    const int t = threadIdx.x;
    const int chunk = blockIdx.x, h = blockIdx.y, b = blockIdx.z;
    const int s0 = chunk * 128;
    __shared__ float Mh[128], iZ[128];
    __shared__ float aa[8][128];
    __shared__ float kk[8][64], vv[8][64];
    if (t < 128) {
        Mh[t] = colM[b * HL + h * Lc + t];
        iZ[t] = colInvZ[b * HL + h * Lc + t];
    }
    __syncthreads();
    const int lg = t >> 3, dg = t & 7;
    const int l0 = lg * 4, d0 = dg * 8;
    float aK[4][8] = {}, aV[4][8] = {};
    for (int so = 0; so < 16; ++so) {
        const int sbase = s0 + so * 8;
#pragma unroll
        for (int i = 0; i < 4; ++i) {
            const int e = i * 256 + t;
            const int si = e >> 7, li = e & 127;
            aa[si][li] = __expf(bs2f(Dlog[((size_t)b * S_LEN + sbase + si) * HL + h * Lc + li]) - Mh[li]) * iZ[li];
        }
#pragma unroll
        for (int i = 0; i < 2; ++i) {
            const int e = i * 256 + t;
            const int si = e >> 6, d = e & 63;
            kk[si][d] = Kb[((size_t)(b * S_LEN + sbase + si)) * 512 + h * 64 + d];
            vv[si][d] = Vb[((size_t)(b * S_LEN + sbase + si)) * 512 + h * 64 + d];
        }
        __syncthreads();
#pragma unroll
        for (int si = 0; si < 8; ++si) {
            const float4 a4 = *(const float4*)&aa[si][l0];
            const float a[4] = {a4.x, a4.y, a4.z, a4.w};
            const float4 k0 = *(const float4*)&kk[si][d0];
            const float4 k1 = *(const float4*)&kk[si][d0 + 4];
            const float4 v0 = *(const float4*)&vv[si][d0];
            const float4 v1 = *(const float4*)&vv[si][d0 + 4];
            const float k8[8] = {k0.x, k0.y, k0.z, k0.w, k1.x, k1.y, k1.z, k1.w};
            const float v8[8] = {v0.x, v0.y, v0.z, v0.w, v1.x, v1.y, v1.z, v1.w};
#pragma unroll
            for (int i = 0; i < 4; ++i)
#pragma unroll
                for (int j = 0; j < 8; ++j) {
                    aK[i][j] = fmaf(a[i], k8[j], aK[i][j]);
                    aV[i][j] = fmaf(a[i], v8[j], aV[i][j]);
                }
        }
        __syncthreads();
    }
#pragma unroll
    for (int i = 0; i < 4; ++i) {
        const size_t o = (((size_t)(b * Lc + l0 + i)) * 32 + chunk) * 512 + h * 64 + d0;
        bshort8 ok, ov;
#pragma unroll
        for (int j = 0; j < 8; ++j) { ok[j] = f2bs(aK[i][j]); ov[j] = f2bs(aV[i][j]); }
        *(bshort8*)&partK[o] = ok;
        *(bshort8*)&partV[o] = ov;
    }
}

// ---------------- Kc/Vc stage 2: reduce chunks + LN over 512, write bf16 (B,H,L,DH) ----------------
__global__ __launch_bounds__(256) void kcvc_s2(const short* __restrict__ partK,
    const short* __restrict__ partV, const float* __restrict__ g, const float* __restrict__ beta,
    short* __restrict__ KcBf, short* __restrict__ VcBf)
{
    const int l = blockIdx.x, b = blockIdx.y, t = threadIdx.x;
    const size_t base = ((size_t)(b * Lc + l)) * 32 * 512;
    float k0 = 0.f, k1 = 0.f, v0 = 0.f, v1 = 0.f;
    for (int ch = 0; ch < 32; ++ch) {
        const size_t o = base + (size_t)ch * 512;
        k0 += bs2f(partK[o + t]);       k1 += bs2f(partK[o + t + 256]);
        v0 += bs2f(partV[o + t]);       v1 += bs2f(partV[o + t + 256]);
    }
    float sk = k0 + k1, ssk = k0 * k0 + k1 * k1;
    float sv = v0 + v1, ssv = v0 * v0 + v1 * v1;
#pragma unroll
    for (int off = 32; off >= 1; off >>= 1) {
        sk += __shfl_xor(sk, off); ssk += __shfl_xor(ssk, off);
        sv += __shfl_xor(sv, off); ssv += __shfl_xor(ssv, off);
    }
    __shared__ float red[4][4];
    if ((t & 63) == 0) {
        red[0][t >> 6] = sk; red[1][t >> 6] = ssk;
        red[2][t >> 6] = sv; red[3][t >> 6] = ssv;
    }
    __syncthreads();
    sk = red[0][0] + red[0][1] + red[0][2] + red[0][3];
    ssk = red[1][0] + red[1][1] + red[1][2] + red[1][3];
    sv = red[2][0] + red[2][1] + red[2][2] + red[2][3];
    ssv = red[3][0] + red[3][1] + red[3][2] + red[3][3];
    const float muK = sk * (1.f / 512.f);
    const float rK = rsqrtf(ssk * (1.f / 512.f) - muK * muK + 1e-5f);
    const float muV = sv * (1.f / 512.f);
    const float rV = rsqrtf(ssv * (1.f / 512.f) - muV * muV + 1e-5f);
#pragma unroll
    for (int half = 0; half < 2; ++half) {
        const int c = t + half * 256;
        const float xk = half ? k1 : k0;
        const float xv = half ? v1 : v0;
        const size_t o = ((size_t)(b * Hn + (c >> 6)) * Lc + l) * DHn + (c & 63);
        KcBf[o] = f2bs((xk - muK) * rK * g[c] + beta[c]);
        VcBf[o] = f2bs((xv - muV) * rV * g[c] + beta[c]);
    }
}

// ---------------- MFMA flash attention: 64 q-rows per block, 6 key chunks of 64 ----------------
__global__ __launch_bounds__(256) void attn_mfma(
    const short* __restrict__ Qbf, const short* __restrict__ Kbf, const short* __restrict__ Vbf,
    const short* __restrict__ KcBf, const short* __restrict__ VcBf,
    const int* __restrict__ mask, short* __restrict__ C)
{
    __shared__ __align__(16) short Q_l[64 * 64];   // [q][d] A-frag layout
    __shared__ __align__(16) short K_l[64 * 64];   // [j][d] B-frag layout (contraction d)
    __shared__ __align__(16) short Vt_l[64 * 72];  // [d][j] B-frag layout (contraction j), padded
    __shared__ __align__(16) short P_l[64 * 72];   // [q][j] A-frag layout (contraction j), padded
    __shared__ float vb[64];
    const int t = threadIdx.x;
    const int qt = blockIdx.x, h = blockIdx.y, b = blockIdx.z;
    const int q0 = qt * 64, gg = qt >> 1;
    const size_t bh = (size_t)(b * Hn + h);
    const int lane = t & 63, wave = t >> 6;
    const int quad = lane >> 4, r15 = lane & 15;

    // stage Q once (4096 shorts, 2 rounds of global_load_lds)
    gl16(&Qbf[(bh * S_LEN + q0) * DHn + t * 8], &Q_l[t * 8]);
    gl16(&Qbf[(bh * S_LEN + q0) * DHn + 2048 + t * 8], &Q_l[2048 + t * 8]);

    const int vj = t >> 2, vd0 = (t & 3) * 16;   // V-transpose mapping (coalesced global read)
    f32x4 o[4];
#pragma unroll
    for (int df = 0; df < 4; ++df) o[df] = (f32x4){0.f, 0.f, 0.f, 0.f};
    float mrow[4] = {-1e30f, -1e30f, -1e30f, -1e30f};
    float lrow[4] = {0.f, 0.f, 0.f, 0.f};

    for (int cc = 0; cc < 6; ++cc) {
        const short* ksrc; const short* vsrc;
        int sk0 = 0;
        if (cc < 2) {
            ksrc = &KcBf[(bh * Lc + cc * 64) * DHn];
            vsrc = &VcBf[(bh * Lc + cc * 64) * DHn];
        } else {
            sk0 = gg * 128 - 64 + (cc - 2) * 64;
            if (sk0 < 0 || sk0 >= S_LEN) continue;   // 64-aligned: fully OOB -> skip (block-uniform)
            ksrc = &Kbf[(bh * S_LEN + sk0) * DHn];
            vsrc = &Vbf[(bh * S_LEN + sk0) * DHn];
        }
        __syncthreads();   // previous chunk's PV reads done
        if (t < 64) {
            float v = 0.f;
            if (cc >= 2 && mask[b * S_LEN + sk0 + t] == 0) v = -1e30f;
            vb[t] = v;
        }
        gl16(&ksrc[t * 8], &K_l[t * 8]);
        gl16(&ksrc[2048 + t * 8], &K_l[2048 + t * 8]);
        // V transpose into LDS [d][j]
        {
            const bshort8 v0 = *(const bshort8*)&vsrc[vj * 64 + vd0];
            const bshort8 v1 = *(const bshort8*)&vsrc[vj * 64 + vd0 + 8];
#pragma unroll
            for (int i = 0; i < 8; ++i) {
                Vt_l[(vd0 + i) * 72 + vj] = v0[i];
                Vt_l[(vd0 + 8 + i) * 72 + vj] = v1[i];
            }
        }
        __syncthreads();   // K staged (vmcnt drained), Vt + vb visible
        // QK^T: wave computes its 16 q rows x all 64 keys
        f32x4 c[4];
#pragma unroll
        for (int jf = 0; jf < 4; ++jf) c[jf] = (f32x4){0.f, 0.f, 0.f, 0.f};
#pragma unroll
        for (int ks = 0; ks < 2; ++ks) {
            const bshort8 aq = *(const bshort8*)&Q_l[(wave * 16 + r15) * 64 + ks * 32 + quad * 8];
#pragma unroll
            for (int jf = 0; jf < 4; ++jf) {
                const bshort8 bk = *(const bshort8*)&K_l[(jf * 16 + r15) * 64 + ks * 32 + quad * 8];
                c[jf] = __builtin_amdgcn_mfma_f32_16x16x32_bf16(aq, bk, c[jf], 0, 0, 0);
            }
        }
        // online softmax per q row (row = quad*4 + r, cols spread over r15 group x jf)
        float vbl[4];
#pragma unroll
        for (int jf = 0; jf < 4; ++jf) vbl[jf] = vb[jf * 16 + r15];
        float sc[4][4];
#pragma unroll
        for (int jf = 0; jf < 4; ++jf)
#pragma unroll
            for (int r = 0; r < 4; ++r) sc[jf][r] = c[jf][r] + vbl[jf];
        float mx[4];
#pragma unroll
        for (int r = 0; r < 4; ++r)
            mx[r] = fmaxf(fmaxf(sc[0][r], sc[1][r]), fmaxf(sc[2][r], sc[3][r]));
#pragma unroll
        for (int off = 1; off <= 8; off <<= 1)
#pragma unroll
            for (int r = 0; r < 4; ++r) mx[r] = fmaxf(mx[r], __shfl_xor(mx[r], off));
        float alpha[4];
#pragma unroll
        for (int r = 0; r < 4; ++r) {
            const float mn = fmaxf(mrow[r], mx[r]);
            alpha[r] = __expf(mrow[r] - mn);
            mrow[r] = mn;
        }
        float sum[4] = {0.f, 0.f, 0.f, 0.f};
#pragma unroll
        for (int jf = 0; jf < 4; ++jf)
#pragma unroll
            for (int r = 0; r < 4; ++r) {
                const float p = __expf(sc[jf][r] - mrow[r]);
                sum[r] += p;
                P_l[(wave * 16 + quad * 4 + r) * 72 + jf * 16 + r15] = f2bs(p);
            }
#pragma unroll
        for (int off = 1; off <= 8; off <<= 1)
#pragma unroll
            for (int r = 0; r < 4; ++r) sum[r] += __shfl_xor(sum[r], off);
#pragma unroll
        for (int r = 0; r < 4; ++r) lrow[r] = lrow[r] * alpha[r] + sum[r];
#pragma unroll
        for (int df = 0; df < 4; ++df)
#pragma unroll
            for (int r = 0; r < 4; ++r) o[df][r] *= alpha[r];
        // PV: A-frags from own wave's P rows (same-wave LDS, no barrier needed); Vt synced above
#pragma unroll
        for (int ks = 0; ks < 2; ++ks) {
            const bshort8 ap = *(const bshort8*)&P_l[(wave * 16 + r15) * 72 + ks * 32 + quad * 8];
#pragma unroll
            for (int df = 0; df < 4; ++df) {
                const bshort8 bv = *(const bshort8*)&Vt_l[(df * 16 + r15) * 72 + ks * 32 + quad * 8];
                o[df] = __builtin_amdgcn_mfma_f32_16x16x32_bf16(ap, bv, o[df], 0, 0, 0);
            }
        }
    }
    // epilogue: normalize + store bf16
#pragma unroll
    for (int r = 0; r < 4; ++r) {
        const int q = q0 + wave * 16 + quad * 4 + r;
        const float rl = (mask[b * S_LEN + q] == 0) ? 0.f : (1.f / lrow[r]);
        const size_t ob = ((size_t)b * S_LEN + q) * 512 + h * 64;
#pragma unroll
        for (int df = 0; df < 4; ++df)
            C[ob + df * 16 + r15] = f2bs(o[df][r] * rl);
    }
}

extern "C" void kernel_launch(void* const* d_in, const int* in_sizes, int n_in,
                              void* d_out, int out_size, void* d_ws, size_t ws_size,
                              hipStream_t stream) {
    (void)in_sizes; (void)n_in; (void)out_size; (void)ws_size;
    const float* X    = (const float*)d_in[0];
    const int*   mask = (const int*)d_in[1];
    const float* Wq = (const float*)d_in[2];  const float* bq = (const float*)d_in[3];
    const float* Wk = (const float*)d_in[4];  const float* bk = (const float*)d_in[5];
    const float* Wv = (const float*)d_in[6];  const float* bv = (const float*)d_in[7];
    const float* Wo = (const float*)d_in[8];  const float* bo = (const float*)d_in[9];
    const float* lnlg = (const float*)d_in[10]; const float* lnlb = (const float*)d_in[11];
    const float* lnsg = (const float*)d_in[12]; const float* lnsb = (const float*)d_in[13];
    const float* Wd = (const float*)d_in[14]; const float* bd = (const float*)d_in[15];

    float* ws = (float*)d_ws;
    float* Kb     = ws;                        // 4,194,304 f32 row-major, LN'd in place
    float* Vb     = Kb + 4194304;              // 4,194,304 f32
    short* Qbf    = (short*)(Vb + 4194304);    // 4,194,304 bf16 (B,H,S,DH), pre-scaled
    short* Kbf    = Qbf + 4194304;             // 4,194,304 bf16 (B,H,S,DH), LN'd
    short* Vbf    = Kbf + 4194304;             // 4,194,304 bf16 (B,H,S,DH), LN'd
    short* DlogBf = Vbf + 4194304;             // 8,388,608 bf16
    short* Xbf    = DlogBf + 8388608;          // 4,194,304 bf16 (reused: partK, then Cbf)
    short* WTall  = Xbf + 4194304;             // 1,310,720 bf16
    short* WoT    = WTall + 1310720;           // 262,144 bf16
    short* KcBf   = WoT + 262144;              // 131,072 bf16 (B,H,L,DH)
    short* VcBf   = KcBf + 131072;             // 131,072 bf16
    short* partV  = VcBf + 131072;             // 4,194,304 bf16
    float* pM     = (float*)(partV + 4194304); // 65,536
    float* pZ     = pM + 65536;                // 65,536
    float* colM   = pZ + 65536;                // 2,048
    float* colInvZ= colM + 2048;               // 2,048
    short* partK  = Xbf;                       // reuse (Xbf dead after gemm_proj)
    short* Cbf    = Xbf;                       // reuse (partK dead after kcvc_s2)
    // total ≈ 96.5 MB (≤ round-3's proven 97.0 MB)

    const dim3 blk(256);
    cvt_bf<<<2048, blk, 0, stream>>>(X, Xbf);
    wtrans<<<dim3(16, 16), dim3(32, 8), 0, stream>>>(Wq, WTall, 512);
    wtrans<<<dim3(16, 16), dim3(32, 8), 0, stream>>>(Wk, WTall + 512 * 512, 512);
    wtrans<<<dim3(16, 16), dim3(32, 8), 0, stream>>>(Wv, WTall + 1024 * 512, 512);
    wtrans<<<dim3(32, 16), dim3(32, 8), 0, stream>>>(Wd, WTall + 1536 * 512, 1024);
    wtrans<<<dim3(16, 16), dim3(32, 8), 0, stream>>>(Wo, WoT, 512);
    gemm_proj<<<dim3(20, 64), blk, 0, stream>>>(Xbf, WTall, bq, bk, bv, bd, Qbf, Kb, Vb, DlogBf);
    ln_ip<<<dim3(8192, 2), blk, 0, stream>>>(Kb, Vb, lnlg, lnlb, Kbf, Vbf);
    colsm_partial<<<dim3(4, 32, 2), blk, 0, stream>>>(DlogBf, pM, pZ);
    colsm_combine<<<8, blk, 0, stream>>>(pM, pZ, colM, colInvZ);
    kcvc_s1<<<dim3(32, 8, 2), blk, 0, stream>>>(DlogBf, colM, colInvZ, Kb, Vb, partK, partV);
    kcvc_s2<<<dim3(128, 2), blk, 0, stream>>>(partK, partV, lnsg, lnsb, KcBf, VcBf);
    attn_mfma<<<dim3(64, 8, 2), blk, 0, stream>>>(Qbf, Kbf, Vbf, KcBf, VcBf, mask, Cbf);
    gemm_out<<<dim3(4, 64), blk, 0, stream>>>(Cbf, WoT, bo, (float*)d_out);
}

// Round 5
// 263.913 us; speedup vs baseline: 3.4089x; 1.0831x over previous
//
#include <hip/hip_runtime.h>
#include <hip/hip_bf16.h>

#define S_LEN 4096
#define Hn 8
#define DHn 64
#define Lc 128
#define HL 1024
#define KD 512   // inner dim of all GEMMs

typedef __attribute__((ext_vector_type(8))) short bshort8;
typedef __attribute__((ext_vector_type(4))) float f32x4;

__device__ __forceinline__ short f2bs(float f) {
    union { float f; unsigned u; } x; x.f = f;
    const unsigned r = x.u + 0x7FFFu + ((x.u >> 16) & 1u);
    return (short)(r >> 16);
}
__device__ __forceinline__ float bs2f(short s) {
    union { unsigned u; float f; } x; x.u = ((unsigned)(unsigned short)s) << 16;
    return x.f;
}

// async global(bf16 bits as short) -> LDS, 16B per lane
__device__ __forceinline__ void gl16(const short* g, short* l) {
    __builtin_amdgcn_global_load_lds((const __attribute__((address_space(1))) void*)g,
                                     (__attribute__((address_space(3))) void*)l, 16, 0, 0);
}

// ---------------- f32 -> bf16 convert (8 elems/thread) ----------------
__global__ __launch_bounds__(256) void cvt_bf(const float* __restrict__ src, short* __restrict__ dst)
{
    const int i = (blockIdx.x * 256 + threadIdx.x) * 8;
    const float4 a = *(const float4*)&src[i];
    const float4 b = *(const float4*)&src[i + 4];
    bshort8 o;
    o[0] = f2bs(a.x); o[1] = f2bs(a.y); o[2] = f2bs(a.z); o[3] = f2bs(a.w);
    o[4] = f2bs(b.x); o[5] = f2bs(b.y); o[6] = f2bs(b.z); o[7] = f2bs(b.w);
    *(bshort8*)&dst[i] = o;
}

// ---------------- transpose + convert: W (KD x N f32) -> out (N x KD bf16) ----------------
__global__ __launch_bounds__(256) void wtrans(const float* __restrict__ W, short* __restrict__ out, int N)
{
    __shared__ float Tl[32][33];
    const int tx = threadIdx.x, ty = threadIdx.y;
    const int n0 = blockIdx.x * 32, k0 = blockIdx.y * 32;
#pragma unroll
    for (int i = ty; i < 32; i += 8)
        Tl[i][tx] = W[(size_t)(k0 + i) * N + n0 + tx];
    __syncthreads();
#pragma unroll
    for (int i = ty; i < 32; i += 8)
        out[(size_t)(n0 + i) * KD + k0 + tx] = f2bs(Tl[tx][i]);
}

// ---------------- fused projection GEMM (MFMA): X(8192x512) @ [Wq|Wk|Wv|Wd] ----------------
__global__ __launch_bounds__(256) void gemm_proj(const short* __restrict__ Xbf,
    const short* __restrict__ WT,
    const float* __restrict__ bq, const float* __restrict__ bk,
    const float* __restrict__ bv, const float* __restrict__ bd,
    short* __restrict__ Qbf, short* __restrict__ KbBf, short* __restrict__ VbBf,
    short* __restrict__ DlogBf)
{
    __shared__ __align__(16) short A_s[128 * 32];
    __shared__ __align__(16) short B_s[128 * 32];
    const int t = threadIdx.x;
    const int n0 = blockIdx.x * 128, m0 = blockIdx.y * 128;
    const int lane = t & 63, wave = t >> 6;
    const int wm = wave >> 1, wn = wave & 1;
    const int quad = lane >> 4, r15 = lane & 15;
    const int eOff = t * 8;
    const int am = eOff >> 5, ak = eOff & 31;
    f32x4 acc[4][4];
#pragma unroll
    for (int i = 0; i < 4; ++i)
#pragma unroll
        for (int j = 0; j < 4; ++j) acc[i][j] = (f32x4){0.f, 0.f, 0.f, 0.f};

    for (int kk = 0; kk < KD; kk += 32) {
        gl16(&Xbf[(size_t)(m0 + am) * KD + kk + ak],      &A_s[eOff]);
        gl16(&Xbf[(size_t)(m0 + 64 + am) * KD + kk + ak], &A_s[2048 + eOff]);
        gl16(&WT[(size_t)(n0 + am) * KD + kk + ak],       &B_s[eOff]);
        gl16(&WT[(size_t)(n0 + 64 + am) * KD + kk + ak],  &B_s[2048 + eOff]);
        __syncthreads();
        bshort8 af[4], bfr[4];
#pragma unroll
        for (int i = 0; i < 4; ++i) af[i]  = *(const bshort8*)&A_s[(wm * 64 + i * 16 + r15) * 32 + quad * 8];
#pragma unroll
        for (int j = 0; j < 4; ++j) bfr[j] = *(const bshort8*)&B_s[(wn * 64 + j * 16 + r15) * 32 + quad * 8];
#pragma unroll
        for (int i = 0; i < 4; ++i)
#pragma unroll
            for (int j = 0; j < 4; ++j)
                acc[i][j] = __builtin_amdgcn_mfma_f32_16x16x32_bf16(af[i], bfr[j], acc[i][j], 0, 0, 0);
        __syncthreads();
    }
    const int seg = (n0 >= 1536) ? 3 : (n0 >> 9);   // block-uniform
#pragma unroll
    for (int i = 0; i < 4; ++i)
#pragma unroll
        for (int j = 0; j < 4; ++j)
#pragma unroll
            for (int r = 0; r < 4; ++r) {
                const int gm = m0 + wm * 64 + i * 16 + quad * 4 + r;
                const int gn = n0 + wn * 64 + j * 16 + r15;
                float v = acc[i][j][r];
                if (seg == 0) {
                    v = (v + bq[gn]) * 0.125f;
                    const int bb = gm >> 12, s = gm & 4095, hh = gn >> 6, d = gn & 63;
                    Qbf[((size_t)(bb * Hn + hh) * S_LEN + s) * DHn + d] = f2bs(v);
                } else if (seg == 1) {
                    KbBf[(size_t)gm * 512 + (gn - 512)] = f2bs(v + bk[gn - 512]);
                } else if (seg == 2) {
                    VbBf[(size_t)gm * 512 + (gn - 1024)] = f2bs(v + bv[gn - 1024]);
                } else {
                    DlogBf[(size_t)gm * 1024 + (gn - 1536)] = f2bs(v + bd[gn - 1536]);
                }
            }
}

// ---------------- output GEMM (MFMA): Cbf(8192x512) @ WoT -> out f32 ----------------
__global__ __launch_bounds__(256) void gemm_out(const short* __restrict__ Abf,
    const short* __restrict__ WT, const float* __restrict__ bias, float* __restrict__ outp)
{
    __shared__ __align__(16) short A_s[128 * 32];
    __shared__ __align__(16) short B_s[128 * 32];
    const int t = threadIdx.x;
    const int n0 = blockIdx.x * 128, m0 = blockIdx.y * 128;
    const int lane = t & 63, wave = t >> 6;
    const int wm = wave >> 1, wn = wave & 1;
    const int quad = lane >> 4, r15 = lane & 15;
    const int eOff = t * 8;
    const int am = eOff >> 5, ak = eOff & 31;
    f32x4 acc[4][4];
#pragma unroll
    for (int i = 0; i < 4; ++i)
#pragma unroll
        for (int j = 0; j < 4; ++j) acc[i][j] = (f32x4){0.f, 0.f, 0.f, 0.f};

    for (int kk = 0; kk < KD; kk += 32) {
        gl16(&Abf[(size_t)(m0 + am) * KD + kk + ak],      &A_s[eOff]);
        gl16(&Abf[(size_t)(m0 + 64 + am) * KD + kk + ak], &A_s[2048 + eOff]);
        gl16(&WT[(size_t)(n0 + am) * KD + kk + ak],       &B_s[eOff]);
        gl16(&WT[(size_t)(n0 + 64 + am) * KD + kk + ak],  &B_s[2048 + eOff]);
        __syncthreads();
        bshort8 af[4], bfr[4];
#pragma unroll
        for (int i = 0; i < 4; ++i) af[i]  = *(const bshort8*)&A_s[(wm * 64 + i * 16 + r15) * 32 + quad * 8];
#pragma unroll
        for (int j = 0; j < 4; ++j) bfr[j] = *(const bshort8*)&B_s[(wn * 64 + j * 16 + r15) * 32 + quad * 8];
#pragma unroll
        for (int i = 0; i < 4; ++i)
#pragma unroll
            for (int j = 0; j < 4; ++j)
                acc[i][j] = __builtin_amdgcn_mfma_f32_16x16x32_bf16(af[i], bfr[j], acc[i][j], 0, 0, 0);
        __syncthreads();
    }
#pragma unroll
    for (int i = 0; i < 4; ++i)
#pragma unroll
        for (int j = 0; j < 4; ++j)
#pragma unroll
            for (int r = 0; r < 4; ++r) {
                const int gm = m0 + wm * 64 + i * 16 + quad * 4 + r;
                const int gn = n0 + wn * 64 + j * 16 + r15;
                outp[(size_t)gm * 512 + gn] = acc[i][j][r] + bias[gn];
            }
}

// ---------------- row LayerNorm over 512 (bf16 in, bf16 (B,H,S,DH) out) ----------------
__global__ __launch_bounds__(256) void ln_ip(const short* __restrict__ KbBf, const short* __restrict__ VbBf,
    const float* __restrict__ g, const float* __restrict__ beta,
    short* __restrict__ Kbf, short* __restrict__ Vbf)
{
    const short* src = blockIdx.y ? VbBf : KbBf;
    short* dst = blockIdx.y ? Vbf : Kbf;
    const int row = blockIdx.x, t = threadIdx.x;
    const size_t base = (size_t)row * 512;
    const float x0 = bs2f(src[base + t]);
    const float x1 = bs2f(src[base + t + 256]);
    float s = x0 + x1, ss = x0 * x0 + x1 * x1;
#pragma unroll
    for (int off = 32; off >= 1; off >>= 1) { s += __shfl_xor(s, off); ss += __shfl_xor(ss, off); }
    __shared__ float red[2][4];
    if ((t & 63) == 0) { red[0][t >> 6] = s; red[1][t >> 6] = ss; }
    __syncthreads();
    s = red[0][0] + red[0][1] + red[0][2] + red[0][3];
    ss = red[1][0] + red[1][1] + red[1][2] + red[1][3];
    const float mu = s * (1.f / 512.f);
    const float r = rsqrtf(ss * (1.f / 512.f) - mu * mu + 1e-5f);
    const int bb = row >> 12, sidx = row & 4095;
#pragma unroll
    for (int half = 0; half < 2; ++half) {
        const int c = t + half * 256;
        const float x = half ? x1 : x0;
        const float v = (x - mu) * r * g[c] + beta[c];
        dst[((size_t)(bb * Hn + (c >> 6)) * S_LEN + sidx) * DHn + (c & 63)] = f2bs(v);
    }
}

// ---------------- column softmax over S: partial online max/sum (bf16 src) ----------------
__global__ __launch_bounds__(256) void colsm_partial(const short* __restrict__ Dlog,
    float* __restrict__ pM, float* __restrict__ pZ)
{
    const int t = threadIdx.x;
    const int cidx = blockIdx.x * 256 + t;
    const int chunk = blockIdx.y, b = blockIdx.z;
    const int s0 = chunk * 128;
    float m = -1e30f, z = 0.f;
#pragma unroll 4
    for (int s = 0; s < 128; ++s) {
        const float x = bs2f(Dlog[((size_t)b * S_LEN + s0 + s) * HL + cidx]);
        const float mn = fmaxf(m, x);
        z = z * __expf(m - mn) + __expf(x - mn);
        m = mn;
    }
    pM[((size_t)b * HL + cidx) * 32 + chunk] = m;
    pZ[((size_t)b * HL + cidx) * 32 + chunk] = z;
}

__global__ __launch_bounds__(256) void colsm_combine(const float* __restrict__ pM,
    const float* __restrict__ pZ, float* __restrict__ colM, float* __restrict__ colInvZ)
{
    const int idx = blockIdx.x * 256 + threadIdx.x;
    float M = -1e30f;
#pragma unroll
    for (int i = 0; i < 32; ++i) M = fmaxf(M, pM[(size_t)idx * 32 + i]);
    float Z = 0.f;
#pragma unroll
    for (int i = 0; i < 32; ++i) Z += pZ[(size_t)idx * 32 + i] * __expf(pM[(size_t)idx * 32 + i] - M);
    colM[idx] = M;
    colInvZ[idx] = 1.f / Z;
}

// ---------------- Kc/Vc stage 1 (MFMA): hs[l,s] @ K[s,d] per (seg,h,b), bf16 partials ----------------
__global__ __launch_bounds__(256) void kcvc_mfma(const short* __restrict__ Dlog,
    const float* __restrict__ colM, const float* __restrict__ colInvZ,
    const short* __restrict__ Kbf, const short* __restrict__ Vbf,
    short* __restrict__ partK, short* __restrict__ partV)
{
    __shared__ __align__(16) short aa[128 * 72];   // [l][s] A-frag layout
    __shared__ __align__(16) short Kt[64 * 72];    // [d][s] B-frag layout
    __shared__ __align__(16) short Vt[64 * 72];
    __shared__ float Mh[128], iZ[128];
    const int t = threadIdx.x;
    const int seg = blockIdx.x, h = blockIdx.y, b = blockIdx.z;
    const int s0 = seg * 128;
    const size_t bh = (size_t)(b * Hn + h);
    if (t < 128) {
        Mh[t] = colM[b * HL + h * Lc + t];
        iZ[t] = colInvZ[b * HL + h * Lc + t];
    }
    const int lane = t & 63, wave = t >> 6;
    const int quad = lane >> 4, r15 = lane & 15;
    const int al = t & 127, ah = t >> 7;          // aa staging: l, s-half
    const int vj = t >> 2, vd0 = (t & 3) * 16;    // K/V transpose staging
    f32x4 aK[2][4], aV[2][4];
#pragma unroll
    for (int i = 0; i < 2; ++i)
#pragma unroll
        for (int j = 0; j < 4; ++j) { aK[i][j] = (f32x4){0.f,0.f,0.f,0.f}; aV[i][j] = (f32x4){0.f,0.f,0.f,0.f}; }
    __syncthreads();   // Mh/iZ visible
    const float M = Mh[al], Z = iZ[al];

    for (int c = 0; c < 2; ++c) {
        const int sc0 = s0 + c * 64;
        if (c) __syncthreads();   // previous chunk's MFMA reads done
        // stage exp'd hs chunk: aa[l][s_local]
#pragma unroll
        for (int gch = 0; gch < 4; ++gch) {
            bshort8 o;
#pragma unroll
            for (int j = 0; j < 8; ++j) {
                const int s = sc0 + ah * 32 + gch * 8 + j;
                o[j] = f2bs(__expf(bs2f(Dlog[((size_t)b * S_LEN + s) * HL + h * Lc + al]) - M) * Z);
            }
            *(bshort8*)&aa[al * 72 + ah * 32 + gch * 8] = o;
        }
        // stage K/V transposed
        {
            const size_t rb = (bh * S_LEN + sc0 + vj) * DHn + vd0;
            const bshort8 k0 = *(const bshort8*)&Kbf[rb];
            const bshort8 k1 = *(const bshort8*)&Kbf[rb + 8];
            const bshort8 v0 = *(const bshort8*)&Vbf[rb];
            const bshort8 v1 = *(const bshort8*)&Vbf[rb + 8];
#pragma unroll
            for (int i = 0; i < 8; ++i) {
                Kt[(vd0 + i) * 72 + vj] = k0[i]; Kt[(vd0 + 8 + i) * 72 + vj] = k1[i];
                Vt[(vd0 + i) * 72 + vj] = v0[i]; Vt[(vd0 + 8 + i) * 72 + vj] = v1[i];
            }
        }
        __syncthreads();
#pragma unroll
        for (int ks = 0; ks < 2; ++ks) {
            const bshort8 a0 = *(const bshort8*)&aa[(wave * 32 + r15) * 72 + ks * 32 + quad * 8];
            const bshort8 a1 = *(const bshort8*)&aa[(wave * 32 + 16 + r15) * 72 + ks * 32 + quad * 8];
#pragma unroll
            for (int j = 0; j < 4; ++j) {
                const bshort8 bk = *(const bshort8*)&Kt[(j * 16 + r15) * 72 + ks * 32 + quad * 8];
                const bshort8 bv = *(const bshort8*)&Vt[(j * 16 + r15) * 72 + ks * 32 + quad * 8];
                aK[0][j] = __builtin_amdgcn_mfma_f32_16x16x32_bf16(a0, bk, aK[0][j], 0, 0, 0);
                aK[1][j] = __builtin_amdgcn_mfma_f32_16x16x32_bf16(a1, bk, aK[1][j], 0, 0, 0);
                aV[0][j] = __builtin_amdgcn_mfma_f32_16x16x32_bf16(a0, bv, aV[0][j], 0, 0, 0);
                aV[1][j] = __builtin_amdgcn_mfma_f32_16x16x32_bf16(a1, bv, aV[1][j], 0, 0, 0);
            }
        }
    }
    // epilogue: C layout col=r15 (d), row=quad*4+reg (l); partial chunk index = seg
#pragma unroll
    for (int i = 0; i < 2; ++i)
#pragma unroll
        for (int j = 0; j < 4; ++j)
#pragma unroll
            for (int r = 0; r < 4; ++r) {
                const int l = wave * 32 + i * 16 + quad * 4 + r;
                const int d = j * 16 + r15;
                const size_t o = (((size_t)(b * Lc + l)) * 32 + seg) * 512 + h * 64 + d;
                partK[o] = f2bs(aK[i][j][r]);
                partV[o] = f2bs(aV[i][j][r]);
            }
}

// ---------------- Kc/Vc stage 2: reduce chunks + LN over 512, write bf16 (B,H,L,DH) ----------------
__global__ __launch_bounds__(256) void kcvc_s2(const short* __restrict__ partK,
    const short* __restrict__ partV, const float* __restrict__ g, const float* __restrict__ beta,
    short* __restrict__ KcBf, short* __restrict__ VcBf)
{
    const int l = blockIdx.x, b = blockIdx.y, t = threadIdx.x;
    const size_t base = ((size_t)(b * Lc + l)) * 32 * 512;
    float k0 = 0.f, k1 = 0.f, v0 = 0.f, v1 = 0.f;
    for (int ch = 0; ch < 32; ++ch) {
        const size_t o = base + (size_t)ch * 512;
        k0 += bs2f(partK[o + t]);       k1 += bs2f(partK[o + t + 256]);
        v0 += bs2f(partV[o + t]);       v1 += bs2f(partV[o + t + 256]);
    }
    float sk = k0 + k1, ssk = k0 * k0 + k1 * k1;
    float sv = v0 + v1, ssv = v0 * v0 + v1 * v1;
#pragma unroll
    for (int off = 32; off >= 1; off >>= 1) {
        sk += __shfl_xor(sk, off); ssk += __shfl_xor(ssk, off);
        sv += __shfl_xor(sv, off); ssv += __shfl_xor(ssv, off);
    }
    __shared__ float red[4][4];
    if ((t & 63) == 0) {
        red[0][t >> 6] = sk; red[1][t >> 6] = ssk;
        red[2][t >> 6] = sv; red[3][t >> 6] = ssv;
    }
    __syncthreads();
    sk = red[0][0] + red[0][1] + red[0][2] + red[0][3];
    ssk = red[1][0] + red[1][1] + red[1][2] + red[1][3];
    sv = red[2][0] + red[2][1] + red[2][2] + red[2][3];
    ssv = red[3][0] + red[3][1] + red[3][2] + red[3][3];
    const float muK = sk * (1.f / 512.f);
    const float rK = rsqrtf(ssk * (1.f / 512.f) - muK * muK + 1e-5f);
    const float muV = sv * (1.f / 512.f);
    const float rV = rsqrtf(ssv * (1.f / 512.f) - muV * muV + 1e-5f);
#pragma unroll
    for (int half = 0; half < 2; ++half) {
        const int c = t + half * 256;
        const float xk = half ? k1 : k0;
        const float xv = half ? v1 : v0;
        const size_t o = ((size_t)(b * Hn + (c >> 6)) * Lc + l) * DHn + (c & 63);
        KcBf[o] = f2bs((xk - muK) * rK * g[c] + beta[c]);
        VcBf[o] = f2bs((xv - muV) * rV * g[c] + beta[c]);
    }
}

// ---------------- MFMA flash attention: 64 q-rows per block, 6 key chunks of 64 ----------------
__global__ __launch_bounds__(256) void attn_mfma(
    const short* __restrict__ Qbf, const short* __restrict__ Kbf, const short* __restrict__ Vbf,
    const short* __restrict__ KcBf, const short* __restrict__ VcBf,
    const int* __restrict__ mask, short* __restrict__ C)
{
    __shared__ __align__(16) short Q_l[64 * 64];   // [q][d] A-frag layout
    __shared__ __align__(16) short K_l[64 * 64];   // [j][d] B-frag layout (contraction d)
    __shared__ __align__(16) short Vt_l[64 * 72];  // [d][j] B-frag layout (contraction j), padded
    __shared__ __align__(16) short P_l[64 * 72];   // [q][j] A-frag layout (contraction j), padded
    __shared__ float vb[64];
    const int t = threadIdx.x;
    const int qt = blockIdx.x, h = blockIdx.y, b = blockIdx.z;
    const int q0 = qt * 64, gg = qt >> 1;
    const size_t bh = (size_t)(b * Hn + h);
    const int lane = t & 63, wave = t >> 6;
    const int quad = lane >> 4, r15 = lane & 15;

    gl16(&Qbf[(bh * S_LEN + q0) * DHn + t * 8], &Q_l[t * 8]);
    gl16(&Qbf[(bh * S_LEN + q0) * DHn + 2048 + t * 8], &Q_l[2048 + t * 8]);

    const int vj = t >> 2, vd0 = (t & 3) * 16;
    f32x4 o[4];
#pragma unroll
    for (int df = 0; df < 4; ++df) o[df] = (f32x4){0.f, 0.f, 0.f, 0.f};
    float mrow[4] = {-1e30f, -1e30f, -1e30f, -1e30f};
    float lrow[4] = {0.f, 0.f, 0.f, 0.f};

    for (int cc = 0; cc < 6; ++cc) {
        const short* ksrc; const short* vsrc;
        int sk0 = 0;
        if (cc < 2) {
            ksrc = &KcBf[(bh * Lc + cc * 64) * DHn];
            vsrc = &VcBf[(bh * Lc + cc * 64) * DHn];
        } else {
            sk0 = gg * 128 - 64 + (cc - 2) * 64;
            if (sk0 < 0 || sk0 >= S_LEN) continue;   // 64-aligned: fully OOB -> skip (block-uniform)
            ksrc = &Kbf[(bh * S_LEN + sk0) * DHn];
            vsrc = &Vbf[(bh * S_LEN + sk0) * DHn];
        }
        __syncthreads();
        if (t < 64) {
            float v = 0.f;
            if (cc >= 2 && mask[b * S_LEN + sk0 + t] == 0) v = -1e30f;
            vb[t] = v;
        }
        gl16(&ksrc[t * 8], &K_l[t * 8]);
        gl16(&ksrc[2048 + t * 8], &K_l[2048 + t * 8]);
        {
            const bshort8 v0 = *(const bshort8*)&vsrc[vj * 64 + vd0];
            const bshort8 v1 = *(const bshort8*)&vsrc[vj * 64 + vd0 + 8];
#pragma unroll
            for (int i = 0; i < 8; ++i) {
                Vt_l[(vd0 + i) * 72 + vj] = v0[i];
                Vt_l[(vd0 + 8 + i) * 72 + vj] = v1[i];
            }
        }
        __syncthreads();
        f32x4 c[4];
#pragma unroll
        for (int jf = 0; jf < 4; ++jf) c[jf] = (f32x4){0.f, 0.f, 0.f, 0.f};
#pragma unroll
        for (int ks = 0; ks < 2; ++ks) {
            const bshort8 aq = *(const bshort8*)&Q_l[(wave * 16 + r15) * 64 + ks * 32 + quad * 8];
#pragma unroll
            for (int jf = 0; jf < 4; ++jf) {
                const bshort8 bk = *(const bshort8*)&K_l[(jf * 16 + r15) * 64 + ks * 32 + quad * 8];
                c[jf] = __builtin_amdgcn_mfma_f32_16x16x32_bf16(aq, bk, c[jf], 0, 0, 0);
            }
        }
        float vbl[4];
#pragma unroll
        for (int jf = 0; jf < 4; ++jf) vbl[jf] = vb[jf * 16 + r15];
        float sc[4][4];
#pragma unroll
        for (int jf = 0; jf < 4; ++jf)
#pragma unroll
            for (int r = 0; r < 4; ++r) sc[jf][r] = c[jf][r] + vbl[jf];
        float mx[4];
#pragma unroll
        for (int r = 0; r < 4; ++r)
            mx[r] = fmaxf(fmaxf(sc[0][r], sc[1][r]), fmaxf(sc[2][r], sc[3][r]));
#pragma unroll
        for (int off = 1; off <= 8; off <<= 1)
#pragma unroll
            for (int r = 0; r < 4; ++r) mx[r] = fmaxf(mx[r], __shfl_xor(mx[r], off));
        float alpha[4];
#pragma unroll
        for (int r = 0; r < 4; ++r) {
            const float mn = fmaxf(mrow[r], mx[r]);
            alpha[r] = __expf(mrow[r] - mn);
            mrow[r] = mn;
        }
        float sum[4] = {0.f, 0.f, 0.f, 0.f};
#pragma unroll
        for (int jf = 0; jf < 4; ++jf)
#pragma unroll
            for (int r = 0; r < 4; ++r) {
                const float p = __expf(sc[jf][r] - mrow[r]);
                sum[r] += p;
                P_l[(wave * 16 + quad * 4 + r) * 72 + jf * 16 + r15] = f2bs(p);
            }
#pragma unroll
        for (int off = 1; off <= 8; off <<= 1)
#pragma unroll
            for (int r = 0; r < 4; ++r) sum[r] += __shfl_xor(sum[r], off);
#pragma unroll
        for (int r = 0; r < 4; ++r) lrow[r] = lrow[r] * alpha[r] + sum[r];
#pragma unroll
        for (int df = 0; df < 4; ++df)
#pragma unroll
            for (int r = 0; r < 4; ++r) o[df][r] *= alpha[r];
#pragma unroll
        for (int ks = 0; ks < 2; ++ks) {
            const bshort8 ap = *(const bshort8*)&P_l[(wave * 16 + r15) * 72 + ks * 32 + quad * 8];
#pragma unroll
            for (int df = 0; df < 4; ++df) {
                const bshort8 bv = *(const bshort8*)&Vt_l[(df * 16 + r15) * 72 + ks * 32 + quad * 8];
                o[df] = __builtin_amdgcn_mfma_f32_16x16x32_bf16(ap, bv, o[df], 0, 0, 0);
            }
        }
    }
#pragma unroll
    for (int r = 0; r < 4; ++r) {
        const int q = q0 + wave * 16 + quad * 4 + r;
        const float rl = (mask[b * S_LEN + q] == 0) ? 0.f : (1.f / lrow[r]);
        const size_t ob = ((size_t)b * S_LEN + q) * 512 + h * 64;
#pragma unroll
        for (int df = 0; df < 4; ++df)
            C[ob + df * 16 + r15] = f2bs(o[df][r] * rl);
    }
}

extern "C" void kernel_launch(void* const* d_in, const int* in_sizes, int n_in,
                              void* d_out, int out_size, void* d_ws, size_t ws_size,
                              hipStream_t stream) {
    (void)in_sizes; (void)n_in; (void)out_size; (void)ws_size;
    const float* X    = (const float*)d_in[0];
    const int*   mask = (const int*)d_in[1];
    const float* Wq = (const float*)d_in[2];  const float* bq = (const float*)d_in[3];
    const float* Wk = (const float*)d_in[4];  const float* bk = (const float*)d_in[5];
    const float* Wv = (const float*)d_in[6];  const float* bv = (const float*)d_in[7];
    const float* Wo = (const float*)d_in[8];  const float* bo = (const float*)d_in[9];
    const float* lnlg = (const float*)d_in[10]; const float* lnlb = (const float*)d_in[11];
    const float* lnsg = (const float*)d_in[12]; const float* lnsb = (const float*)d_in[13];
    const float* Wd = (const float*)d_in[14]; const float* bd = (const float*)d_in[15];

    short* sw = (short*)d_ws;
    short* Qbf    = sw;                        // 4,194,304 bf16 (B,H,S,DH), pre-scaled
    short* Kbf    = Qbf + 4194304;             // 4,194,304 bf16 (B,H,S,DH), LN'd
    short* Vbf    = Kbf + 4194304;             // 4,194,304 bf16 (B,H,S,DH), LN'd
    short* KbBf   = Vbf + 4194304;             // 4,194,304 bf16 row-major pre-LN K
    short* VbBf   = KbBf + 4194304;            // 4,194,304 bf16 row-major pre-LN V
    short* DlogBf = VbBf + 4194304;            // 8,388,608 bf16
    short* Xbf    = DlogBf + 8388608;          // 4,194,304 bf16 (reused: partK, then Cbf)
    short* WTall  = Xbf + 4194304;             // 1,310,720 bf16
    short* WoT    = WTall + 1310720;           // 262,144 bf16
    short* KcBf   = WoT + 262144;              // 131,072 bf16 (B,H,L,DH)
    short* VcBf   = KcBf + 131072;             // 131,072 bf16
    short* partV  = VcBf + 131072;             // 4,194,304 bf16
    float* pM     = (float*)(partV + 4194304); // 65,536 f32
    float* pZ     = pM + 65536;                // 65,536
    float* colM   = pZ + 65536;                // 2,048
    float* colInvZ= colM + 2048;               // 2,048
    short* partK  = Xbf;                       // reuse (Xbf dead after gemm_proj)
    short* Cbf    = Xbf;                       // reuse (partK dead after kcvc_s2)
    // total ≈ 79.7 MB

    const dim3 blk(256);
    cvt_bf<<<2048, blk, 0, stream>>>(X, Xbf);
    wtrans<<<dim3(16, 16), dim3(32, 8), 0, stream>>>(Wq, WTall, 512);
    wtrans<<<dim3(16, 16), dim3(32, 8), 0, stream>>>(Wk, WTall + 512 * 512, 512);
    wtrans<<<dim3(16, 16), dim3(32, 8), 0, stream>>>(Wv, WTall + 1024 * 512, 512);
    wtrans<<<dim3(32, 16), dim3(32, 8), 0, stream>>>(Wd, WTall + 1536 * 512, 1024);
    wtrans<<<dim3(16, 16), dim3(32, 8), 0, stream>>>(Wo, WoT, 512);
    gemm_proj<<<dim3(20, 64), blk, 0, stream>>>(Xbf, WTall, bq, bk, bv, bd, Qbf, KbBf, VbBf, DlogBf);
    ln_ip<<<dim3(8192, 2), blk, 0, stream>>>(KbBf, VbBf, lnlg, lnlb, Kbf, Vbf);
    colsm_partial<<<dim3(4, 32, 2), blk, 0, stream>>>(DlogBf, pM, pZ);
    colsm_combine<<<8, blk, 0, stream>>>(pM, pZ, colM, colInvZ);
    kcvc_mfma<<<dim3(32, 8, 2), blk, 0, stream>>>(DlogBf, colM, colInvZ, Kbf, Vbf, partK, partV);
    kcvc_s2<<<dim3(128, 2), blk, 0, stream>>>(partK, partV, lnsg, lnsb, KcBf, VcBf);
    attn_mfma<<<dim3(64, 8, 2), blk, 0, stream>>>(Qbf, Kbf, Vbf, KcBf, VcBf, mask, Cbf);
    gemm_out<<<dim3(4, 64), blk, 0, stream>>>(Cbf, WoT, bo, (float*)d_out);
}

// Round 6
// 245.076 us; speedup vs baseline: 3.6710x; 1.0769x over previous
//
#include <hip/hip_runtime.h>
#include <hip/hip_bf16.h>

#define S_LEN 4096
#define Hn 8
#define DHn 64
#define Lc 128
#define HL 1024
#define KD 512   // inner dim of all GEMMs

typedef __attribute__((ext_vector_type(8))) short bshort8;
typedef __attribute__((ext_vector_type(4))) float f32x4;

__device__ __forceinline__ short f2bs(float f) {
    union { float f; unsigned u; } x; x.f = f;
    const unsigned r = x.u + 0x7FFFu + ((x.u >> 16) & 1u);
    return (short)(r >> 16);
}
__device__ __forceinline__ float bs2f(short s) {
    union { unsigned u; float f; } x; x.u = ((unsigned)(unsigned short)s) << 16;
    return x.f;
}

// async global(bf16 bits as short) -> LDS, 16B per lane (GEMMs only; LDS must be unpadded)
__device__ __forceinline__ void gl16(const short* g, short* l) {
    __builtin_amdgcn_global_load_lds((const __attribute__((address_space(1))) void*)g,
                                     (__attribute__((address_space(3))) void*)l, 16, 0, 0);
}

// ---------------- fused prep: X->bf16 + all weight transposes ----------------
__global__ __launch_bounds__(256) void prep_all(const float* __restrict__ X,
    const float* __restrict__ Wq, const float* __restrict__ Wk, const float* __restrict__ Wv,
    const float* __restrict__ Wd, const float* __restrict__ Wo,
    short* __restrict__ Xbf, short* __restrict__ WTall, short* __restrict__ WoT)
{
    const int t = threadIdx.x;
    int blk = blockIdx.x;
    if (blk < 2048) {
        const int i = (blk * 256 + t) * 8;
        const float4 a = *(const float4*)&X[i];
        const float4 b = *(const float4*)&X[i + 4];
        bshort8 o;
        o[0] = f2bs(a.x); o[1] = f2bs(a.y); o[2] = f2bs(a.z); o[3] = f2bs(a.w);
        o[4] = f2bs(b.x); o[5] = f2bs(b.y); o[6] = f2bs(b.z); o[7] = f2bs(b.w);
        *(bshort8*)&Xbf[i] = o;
        return;
    }
    blk -= 2048;
    const float* W; short* out; int N;
    if (blk < 256)       { W = Wq; out = WTall;              N = 512;  }
    else if (blk < 512)  { W = Wk; out = WTall + 512 * 512;  N = 512;  blk -= 256; }
    else if (blk < 768)  { W = Wv; out = WTall + 1024 * 512; N = 512;  blk -= 512; }
    else if (blk < 1280) { W = Wd; out = WTall + 1536 * 512; N = 1024; blk -= 768; }
    else                 { W = Wo; out = WoT;                N = 512;  blk -= 1280; }
    const int nb = N >> 5;
    const int n0 = (blk % nb) * 32, k0 = (blk / nb) * 32;
    __shared__ float Tl[32][33];
    const int tx = t & 31, ty = t >> 5;
#pragma unroll
    for (int i = ty; i < 32; i += 8)
        Tl[i][tx] = W[(size_t)(k0 + i) * N + n0 + tx];
    __syncthreads();
#pragma unroll
    for (int i = ty; i < 32; i += 8)
        out[(size_t)(n0 + i) * KD + k0 + tx] = f2bs(Tl[tx][i]);
}

// ---------------- fused projection GEMM (MFMA) + seg3 column-softmax partials ----------------
__global__ __launch_bounds__(256) void gemm_proj(const short* __restrict__ Xbf,
    const short* __restrict__ WT,
    const float* __restrict__ bq, const float* __restrict__ bk,
    const float* __restrict__ bv, const float* __restrict__ bd,
    short* __restrict__ Qbf, short* __restrict__ KbBf, short* __restrict__ VbBf,
    short* __restrict__ DlogBf, float* __restrict__ pM, float* __restrict__ pZ)
{
    __shared__ __align__(16) short A_s[128 * 32];
    __shared__ __align__(16) short B_s[128 * 32];
    const int t = threadIdx.x;
    const int n0 = blockIdx.x * 128, m0 = blockIdx.y * 128;
    const int lane = t & 63, wave = t >> 6;
    const int wm = wave >> 1, wn = wave & 1;
    const int quad = lane >> 4, r15 = lane & 15;
    const int eOff = t * 8;
    const int am = eOff >> 5, ak = eOff & 31;
    f32x4 acc[4][4];
#pragma unroll
    for (int i = 0; i < 4; ++i)
#pragma unroll
        for (int j = 0; j < 4; ++j) acc[i][j] = (f32x4){0.f, 0.f, 0.f, 0.f};

    for (int kk = 0; kk < KD; kk += 32) {
        gl16(&Xbf[(size_t)(m0 + am) * KD + kk + ak],      &A_s[eOff]);
        gl16(&Xbf[(size_t)(m0 + 64 + am) * KD + kk + ak], &A_s[2048 + eOff]);
        gl16(&WT[(size_t)(n0 + am) * KD + kk + ak],       &B_s[eOff]);
        gl16(&WT[(size_t)(n0 + 64 + am) * KD + kk + ak],  &B_s[2048 + eOff]);
        __syncthreads();
        bshort8 af[4], bfr[4];
#pragma unroll
        for (int i = 0; i < 4; ++i) af[i]  = *(const bshort8*)&A_s[(wm * 64 + i * 16 + r15) * 32 + quad * 8];
#pragma unroll
        for (int j = 0; j < 4; ++j) bfr[j] = *(const bshort8*)&B_s[(wn * 64 + j * 16 + r15) * 32 + quad * 8];
#pragma unroll
        for (int i = 0; i < 4; ++i)
#pragma unroll
            for (int j = 0; j < 4; ++j)
                acc[i][j] = __builtin_amdgcn_mfma_f32_16x16x32_bf16(af[i], bfr[j], acc[i][j], 0, 0, 0);
        __syncthreads();
    }
    const int seg = (n0 >= 1536) ? 3 : (n0 >> 9);   // block-uniform

    if (seg == 3) {
        // fused column-softmax partial (max + sum-exp over this block's 128 rows)
        float* cred = (float*)A_s;   // 256 floats, A_s dead after k-loop
        float bdv[4];
#pragma unroll
        for (int j = 0; j < 4; ++j) bdv[j] = bd[n0 - 1536 + wn * 64 + j * 16 + r15];
        float mj[4] = {-1e30f, -1e30f, -1e30f, -1e30f};
#pragma unroll
        for (int i = 0; i < 4; ++i)
#pragma unroll
            for (int j = 0; j < 4; ++j)
#pragma unroll
                for (int r = 0; r < 4; ++r) mj[j] = fmaxf(mj[j], acc[i][j][r] + bdv[j]);
#pragma unroll
        for (int j = 0; j < 4; ++j) {
            mj[j] = fmaxf(mj[j], __shfl_xor(mj[j], 16));
            mj[j] = fmaxf(mj[j], __shfl_xor(mj[j], 32));
        }
        if (quad == 0)
#pragma unroll
            for (int j = 0; j < 4; ++j) cred[((wm * 2 + wn) * 4 + j) * 16 + r15] = mj[j];
        __syncthreads();
        float Mc[4];
#pragma unroll
        for (int j = 0; j < 4; ++j)
            Mc[j] = fmaxf(cred[((0 * 2 + wn) * 4 + j) * 16 + r15], cred[((1 * 2 + wn) * 4 + j) * 16 + r15]);
        float zj[4] = {0.f, 0.f, 0.f, 0.f};
#pragma unroll
        for (int i = 0; i < 4; ++i)
#pragma unroll
            for (int j = 0; j < 4; ++j)
#pragma unroll
                for (int r = 0; r < 4; ++r) zj[j] += __expf(acc[i][j][r] + bdv[j] - Mc[j]);
#pragma unroll
        for (int j = 0; j < 4; ++j) {
            zj[j] += __shfl_xor(zj[j], 16);
            zj[j] += __shfl_xor(zj[j], 32);
        }
        __syncthreads();   // maxes consumed
        if (quad == 0)
#pragma unroll
            for (int j = 0; j < 4; ++j) cred[((wm * 2 + wn) * 4 + j) * 16 + r15] = zj[j];
        __syncthreads();
        if (quad == 0 && wm == 0) {
            const int bb = m0 >> 12, chunk = (m0 >> 7) & 31;
#pragma unroll
            for (int j = 0; j < 4; ++j) {
                const int cidx = n0 - 1536 + wn * 64 + j * 16 + r15;
                const float Z = cred[((0 * 2 + wn) * 4 + j) * 16 + r15] + cred[((1 * 2 + wn) * 4 + j) * 16 + r15];
                pM[((size_t)bb * HL + cidx) * 32 + chunk] = Mc[j];
                pZ[((size_t)bb * HL + cidx) * 32 + chunk] = Z;
            }
        }
    }

#pragma unroll
    for (int i = 0; i < 4; ++i)
#pragma unroll
        for (int j = 0; j < 4; ++j)
#pragma unroll
            for (int r = 0; r < 4; ++r) {
                const int gm = m0 + wm * 64 + i * 16 + quad * 4 + r;
                const int gn = n0 + wn * 64 + j * 16 + r15;
                float v = acc[i][j][r];
                if (seg == 0) {
                    v = (v + bq[gn]) * 0.125f;
                    const int bb = gm >> 12, s = gm & 4095, hh = gn >> 6, d = gn & 63;
                    Qbf[((size_t)(bb * Hn + hh) * S_LEN + s) * DHn + d] = f2bs(v);
                } else if (seg == 1) {
                    KbBf[(size_t)gm * 512 + (gn - 512)] = f2bs(v + bk[gn - 512]);
                } else if (seg == 2) {
                    VbBf[(size_t)gm * 512 + (gn - 1024)] = f2bs(v + bv[gn - 1024]);
                } else {
                    DlogBf[(size_t)gm * 1024 + (gn - 1536)] = f2bs(v + bd[gn - 1536]);
                }
            }
}

// ---------------- output GEMM (MFMA): Cbf(8192x512) @ WoT -> out f32 ----------------
__global__ __launch_bounds__(256) void gemm_out(const short* __restrict__ Abf,
    const short* __restrict__ WT, const float* __restrict__ bias, float* __restrict__ outp)
{
    __shared__ __align__(16) short A_s[128 * 32];
    __shared__ __align__(16) short B_s[128 * 32];
    const int t = threadIdx.x;
    const int n0 = blockIdx.x * 128, m0 = blockIdx.y * 128;
    const int lane = t & 63, wave = t >> 6;
    const int wm = wave >> 1, wn = wave & 1;
    const int quad = lane >> 4, r15 = lane & 15;
    const int eOff = t * 8;
    const int am = eOff >> 5, ak = eOff & 31;
    f32x4 acc[4][4];
#pragma unroll
    for (int i = 0; i < 4; ++i)
#pragma unroll
        for (int j = 0; j < 4; ++j) acc[i][j] = (f32x4){0.f, 0.f, 0.f, 0.f};

    for (int kk = 0; kk < KD; kk += 32) {
        gl16(&Abf[(size_t)(m0 + am) * KD + kk + ak],      &A_s[eOff]);
        gl16(&Abf[(size_t)(m0 + 64 + am) * KD + kk + ak], &A_s[2048 + eOff]);
        gl16(&WT[(size_t)(n0 + am) * KD + kk + ak],       &B_s[eOff]);
        gl16(&WT[(size_t)(n0 + 64 + am) * KD + kk + ak],  &B_s[2048 + eOff]);
        __syncthreads();
        bshort8 af[4], bfr[4];
#pragma unroll
        for (int i = 0; i < 4; ++i) af[i]  = *(const bshort8*)&A_s[(wm * 64 + i * 16 + r15) * 32 + quad * 8];
#pragma unroll
        for (int j = 0; j < 4; ++j) bfr[j] = *(const bshort8*)&B_s[(wn * 64 + j * 16 + r15) * 32 + quad * 8];
#pragma unroll
        for (int i = 0; i < 4; ++i)
#pragma unroll
            for (int j = 0; j < 4; ++j)
                acc[i][j] = __builtin_amdgcn_mfma_f32_16x16x32_bf16(af[i], bfr[j], acc[i][j], 0, 0, 0);
        __syncthreads();
    }
#pragma unroll
    for (int i = 0; i < 4; ++i)
#pragma unroll
        for (int j = 0; j < 4; ++j)
#pragma unroll
            for (int r = 0; r < 4; ++r) {
                const int gm = m0 + wm * 64 + i * 16 + quad * 4 + r;
                const int gn = n0 + wn * 64 + j * 16 + r15;
                outp[(size_t)gm * 512 + gn] = acc[i][j][r] + bias[gn];
            }
}

// ---------------- row LayerNorm over 512 (bf16 in, bf16 (B,H,S,DH) out) ----------------
__global__ __launch_bounds__(256) void ln_ip(const short* __restrict__ KbBf, const short* __restrict__ VbBf,
    const float* __restrict__ g, const float* __restrict__ beta,
    short* __restrict__ Kbf, short* __restrict__ Vbf)
{
    const short* src = blockIdx.y ? VbBf : KbBf;
    short* dst = blockIdx.y ? Vbf : Kbf;
    const int row = blockIdx.x, t = threadIdx.x;
    const size_t base = (size_t)row * 512;
    const float x0 = bs2f(src[base + t]);
    const float x1 = bs2f(src[base + t + 256]);
    float s = x0 + x1, ss = x0 * x0 + x1 * x1;
#pragma unroll
    for (int off = 32; off >= 1; off >>= 1) { s += __shfl_xor(s, off); ss += __shfl_xor(ss, off); }
    __shared__ float red[2][4];
    if ((t & 63) == 0) { red[0][t >> 6] = s; red[1][t >> 6] = ss; }
    __syncthreads();
    s = red[0][0] + red[0][1] + red[0][2] + red[0][3];
    ss = red[1][0] + red[1][1] + red[1][2] + red[1][3];
    const float mu = s * (1.f / 512.f);
    const float r = rsqrtf(ss * (1.f / 512.f) - mu * mu + 1e-5f);
    const int bb = row >> 12, sidx = row & 4095;
#pragma unroll
    for (int half = 0; half < 2; ++half) {
        const int c = t + half * 256;
        const float x = half ? x1 : x0;
        const float v = (x - mu) * r * g[c] + beta[c];
        dst[((size_t)(bb * Hn + (c >> 6)) * S_LEN + sidx) * DHn + (c & 63)] = f2bs(v);
    }
}

__global__ __launch_bounds__(256) void colsm_combine(const float* __restrict__ pM,
    const float* __restrict__ pZ, float* __restrict__ colM, float* __restrict__ colInvZ)
{
    const int idx = blockIdx.x * 256 + threadIdx.x;
    float M = -1e30f;
#pragma unroll
    for (int i = 0; i < 32; ++i) M = fmaxf(M, pM[(size_t)idx * 32 + i]);
    float Z = 0.f;
#pragma unroll
    for (int i = 0; i < 32; ++i) Z += pZ[(size_t)idx * 32 + i] * __expf(pM[(size_t)idx * 32 + i] - M);
    colM[idx] = M;
    colInvZ[idx] = 1.f / Z;
}

// ---------------- Kc/Vc stage 1 (MFMA, conflict-free LDS): hs @ K/V per (seg,h,b) ----------------
__global__ __launch_bounds__(256) void kcvc_mfma(const short* __restrict__ Dlog,
    const float* __restrict__ colM, const float* __restrict__ colInvZ,
    const short* __restrict__ Kbf, const short* __restrict__ Vbf,
    short* __restrict__ partK, short* __restrict__ partV)
{
    __shared__ __align__(16) short aa[128 * 72];   // [l][s], 72-pad: frag reads 2-way
    __shared__ __align__(16) short Kt[64 * 72];    // [d][s]
    __shared__ __align__(16) short Vt[64 * 72];
    __shared__ float Mh[128], iZ[128];
    const int t = threadIdx.x;
    const int seg = blockIdx.x, h = blockIdx.y, b = blockIdx.z;
    const int s0 = seg * 128;
    const size_t bh = (size_t)(b * Hn + h);
    if (t < 128) {
        Mh[t] = colM[b * HL + h * Lc + t];
        iZ[t] = colInvZ[b * HL + h * Lc + t];
    }
    const int lane = t & 63, wave = t >> 6;
    const int quad = lane >> 4, r15 = lane & 15;
    const int al = t & 127, ah = t >> 7;
    const int vj = t & 63, vd0 = (t >> 6) * 16;   // lane=j transpose: writes conflict-free
    f32x4 aK[2][4], aV[2][4];
#pragma unroll
    for (int i = 0; i < 2; ++i)
#pragma unroll
        for (int j = 0; j < 4; ++j) { aK[i][j] = (f32x4){0.f,0.f,0.f,0.f}; aV[i][j] = (f32x4){0.f,0.f,0.f,0.f}; }
    __syncthreads();   // Mh/iZ visible
    const float M = Mh[al], Z = iZ[al];

    for (int c = 0; c < 2; ++c) {
        const int sc0 = s0 + c * 64;
        if (c) __syncthreads();
#pragma unroll
        for (int gch = 0; gch < 4; ++gch) {
            bshort8 o;
#pragma unroll
            for (int j = 0; j < 8; ++j) {
                const int s = sc0 + ah * 32 + gch * 8 + j;
                o[j] = f2bs(__expf(bs2f(Dlog[((size_t)b * S_LEN + s) * HL + h * Lc + al]) - M) * Z);
            }
            *(bshort8*)&aa[al * 72 + ah * 32 + gch * 8] = o;
        }
        {
            const size_t rb = (bh * S_LEN + sc0 + vj) * DHn + vd0;
            const bshort8 k0 = *(const bshort8*)&Kbf[rb];
            const bshort8 k1 = *(const bshort8*)&Kbf[rb + 8];
            const bshort8 v0 = *(const bshort8*)&Vbf[rb];
            const bshort8 v1 = *(const bshort8*)&Vbf[rb + 8];
#pragma unroll
            for (int i = 0; i < 8; ++i) {
                Kt[(vd0 + i) * 72 + vj] = k0[i]; Kt[(vd0 + 8 + i) * 72 + vj] = k1[i];
                Vt[(vd0 + i) * 72 + vj] = v0[i]; Vt[(vd0 + 8 + i) * 72 + vj] = v1[i];
            }
        }
        __syncthreads();
#pragma unroll
        for (int ks = 0; ks < 2; ++ks) {
            const bshort8 a0 = *(const bshort8*)&aa[(wave * 32 + r15) * 72 + ks * 32 + quad * 8];
            const bshort8 a1 = *(const bshort8*)&aa[(wave * 32 + 16 + r15) * 72 + ks * 32 + quad * 8];
#pragma unroll
            for (int j = 0; j < 4; ++j) {
                const bshort8 bk = *(const bshort8*)&Kt[(j * 16 + r15) * 72 + ks * 32 + quad * 8];
                const bshort8 bv = *(const bshort8*)&Vt[(j * 16 + r15) * 72 + ks * 32 + quad * 8];
                aK[0][j] = __builtin_amdgcn_mfma_f32_16x16x32_bf16(a0, bk, aK[0][j], 0, 0, 0);
                aK[1][j] = __builtin_amdgcn_mfma_f32_16x16x32_bf16(a1, bk, aK[1][j], 0, 0, 0);
                aV[0][j] = __builtin_amdgcn_mfma_f32_16x16x32_bf16(a0, bv, aV[0][j], 0, 0, 0);
                aV[1][j] = __builtin_amdgcn_mfma_f32_16x16x32_bf16(a1, bv, aV[1][j], 0, 0, 0);
            }
        }
    }
#pragma unroll
    for (int i = 0; i < 2; ++i)
#pragma unroll
        for (int j = 0; j < 4; ++j)
#pragma unroll
            for (int r = 0; r < 4; ++r) {
                const int l = wave * 32 + i * 16 + quad * 4 + r;
                const int d = j * 16 + r15;
                const size_t o = (((size_t)(b * Lc + l)) * 32 + seg) * 512 + h * 64 + d;
                partK[o] = f2bs(aK[i][j][r]);
                partV[o] = f2bs(aV[i][j][r]);
            }
}

// ---------------- Kc/Vc stage 2: reduce chunks + LN over 512, write bf16 (B,H,L,DH) ----------------
__global__ __launch_bounds__(256) void kcvc_s2(const short* __restrict__ partK,
    const short* __restrict__ partV, const float* __restrict__ g, const float* __restrict__ beta,
    short* __restrict__ KcBf, short* __restrict__ VcBf)
{
    const int l = blockIdx.x, b = blockIdx.y, t = threadIdx.x;
    const size_t base = ((size_t)(b * Lc + l)) * 32 * 512;
    float k0 = 0.f, k1 = 0.f, v0 = 0.f, v1 = 0.f;
    for (int ch = 0; ch < 32; ++ch) {
        const size_t o = base + (size_t)ch * 512;
        k0 += bs2f(partK[o + t]);       k1 += bs2f(partK[o + t + 256]);
        v0 += bs2f(partV[o + t]);       v1 += bs2f(partV[o + t + 256]);
    }
    float sk = k0 + k1, ssk = k0 * k0 + k1 * k1;
    float sv = v0 + v1, ssv = v0 * v0 + v1 * v1;
#pragma unroll
    for (int off = 32; off >= 1; off >>= 1) {
        sk += __shfl_xor(sk, off); ssk += __shfl_xor(ssk, off);
        sv += __shfl_xor(sv, off); ssv += __shfl_xor(ssv, off);
    }
    __shared__ float red[4][4];
    if ((t & 63) == 0) {
        red[0][t >> 6] = sk; red[1][t >> 6] = ssk;
        red[2][t >> 6] = sv; red[3][t >> 6] = ssv;
    }
    __syncthreads();
    sk = red[0][0] + red[0][1] + red[0][2] + red[0][3];
    ssk = red[1][0] + red[1][1] + red[1][2] + red[1][3];
    sv = red[2][0] + red[2][1] + red[2][2] + red[2][3];
    ssv = red[3][0] + red[3][1] + red[3][2] + red[3][3];
    const float muK = sk * (1.f / 512.f);
    const float rK = rsqrtf(ssk * (1.f / 512.f) - muK * muK + 1e-5f);
    const float muV = sv * (1.f / 512.f);
    const float rV = rsqrtf(ssv * (1.f / 512.f) - muV * muV + 1e-5f);
#pragma unroll
    for (int half = 0; half < 2; ++half) {
        const int c = t + half * 256;
        const float xk = half ? k1 : k0;
        const float xv = half ? v1 : v0;
        const size_t o = ((size_t)(b * Hn + (c >> 6)) * Lc + l) * DHn + (c & 63);
        KcBf[o] = f2bs((xk - muK) * rK * g[c] + beta[c]);
        VcBf[o] = f2bs((xv - muV) * rV * g[c] + beta[c]);
    }
}

// ---------------- MFMA flash attention (72-pad conflict-free LDS) ----------------
__global__ __launch_bounds__(256) void attn_mfma(
    const short* __restrict__ Qbf, const short* __restrict__ Kbf, const short* __restrict__ Vbf,
    const short* __restrict__ KcBf, const short* __restrict__ VcBf,
    const int* __restrict__ mask, short* __restrict__ C)
{
    __shared__ __align__(16) short Q_l[64 * 72];   // [q][d]
    __shared__ __align__(16) short K_l[64 * 72];   // [j][d]
    __shared__ __align__(16) short Vt_l[64 * 72];  // [d][j]
    __shared__ __align__(16) short P_l[64 * 72];   // [q][j]
    __shared__ float vb[64];
    const int t = threadIdx.x;
    const int qt = blockIdx.x, h = blockIdx.y, b = blockIdx.z;
    const int q0 = qt * 64, gg = qt >> 1;
    const size_t bh = (size_t)(b * Hn + h);
    const int lane = t & 63, wave = t >> 6;
    const int quad = lane >> 4, r15 = lane & 15;
    const int sr = t >> 2, sc = (t & 3) * 16;      // padded staging for Q/K
    const int vj = t & 63, vd0 = (t >> 6) * 16;    // lane=j V transpose

    {
        const size_t gq = (bh * S_LEN + q0 + sr) * DHn + sc;
        const bshort8 a = *(const bshort8*)&Qbf[gq];
        const bshort8 b8 = *(const bshort8*)&Qbf[gq + 8];
        *(bshort8*)&Q_l[sr * 72 + sc] = a;
        *(bshort8*)&Q_l[sr * 72 + sc + 8] = b8;
    }
    f32x4 o[4];
#pragma unroll
    for (int df = 0; df < 4; ++df) o[df] = (f32x4){0.f, 0.f, 0.f, 0.f};
    float mrow[4] = {-1e30f, -1e30f, -1e30f, -1e30f};
    float lrow[4] = {0.f, 0.f, 0.f, 0.f};

    for (int cc = 0; cc < 6; ++cc) {
        const short* ksrc; const short* vsrc;
        int sk0 = 0;
        if (cc < 2) {
            ksrc = &KcBf[(bh * Lc + cc * 64) * DHn];
            vsrc = &VcBf[(bh * Lc + cc * 64) * DHn];
        } else {
            sk0 = gg * 128 - 64 + (cc - 2) * 64;
            if (sk0 < 0 || sk0 >= S_LEN) continue;   // 64-aligned: fully OOB -> skip (block-uniform)
            ksrc = &Kbf[(bh * S_LEN + sk0) * DHn];
            vsrc = &Vbf[(bh * S_LEN + sk0) * DHn];
        }
        __syncthreads();   // prev chunk's LDS reads done (also covers Q staging on cc==0)
        if (t < 64) {
            float v = 0.f;
            if (cc >= 2 && mask[b * S_LEN + sk0 + t] == 0) v = -1e30f;
            vb[t] = v;
        }
        {
            const bshort8 a = *(const bshort8*)&ksrc[sr * 64 + sc];
            const bshort8 b8 = *(const bshort8*)&ksrc[sr * 64 + sc + 8];
            *(bshort8*)&K_l[sr * 72 + sc] = a;
            *(bshort8*)&K_l[sr * 72 + sc + 8] = b8;
        }
        {
            const bshort8 v0 = *(const bshort8*)&vsrc[vj * 64 + vd0];
            const bshort8 v1 = *(const bshort8*)&vsrc[vj * 64 + vd0 + 8];
#pragma unroll
            for (int i = 0; i < 8; ++i) {
                Vt_l[(vd0 + i) * 72 + vj] = v0[i];
                Vt_l[(vd0 + 8 + i) * 72 + vj] = v1[i];
            }
        }
        __syncthreads();
        f32x4 c[4];
#pragma unroll
        for (int jf = 0; jf < 4; ++jf) c[jf] = (f32x4){0.f, 0.f, 0.f, 0.f};
#pragma unroll
        for (int ks = 0; ks < 2; ++ks) {
            const bshort8 aq = *(const bshort8*)&Q_l[(wave * 16 + r15) * 72 + ks * 32 + quad * 8];
#pragma unroll
            for (int jf = 0; jf < 4; ++jf) {
                const bshort8 bk = *(const bshort8*)&K_l[(jf * 16 + r15) * 72 + ks * 32 + quad * 8];
                c[jf] = __builtin_amdgcn_mfma_f32_16x16x32_bf16(aq, bk, c[jf], 0, 0, 0);
            }
        }
        float vbl[4];
#pragma unroll
        for (int jf = 0; jf < 4; ++jf) vbl[jf] = vb[jf * 16 + r15];
        float sc4[4][4];
#pragma unroll
        for (int jf = 0; jf < 4; ++jf)
#pragma unroll
            for (int r = 0; r < 4; ++r) sc4[jf][r] = c[jf][r] + vbl[jf];
        float mx[4];
#pragma unroll
        for (int r = 0; r < 4; ++r)
            mx[r] = fmaxf(fmaxf(sc4[0][r], sc4[1][r]), fmaxf(sc4[2][r], sc4[3][r]));
#pragma unroll
        for (int off = 1; off <= 8; off <<= 1)
#pragma unroll
            for (int r = 0; r < 4; ++r) mx[r] = fmaxf(mx[r], __shfl_xor(mx[r], off));
        float alpha[4];
#pragma unroll
        for (int r = 0; r < 4; ++r) {
            const float mn = fmaxf(mrow[r], mx[r]);
            alpha[r] = __expf(mrow[r] - mn);
            mrow[r] = mn;
        }
        float sum[4] = {0.f, 0.f, 0.f, 0.f};
#pragma unroll
        for (int jf = 0; jf < 4; ++jf)
#pragma unroll
            for (int r = 0; r < 4; ++r) {
                const float p = __expf(sc4[jf][r] - mrow[r]);
                sum[r] += p;
                P_l[(wave * 16 + quad * 4 + r) * 72 + jf * 16 + r15] = f2bs(p);
            }
#pragma unroll
        for (int off = 1; off <= 8; off <<= 1)
#pragma unroll
            for (int r = 0; r < 4; ++r) sum[r] += __shfl_xor(sum[r], off);
#pragma unroll
        for (int r = 0; r < 4; ++r) lrow[r] = lrow[r] * alpha[r] + sum[r];
#pragma unroll
        for (int df = 0; df < 4; ++df)
#pragma unroll
            for (int r = 0; r < 4; ++r) o[df][r] *= alpha[r];
        // PV: A-frags from own wave's P rows (same-wave LDS); Vt synced above
#pragma unroll
        for (int ks = 0; ks < 2; ++ks) {
            const bshort8 ap = *(const bshort8*)&P_l[(wave * 16 + r15) * 72 + ks * 32 + quad * 8];
#pragma unroll
            for (int df = 0; df < 4; ++df) {
                const bshort8 bv = *(const bshort8*)&Vt_l[(df * 16 + r15) * 72 + ks * 32 + quad * 8];
                o[df] = __builtin_amdgcn_mfma_f32_16x16x32_bf16(ap, bv, o[df], 0, 0, 0);
            }
        }
    }
#pragma unroll
    for (int r = 0; r < 4; ++r) {
        const int q = q0 + wave * 16 + quad * 4 + r;
        const float rl = (mask[b * S_LEN + q] == 0) ? 0.f : (1.f / lrow[r]);
        const size_t ob = ((size_t)b * S_LEN + q) * 512 + h * 64;
#pragma unroll
        for (int df = 0; df < 4; ++df)
            C[ob + df * 16 + r15] = f2bs(o[df][r] * rl);
    }
}

extern "C" void kernel_launch(void* const* d_in, const int* in_sizes, int n_in,
                              void* d_out, int out_size, void* d_ws, size_t ws_size,
                              hipStream_t stream) {
    (void)in_sizes; (void)n_in; (void)out_size; (void)ws_size;
    const float* X    = (const float*)d_in[0];
    const int*   mask = (const int*)d_in[1];
    const float* Wq = (const float*)d_in[2];  const float* bq = (const float*)d_in[3];
    const float* Wk = (const float*)d_in[4];  const float* bk = (const float*)d_in[5];
    const float* Wv = (const float*)d_in[6];  const float* bv = (const float*)d_in[7];
    const float* Wo = (const float*)d_in[8];  const float* bo = (const float*)d_in[9];
    const float* lnlg = (const float*)d_in[10]; const float* lnlb = (const float*)d_in[11];
    const float* lnsg = (const float*)d_in[12]; const float* lnsb = (const float*)d_in[13];
    const float* Wd = (const float*)d_in[14]; const float* bd = (const float*)d_in[15];

    short* sw = (short*)d_ws;
    short* Qbf    = sw;                        // 4,194,304 bf16 (B,H,S,DH), pre-scaled
    short* Kbf    = Qbf + 4194304;             // 4,194,304 bf16 (B,H,S,DH), LN'd
    short* Vbf    = Kbf + 4194304;             // 4,194,304 bf16 (B,H,S,DH), LN'd
    short* KbBf   = Vbf + 4194304;             // 4,194,304 bf16 row-major pre-LN K
    short* VbBf   = KbBf + 4194304;            // 4,194,304 bf16 row-major pre-LN V
    short* DlogBf = VbBf + 4194304;            // 8,388,608 bf16
    short* Xbf    = DlogBf + 8388608;          // 4,194,304 bf16 (reused: partK, then Cbf)
    short* WTall  = Xbf + 4194304;             // 1,310,720 bf16
    short* WoT    = WTall + 1310720;           // 262,144 bf16
    short* KcBf   = WoT + 262144;              // 131,072 bf16 (B,H,L,DH)
    short* VcBf   = KcBf + 131072;             // 131,072 bf16
    short* partV  = VcBf + 131072;             // 4,194,304 bf16
    float* pM     = (float*)(partV + 4194304); // 65,536 f32
    float* pZ     = pM + 65536;                // 65,536
    float* colM   = pZ + 65536;                // 2,048
    float* colInvZ= colM + 2048;               // 2,048
    short* partK  = Xbf;                       // reuse (Xbf dead after gemm_proj)
    short* Cbf    = Xbf;                       // reuse (partK dead after kcvc_s2)
    // total ≈ 79.7 MB

    const dim3 blk(256);
    prep_all<<<3584, blk, 0, stream>>>(X, Wq, Wk, Wv, Wd, Wo, Xbf, WTall, WoT);
    gemm_proj<<<dim3(20, 64), blk, 0, stream>>>(Xbf, WTall, bq, bk, bv, bd, Qbf, KbBf, VbBf, DlogBf, pM, pZ);
    ln_ip<<<dim3(8192, 2), blk, 0, stream>>>(KbBf, VbBf, lnlg, lnlb, Kbf, Vbf);
    colsm_combine<<<8, blk, 0, stream>>>(pM, pZ, colM, colInvZ);
    kcvc_mfma<<<dim3(32, 8, 2), blk, 0, stream>>>(DlogBf, colM, colInvZ, Kbf, Vbf, partK, partV);
    kcvc_s2<<<dim3(128, 2), blk, 0, stream>>>(partK, partV, lnsg, lnsb, KcBf, VcBf);
    attn_mfma<<<dim3(64, 8, 2), blk, 0, stream>>>(Qbf, Kbf, Vbf, KcBf, VcBf, mask, Cbf);
    gemm_out<<<dim3(4, 64), blk, 0, stream>>>(Cbf, WoT, bo, (float*)d_out);
}

// Round 7
// 239.057 us; speedup vs baseline: 3.7634x; 1.0252x over previous
//
#include <hip/hip_runtime.h>
#include <hip/hip_bf16.h>

#define S_LEN 4096
#define Hn 8
#define DHn 64
#define Lc 128
#define HL 1024
#define KD 512   // inner dim of all GEMMs

typedef __attribute__((ext_vector_type(8))) short bshort8;
typedef __attribute__((ext_vector_type(4))) float f32x4;

__device__ __forceinline__ short f2bs(float f) {
    union { float f; unsigned u; } x; x.f = f;
    const unsigned r = x.u + 0x7FFFu + ((x.u >> 16) & 1u);
    return (short)(r >> 16);
}
__device__ __forceinline__ float bs2f(short s) {
    union { unsigned u; float f; } x; x.u = ((unsigned)(unsigned short)s) << 16;
    return x.f;
}

// async global(bf16 bits as short) -> LDS, 16B per lane (GEMMs only; LDS must be unpadded)
__device__ __forceinline__ void gl16(const short* g, short* l) {
    __builtin_amdgcn_global_load_lds((const __attribute__((address_space(1))) void*)g,
                                     (__attribute__((address_space(3))) void*)l, 16, 0, 0);
}

// ---------------- fused prep: X->bf16 + all weight transposes + colZ zero ----------------
__global__ __launch_bounds__(256) void prep_all(const float* __restrict__ X,
    const float* __restrict__ Wq, const float* __restrict__ Wk, const float* __restrict__ Wv,
    const float* __restrict__ Wd, const float* __restrict__ Wo,
    short* __restrict__ Xbf, short* __restrict__ WTall, short* __restrict__ WoT,
    float* __restrict__ colZ)
{
    const int t = threadIdx.x;
    int blk = blockIdx.x;
    if (blk < 2048) {
        const int i = (blk * 256 + t) * 8;
        const float4 a = *(const float4*)&X[i];
        const float4 b = *(const float4*)&X[i + 4];
        bshort8 o;
        o[0] = f2bs(a.x); o[1] = f2bs(a.y); o[2] = f2bs(a.z); o[3] = f2bs(a.w);
        o[4] = f2bs(b.x); o[5] = f2bs(b.y); o[6] = f2bs(b.z); o[7] = f2bs(b.w);
        *(bshort8*)&Xbf[i] = o;
        return;
    }
    blk -= 2048;
    if (blk == 1536) {   // zero colZ (2048 floats)
        ((float4*)colZ)[t * 2] = make_float4(0.f, 0.f, 0.f, 0.f);
        ((float4*)colZ)[t * 2 + 1] = make_float4(0.f, 0.f, 0.f, 0.f);
        return;
    }
    const float* W; short* out; int N;
    if (blk < 256)       { W = Wq; out = WTall;              N = 512;  }
    else if (blk < 512)  { W = Wk; out = WTall + 512 * 512;  N = 512;  blk -= 256; }
    else if (blk < 768)  { W = Wv; out = WTall + 1024 * 512; N = 512;  blk -= 512; }
    else if (blk < 1280) { W = Wd; out = WTall + 1536 * 512; N = 1024; blk -= 768; }
    else                 { W = Wo; out = WoT;                N = 512;  blk -= 1280; }
    const int nb = N >> 5;
    const int n0 = (blk % nb) * 32, k0 = (blk / nb) * 32;
    __shared__ float Tl[32][33];
    const int tx = t & 31, ty = t >> 5;
#pragma unroll
    for (int i = ty; i < 32; i += 8)
        Tl[i][tx] = W[(size_t)(k0 + i) * N + n0 + tx];
    __syncthreads();
#pragma unroll
    for (int i = ty; i < 32; i += 8)
        out[(size_t)(n0 + i) * KD + k0 + tx] = f2bs(Tl[tx][i]);
}

// ---------------- fused projection GEMM (MFMA): X(8192x512) @ [Wq|Wk|Wv|Wd] ----------------
// (round-5 body: VGPR 84, no softmax fusion — round 6 showed fusion costs occupancy)
__global__ __launch_bounds__(256) void gemm_proj(const short* __restrict__ Xbf,
    const short* __restrict__ WT,
    const float* __restrict__ bq, const float* __restrict__ bk,
    const float* __restrict__ bv, const float* __restrict__ bd,
    short* __restrict__ Qbf, short* __restrict__ KbBf, short* __restrict__ VbBf,
    short* __restrict__ DlogBf)
{
    __shared__ __align__(16) short A_s[128 * 32];
    __shared__ __align__(16) short B_s[128 * 32];
    const int t = threadIdx.x;
    const int n0 = blockIdx.x * 128, m0 = blockIdx.y * 128;
    const int lane = t & 63, wave = t >> 6;
    const int wm = wave >> 1, wn = wave & 1;
    const int quad = lane >> 4, r15 = lane & 15;
    const int eOff = t * 8;
    const int am = eOff >> 5, ak = eOff & 31;
    f32x4 acc[4][4];
#pragma unroll
    for (int i = 0; i < 4; ++i)
#pragma unroll
        for (int j = 0; j < 4; ++j) acc[i][j] = (f32x4){0.f, 0.f, 0.f, 0.f};

    for (int kk = 0; kk < KD; kk += 32) {
        gl16(&Xbf[(size_t)(m0 + am) * KD + kk + ak],      &A_s[eOff]);
        gl16(&Xbf[(size_t)(m0 + 64 + am) * KD + kk + ak], &A_s[2048 + eOff]);
        gl16(&WT[(size_t)(n0 + am) * KD + kk + ak],       &B_s[eOff]);
        gl16(&WT[(size_t)(n0 + 64 + am) * KD + kk + ak],  &B_s[2048 + eOff]);
        __syncthreads();
        bshort8 af[4], bfr[4];
#pragma unroll
        for (int i = 0; i < 4; ++i) af[i]  = *(const bshort8*)&A_s[(wm * 64 + i * 16 + r15) * 32 + quad * 8];
#pragma unroll
        for (int j = 0; j < 4; ++j) bfr[j] = *(const bshort8*)&B_s[(wn * 64 + j * 16 + r15) * 32 + quad * 8];
#pragma unroll
        for (int i = 0; i < 4; ++i)
#pragma unroll
            for (int j = 0; j < 4; ++j)
                acc[i][j] = __builtin_amdgcn_mfma_f32_16x16x32_bf16(af[i], bfr[j], acc[i][j], 0, 0, 0);
        __syncthreads();
    }
    const int seg = (n0 >= 1536) ? 3 : (n0 >> 9);   // block-uniform
#pragma unroll
    for (int i = 0; i < 4; ++i)
#pragma unroll
        for (int j = 0; j < 4; ++j)
#pragma unroll
            for (int r = 0; r < 4; ++r) {
                const int gm = m0 + wm * 64 + i * 16 + quad * 4 + r;
                const int gn = n0 + wn * 64 + j * 16 + r15;
                float v = acc[i][j][r];
                if (seg == 0) {
                    v = (v + bq[gn]) * 0.125f;
                    const int bb = gm >> 12, s = gm & 4095, hh = gn >> 6, d = gn & 63;
                    Qbf[((size_t)(bb * Hn + hh) * S_LEN + s) * DHn + d] = f2bs(v);
                } else if (seg == 1) {
                    KbBf[(size_t)gm * 512 + (gn - 512)] = f2bs(v + bk[gn - 512]);
                } else if (seg == 2) {
                    VbBf[(size_t)gm * 512 + (gn - 1024)] = f2bs(v + bv[gn - 1024]);
                } else {
                    DlogBf[(size_t)gm * 1024 + (gn - 1536)] = f2bs(v + bd[gn - 1536]);
                }
            }
}

// ---------------- output GEMM (MFMA): 64x64 tiles, 1024 blocks for latency hiding ----------------
__global__ __launch_bounds__(256) void gemm_out(const short* __restrict__ Abf,
    const short* __restrict__ WT, const float* __restrict__ bias, float* __restrict__ outp)
{
    __shared__ __align__(16) short A_s[64 * 32];
    __shared__ __align__(16) short B_s[64 * 32];
    const int t = threadIdx.x;
    const int n0 = blockIdx.x * 64, m0 = blockIdx.y * 64;
    const int lane = t & 63, wave = t >> 6;
    const int quad = lane >> 4, r15 = lane & 15;
    const int eOff = t * 8;
    const int am = eOff >> 5, ak = eOff & 31;
    f32x4 acc[4];
#pragma unroll
    for (int j = 0; j < 4; ++j) acc[j] = (f32x4){0.f, 0.f, 0.f, 0.f};

    for (int kk = 0; kk < KD; kk += 32) {
        gl16(&Abf[(size_t)(m0 + am) * KD + kk + ak], &A_s[eOff]);
        gl16(&WT[(size_t)(n0 + am) * KD + kk + ak],  &B_s[eOff]);
        __syncthreads();
        const bshort8 af = *(const bshort8*)&A_s[(wave * 16 + r15) * 32 + quad * 8];
#pragma unroll
        for (int j = 0; j < 4; ++j) {
            const bshort8 bfr = *(const bshort8*)&B_s[(j * 16 + r15) * 32 + quad * 8];
            acc[j] = __builtin_amdgcn_mfma_f32_16x16x32_bf16(af, bfr, acc[j], 0, 0, 0);
        }
        __syncthreads();
    }
#pragma unroll
    for (int j = 0; j < 4; ++j)
#pragma unroll
        for (int r = 0; r < 4; ++r) {
            const int gm = m0 + wave * 16 + quad * 4 + r;
            const int gn = n0 + j * 16 + r15;
            outp[(size_t)gm * 512 + gn] = acc[j][r] + bias[gn];
        }
}

// ---------------- row LayerNorm over 512 (bf16 in, bf16 (B,H,S,DH) out) ----------------
__global__ __launch_bounds__(256) void ln_ip(const short* __restrict__ KbBf, const short* __restrict__ VbBf,
    const float* __restrict__ g, const float* __restrict__ beta,
    short* __restrict__ Kbf, short* __restrict__ Vbf)
{
    const short* src = blockIdx.y ? VbBf : KbBf;
    short* dst = blockIdx.y ? Vbf : Kbf;
    const int row = blockIdx.x, t = threadIdx.x;
    const size_t base = (size_t)row * 512;
    const float x0 = bs2f(src[base + t]);
    const float x1 = bs2f(src[base + t + 256]);
    float s = x0 + x1, ss = x0 * x0 + x1 * x1;
#pragma unroll
    for (int off = 32; off >= 1; off >>= 1) { s += __shfl_xor(s, off); ss += __shfl_xor(ss, off); }
    __shared__ float red[2][4];
    if ((t & 63) == 0) { red[0][t >> 6] = s; red[1][t >> 6] = ss; }
    __syncthreads();
    s = red[0][0] + red[0][1] + red[0][2] + red[0][3];
    ss = red[1][0] + red[1][1] + red[1][2] + red[1][3];
    const float mu = s * (1.f / 512.f);
    const float r = rsqrtf(ss * (1.f / 512.f) - mu * mu + 1e-5f);
    const int bb = row >> 12, sidx = row & 4095;
#pragma unroll
    for (int half = 0; half < 2; ++half) {
        const int c = t + half * 256;
        const float x = half ? x1 : x0;
        const float v = (x - mu) * r * g[c] + beta[c];
        dst[((size_t)(bb * Hn + (c >> 6)) * S_LEN + sidx) * DHn + (c & 63)] = f2bs(v);
    }
}

// ---------------- column sum-exp over S (no max: logits ~N(0,1), shift-invariant) ----------------
__global__ __launch_bounds__(256) void colsum(const short* __restrict__ Dlog, float* __restrict__ colZ)
{
    const int t = threadIdx.x;
    const int cidx = blockIdx.x * 256 + t;
    const int chunk = blockIdx.y, b = blockIdx.z;
    const int s0 = chunk * 128;
    float z = 0.f;
#pragma unroll 4
    for (int s = 0; s < 128; ++s)
        z += __expf(bs2f(Dlog[((size_t)b * S_LEN + s0 + s) * HL + cidx]));
    atomicAdd(&colZ[b * HL + cidx], z);
}

// ---------------- Kc/Vc stage 1 (MFMA, conflict-free LDS): hs @ K/V per (seg,h,b) ----------------
__global__ __launch_bounds__(256) void kcvc_mfma(const short* __restrict__ Dlog,
    const float* __restrict__ colZ,
    const short* __restrict__ Kbf, const short* __restrict__ Vbf,
    short* __restrict__ partK, short* __restrict__ partV)
{
    __shared__ __align__(16) short aa[128 * 72];   // [l][s], 72-pad: frag reads 2-way
    __shared__ __align__(16) short Kt[64 * 72];    // [d][s]
    __shared__ __align__(16) short Vt[64 * 72];
    __shared__ float iZ[128];
    const int t = threadIdx.x;
    const int seg = blockIdx.x, h = blockIdx.y, b = blockIdx.z;
    const int s0 = seg * 128;
    const size_t bh = (size_t)(b * Hn + h);
    if (t < 128) iZ[t] = 1.f / colZ[b * HL + h * Lc + t];
    const int lane = t & 63, wave = t >> 6;
    const int quad = lane >> 4, r15 = lane & 15;
    const int al = t & 127, ah = t >> 7;
    const int vj = t & 63, vd0 = (t >> 6) * 16;   // lane=j transpose: writes conflict-free
    f32x4 aK[2][4], aV[2][4];
#pragma unroll
    for (int i = 0; i < 2; ++i)
#pragma unroll
        for (int j = 0; j < 4; ++j) { aK[i][j] = (f32x4){0.f,0.f,0.f,0.f}; aV[i][j] = (f32x4){0.f,0.f,0.f,0.f}; }
    __syncthreads();   // iZ visible
    const float Z = iZ[al];

    for (int c = 0; c < 2; ++c) {
        const int sc0 = s0 + c * 64;
        if (c) __syncthreads();
#pragma unroll
        for (int gch = 0; gch < 4; ++gch) {
            bshort8 o;
#pragma unroll
            for (int j = 0; j < 8; ++j) {
                const int s = sc0 + ah * 32 + gch * 8 + j;
                o[j] = f2bs(__expf(bs2f(Dlog[((size_t)b * S_LEN + s) * HL + h * Lc + al])) * Z);
            }
            *(bshort8*)&aa[al * 72 + ah * 32 + gch * 8] = o;
        }
        {
            const size_t rb = (bh * S_LEN + sc0 + vj) * DHn + vd0;
            const bshort8 k0 = *(const bshort8*)&Kbf[rb];
            const bshort8 k1 = *(const bshort8*)&Kbf[rb + 8];
            const bshort8 v0 = *(const bshort8*)&Vbf[rb];
            const bshort8 v1 = *(const bshort8*)&Vbf[rb + 8];
#pragma unroll
            for (int i = 0; i < 8; ++i) {
                Kt[(vd0 + i) * 72 + vj] = k0[i]; Kt[(vd0 + 8 + i) * 72 + vj] = k1[i];
                Vt[(vd0 + i) * 72 + vj] = v0[i]; Vt[(vd0 + 8 + i) * 72 + vj] = v1[i];
            }
        }
        __syncthreads();
#pragma unroll
        for (int ks = 0; ks < 2; ++ks) {
            const bshort8 a0 = *(const bshort8*)&aa[(wave * 32 + r15) * 72 + ks * 32 + quad * 8];
            const bshort8 a1 = *(const bshort8*)&aa[(wave * 32 + 16 + r15) * 72 + ks * 32 + quad * 8];
#pragma unroll
            for (int j = 0; j < 4; ++j) {
                const bshort8 bk = *(const bshort8*)&Kt[(j * 16 + r15) * 72 + ks * 32 + quad * 8];
                const bshort8 bv = *(const bshort8*)&Vt[(j * 16 + r15) * 72 + ks * 32 + quad * 8];
                aK[0][j] = __builtin_amdgcn_mfma_f32_16x16x32_bf16(a0, bk, aK[0][j], 0, 0, 0);
                aK[1][j] = __builtin_amdgcn_mfma_f32_16x16x32_bf16(a1, bk, aK[1][j], 0, 0, 0);
                aV[0][j] = __builtin_amdgcn_mfma_f32_16x16x32_bf16(a0, bv, aV[0][j], 0, 0, 0);
                aV[1][j] = __builtin_amdgcn_mfma_f32_16x16x32_bf16(a1, bv, aV[1][j], 0, 0, 0);
            }
        }
    }
#pragma unroll
    for (int i = 0; i < 2; ++i)
#pragma unroll
        for (int j = 0; j < 4; ++j)
#pragma unroll
            for (int r = 0; r < 4; ++r) {
                const int l = wave * 32 + i * 16 + quad * 4 + r;
                const int d = j * 16 + r15;
                const size_t o = (((size_t)(b * Lc + l)) * 32 + seg) * 512 + h * 64 + d;
                partK[o] = f2bs(aK[i][j][r]);
                partV[o] = f2bs(aV[i][j][r]);
            }
}

// ---------------- Kc/Vc stage 2: reduce chunks + LN over 512, write bf16 (B,H,L,DH) ----------------
__global__ __launch_bounds__(256) void kcvc_s2(const short* __restrict__ partK,
    const short* __restrict__ partV, const float* __restrict__ g, const float* __restrict__ beta,
    short* __restrict__ KcBf, short* __restrict__ VcBf)
{
    const int l = blockIdx.x, b = blockIdx.y, t = threadIdx.x;
    const size_t base = ((size_t)(b * Lc + l)) * 32 * 512;
    float k0 = 0.f, k1 = 0.f, v0 = 0.f, v1 = 0.f;
    for (int ch = 0; ch < 32; ++ch) {
        const size_t o = base + (size_t)ch * 512;
        k0 += bs2f(partK[o + t]);       k1 += bs2f(partK[o + t + 256]);
        v0 += bs2f(partV[o + t]);       v1 += bs2f(partV[o + t + 256]);
    }
    float sk = k0 + k1, ssk = k0 * k0 + k1 * k1;
    float sv = v0 + v1, ssv = v0 * v0 + v1 * v1;
#pragma unroll
    for (int off = 32; off >= 1; off >>= 1) {
        sk += __shfl_xor(sk, off); ssk += __shfl_xor(ssk, off);
        sv += __shfl_xor(sv, off); ssv += __shfl_xor(ssv, off);
    }
    __shared__ float red[4][4];
    if ((t & 63) == 0) {
        red[0][t >> 6] = sk; red[1][t >> 6] = ssk;
        red[2][t >> 6] = sv; red[3][t >> 6] = ssv;
    }
    __syncthreads();
    sk = red[0][0] + red[0][1] + red[0][2] + red[0][3];
    ssk = red[1][0] + red[1][1] + red[1][2] + red[1][3];
    sv = red[2][0] + red[2][1] + red[2][2] + red[2][3];
    ssv = red[3][0] + red[3][1] + red[3][2] + red[3][3];
    const float muK = sk * (1.f / 512.f);
    const float rK = rsqrtf(ssk * (1.f / 512.f) - muK * muK + 1e-5f);
    const float muV = sv * (1.f / 512.f);
    const float rV = rsqrtf(ssv * (1.f / 512.f) - muV * muV + 1e-5f);
#pragma unroll
    for (int half = 0; half < 2; ++half) {
        const int c = t + half * 256;
        const float xk = half ? k1 : k0;
        const float xv = half ? v1 : v0;
        const size_t o = ((size_t)(b * Hn + (c >> 6)) * Lc + l) * DHn + (c & 63);
        KcBf[o] = f2bs((xk - muK) * rK * g[c] + beta[c]);
        VcBf[o] = f2bs((xv - muV) * rV * g[c] + beta[c]);
    }
}

// ---------------- MFMA flash attention (72-pad conflict-free LDS) ----------------
__global__ __launch_bounds__(256) void attn_mfma(
    const short* __restrict__ Qbf, const short* __restrict__ Kbf, const short* __restrict__ Vbf,
    const short* __restrict__ KcBf, const short* __restrict__ VcBf,
    const int* __restrict__ mask, short* __restrict__ C)
{
    __shared__ __align__(16) short Q_l[64 * 72];   // [q][d]
    __shared__ __align__(16) short K_l[64 * 72];   // [j][d]
    __shared__ __align__(16) short Vt_l[64 * 72];  // [d][j]
    __shared__ __align__(16) short P_l[64 * 72];   // [q][j]
    __shared__ float vb[64];
    const int t = threadIdx.x;
    const int qt = blockIdx.x, h = blockIdx.y, b = blockIdx.z;
    const int q0 = qt * 64, gg = qt >> 1;
    const size_t bh = (size_t)(b * Hn + h);
    const int lane = t & 63, wave = t >> 6;
    const int quad = lane >> 4, r15 = lane & 15;
    const int sr = t >> 2, sc = (t & 3) * 16;      // padded staging for Q/K
    const int vj = t & 63, vd0 = (t >> 6) * 16;    // lane=j V transpose

    {
        const size_t gq = (bh * S_LEN + q0 + sr) * DHn + sc;
        const bshort8 a = *(const bshort8*)&Qbf[gq];
        const bshort8 b8 = *(const bshort8*)&Qbf[gq + 8];
        *(bshort8*)&Q_l[sr * 72 + sc] = a;
        *(bshort8*)&Q_l[sr * 72 + sc + 8] = b8;
    }
    f32x4 o[4];
#pragma unroll
    for (int df = 0; df < 4; ++df) o[df] = (f32x4){0.f, 0.f, 0.f, 0.f};
    float mrow[4] = {-1e30f, -1e30f, -1e30f, -1e30f};
    float lrow[4] = {0.f, 0.f, 0.f, 0.f};

    for (int cc = 0; cc < 6; ++cc) {
        const short* ksrc; const short* vsrc;
        int sk0 = 0;
        if (cc < 2) {
            ksrc = &KcBf[(bh * Lc + cc * 64) * DHn];
            vsrc = &VcBf[(bh * Lc + cc * 64) * DHn];
        } else {
            sk0 = gg * 128 - 64 + (cc - 2) * 64;
            if (sk0 < 0 || sk0 >= S_LEN) continue;   // 64-aligned: fully OOB -> skip (block-uniform)
            ksrc = &Kbf[(bh * S_LEN + sk0) * DHn];
            vsrc = &Vbf[(bh * S_LEN + sk0) * DHn];
        }
        __syncthreads();   // prev chunk's LDS reads done (also covers Q staging on cc==0)
        if (t < 64) {
            float v = 0.f;
            if (cc >= 2 && mask[b * S_LEN + sk0 + t] == 0) v = -1e30f;
            vb[t] = v;
        }
        {
            const bshort8 a = *(const bshort8*)&ksrc[sr * 64 + sc];
            const bshort8 b8 = *(const bshort8*)&ksrc[sr * 64 + sc + 8];
            *(bshort8*)&K_l[sr * 72 + sc] = a;
            *(bshort8*)&K_l[sr * 72 + sc + 8] = b8;
        }
        {
            const bshort8 v0 = *(const bshort8*)&vsrc[vj * 64 + vd0];
            const bshort8 v1 = *(const bshort8*)&vsrc[vj * 64 + vd0 + 8];
#pragma unroll
            for (int i = 0; i < 8; ++i) {
                Vt_l[(vd0 + i) * 72 + vj] = v0[i];
                Vt_l[(vd0 + 8 + i) * 72 + vj] = v1[i];
            }
        }
        __syncthreads();
        f32x4 c[4];
#pragma unroll
        for (int jf = 0; jf < 4; ++jf) c[jf] = (f32x4){0.f, 0.f, 0.f, 0.f};
#pragma unroll
        for (int ks = 0; ks < 2; ++ks) {
            const bshort8 aq = *(const bshort8*)&Q_l[(wave * 16 + r15) * 72 + ks * 32 + quad * 8];
#pragma unroll
            for (int jf = 0; jf < 4; ++jf) {
                const bshort8 bk = *(const bshort8*)&K_l[(jf * 16 + r15) * 72 + ks * 32 + quad * 8];
                c[jf] = __builtin_amdgcn_mfma_f32_16x16x32_bf16(aq, bk, c[jf], 0, 0, 0);
            }
        }
        float vbl[4];
#pragma unroll
        for (int jf = 0; jf < 4; ++jf) vbl[jf] = vb[jf * 16 + r15];
        float sc4[4][4];
#pragma unroll
        for (int jf = 0; jf < 4; ++jf)
#pragma unroll
            for (int r = 0; r < 4; ++r) sc4[jf][r] = c[jf][r] + vbl[jf];
        float mx[4];
#pragma unroll
        for (int r = 0; r < 4; ++r)
            mx[r] = fmaxf(fmaxf(sc4[0][r], sc4[1][r]), fmaxf(sc4[2][r], sc4[3][r]));
#pragma unroll
        for (int off = 1; off <= 8; off <<= 1)
#pragma unroll
            for (int r = 0; r < 4; ++r) mx[r] = fmaxf(mx[r], __shfl_xor(mx[r], off));
        float alpha[4];
#pragma unroll
        for (int r = 0; r < 4; ++r) {
            const float mn = fmaxf(mrow[r], mx[r]);
            alpha[r] = __expf(mrow[r] - mn);
            mrow[r] = mn;
        }
        float sum[4] = {0.f, 0.f, 0.f, 0.f};
#pragma unroll
        for (int jf = 0; jf < 4; ++jf)
#pragma unroll
            for (int r = 0; r < 4; ++r) {
                const float p = __expf(sc4[jf][r] - mrow[r]);
                sum[r] += p;
                P_l[(wave * 16 + quad * 4 + r) * 72 + jf * 16 + r15] = f2bs(p);
            }
#pragma unroll
        for (int off = 1; off <= 8; off <<= 1)
#pragma unroll
            for (int r = 0; r < 4; ++r) sum[r] += __shfl_xor(sum[r], off);
#pragma unroll
        for (int r = 0; r < 4; ++r) lrow[r] = lrow[r] * alpha[r] + sum[r];
#pragma unroll
        for (int df = 0; df < 4; ++df)
#pragma unroll
            for (int r = 0; r < 4; ++r) o[df][r] *= alpha[r];
        // PV: A-frags from own wave's P rows (same-wave LDS); Vt synced above
#pragma unroll
        for (int ks = 0; ks < 2; ++ks) {
            const bshort8 ap = *(const bshort8*)&P_l[(wave * 16 + r15) * 72 + ks * 32 + quad * 8];
#pragma unroll
            for (int df = 0; df < 4; ++df) {
                const bshort8 bv = *(const bshort8*)&Vt_l[(df * 16 + r15) * 72 + ks * 32 + quad * 8];
                o[df] = __builtin_amdgcn_mfma_f32_16x16x32_bf16(ap, bv, o[df], 0, 0, 0);
            }
        }
    }
#pragma unroll
    for (int r = 0; r < 4; ++r) {
        const int q = q0 + wave * 16 + quad * 4 + r;
        const float rl = (mask[b * S_LEN + q] == 0) ? 0.f : (1.f / lrow[r]);
        const size_t ob = ((size_t)b * S_LEN + q) * 512 + h * 64;
#pragma unroll
        for (int df = 0; df < 4; ++df)
            C[ob + df * 16 + r15] = f2bs(o[df][r] * rl);
    }
}

extern "C" void kernel_launch(void* const* d_in, const int* in_sizes, int n_in,
                              void* d_out, int out_size, void* d_ws, size_t ws_size,
                              hipStream_t stream) {
    (void)in_sizes; (void)n_in; (void)out_size; (void)ws_size;
    const float* X    = (const float*)d_in[0];
    const int*   mask = (const int*)d_in[1];
    const float* Wq = (const float*)d_in[2];  const float* bq = (const float*)d_in[3];
    const float* Wk = (const float*)d_in[4];  const float* bk = (const float*)d_in[5];
    const float* Wv = (const float*)d_in[6];  const float* bv = (const float*)d_in[7];
    const float* Wo = (const float*)d_in[8];  const float* bo = (const float*)d_in[9];
    const float* lnlg = (const float*)d_in[10]; const float* lnlb = (const float*)d_in[11];
    const float* lnsg = (const float*)d_in[12]; const float* lnsb = (const float*)d_in[13];
    const float* Wd = (const float*)d_in[14]; const float* bd = (const float*)d_in[15];

    short* sw = (short*)d_ws;
    short* Qbf    = sw;                        // 4,194,304 bf16 (B,H,S,DH), pre-scaled
    short* Kbf    = Qbf + 4194304;             // 4,194,304 bf16 (B,H,S,DH), LN'd
    short* Vbf    = Kbf + 4194304;             // 4,194,304 bf16 (B,H,S,DH), LN'd
    short* KbBf   = Vbf + 4194304;             // 4,194,304 bf16 row-major pre-LN K
    short* VbBf   = KbBf + 4194304;            // 4,194,304 bf16 row-major pre-LN V
    short* DlogBf = VbBf + 4194304;            // 8,388,608 bf16
    short* Xbf    = DlogBf + 8388608;          // 4,194,304 bf16 (reused: partK, then Cbf)
    short* WTall  = Xbf + 4194304;             // 1,310,720 bf16
    short* WoT    = WTall + 1310720;           // 262,144 bf16
    short* KcBf   = WoT + 262144;              // 131,072 bf16 (B,H,L,DH)
    short* VcBf   = KcBf + 131072;             // 131,072 bf16
    short* partV  = VcBf + 131072;             // 4,194,304 bf16
    float* colZ   = (float*)(partV + 4194304); // 2,048 f32
    short* partK  = Xbf;                       // reuse (Xbf dead after gemm_proj)
    short* Cbf    = Xbf;                       // reuse (partK dead after kcvc_s2)
    // total ≈ 79.5 MB

    const dim3 blk(256);
    prep_all<<<3585, blk, 0, stream>>>(X, Wq, Wk, Wv, Wd, Wo, Xbf, WTall, WoT, colZ);
    gemm_proj<<<dim3(20, 64), blk, 0, stream>>>(Xbf, WTall, bq, bk, bv, bd, Qbf, KbBf, VbBf, DlogBf);
    ln_ip<<<dim3(8192, 2), blk, 0, stream>>>(KbBf, VbBf, lnlg, lnlb, Kbf, Vbf);
    colsum<<<dim3(4, 32, 2), blk, 0, stream>>>(DlogBf, colZ);
    kcvc_mfma<<<dim3(32, 8, 2), blk, 0, stream>>>(DlogBf, colZ, Kbf, Vbf, partK, partV);
    kcvc_s2<<<dim3(128, 2), blk, 0, stream>>>(partK, partV, lnsg, lnsb, KcBf, VcBf);
    attn_mfma<<<dim3(64, 8, 2), blk, 0, stream>>>(Qbf, Kbf, Vbf, KcBf, VcBf, mask, Cbf);
    gemm_out<<<dim3(8, 128), blk, 0, stream>>>(Cbf, WoT, bo, (float*)d_out);
}

// Round 8
// 238.286 us; speedup vs baseline: 3.7756x; 1.0032x over previous
//
#include <hip/hip_runtime.h>
#include <hip/hip_bf16.h>

#define S_LEN 4096
#define Hn 8
#define DHn 64
#define Lc 128
#define HL 1024
#define KD 512   // inner dim of all GEMMs

typedef __attribute__((ext_vector_type(8))) short bshort8;
typedef __attribute__((ext_vector_type(4))) float f32x4;

__device__ __forceinline__ short f2bs(float f) {
    union { float f; unsigned u; } x; x.f = f;
    const unsigned r = x.u + 0x7FFFu + ((x.u >> 16) & 1u);
    return (short)(r >> 16);
}
__device__ __forceinline__ float bs2f(short s) {
    union { unsigned u; float f; } x; x.u = ((unsigned)(unsigned short)s) << 16;
    return x.f;
}

// async global(bf16 bits as short) -> LDS, 16B per lane (GEMMs only; LDS must be unpadded)
__device__ __forceinline__ void gl16(const short* g, short* l) {
    __builtin_amdgcn_global_load_lds((const __attribute__((address_space(1))) void*)g,
                                     (__attribute__((address_space(3))) void*)l, 16, 0, 0);
}

// ---------------- fused prep: X->bf16 + all weight transposes ----------------
__global__ __launch_bounds__(256) void prep_all(const float* __restrict__ X,
    const float* __restrict__ Wq, const float* __restrict__ Wk, const float* __restrict__ Wv,
    const float* __restrict__ Wd, const float* __restrict__ Wo,
    short* __restrict__ Xbf, short* __restrict__ WTall, short* __restrict__ WoT)
{
    const int t = threadIdx.x;
    int blk = blockIdx.x;
    if (blk < 2048) {
        const int i = (blk * 256 + t) * 8;
        const float4 a = *(const float4*)&X[i];
        const float4 b = *(const float4*)&X[i + 4];
        bshort8 o;
        o[0] = f2bs(a.x); o[1] = f2bs(a.y); o[2] = f2bs(a.z); o[3] = f2bs(a.w);
        o[4] = f2bs(b.x); o[5] = f2bs(b.y); o[6] = f2bs(b.z); o[7] = f2bs(b.w);
        *(bshort8*)&Xbf[i] = o;
        return;
    }
    blk -= 2048;
    const float* W; short* out; int N;
    if (blk < 256)       { W = Wq; out = WTall;              N = 512;  }
    else if (blk < 512)  { W = Wk; out = WTall + 512 * 512;  N = 512;  blk -= 256; }
    else if (blk < 768)  { W = Wv; out = WTall + 1024 * 512; N = 512;  blk -= 512; }
    else if (blk < 1280) { W = Wd; out = WTall + 1536 * 512; N = 1024; blk -= 768; }
    else                 { W = Wo; out = WoT;                N = 512;  blk -= 1280; }
    const int nb = N >> 5;
    const int n0 = (blk % nb) * 32, k0 = (blk / nb) * 32;
    __shared__ float Tl[32][33];
    const int tx = t & 31, ty = t >> 5;
#pragma unroll
    for (int i = ty; i < 32; i += 8)
        Tl[i][tx] = W[(size_t)(k0 + i) * N + n0 + tx];
    __syncthreads();
#pragma unroll
    for (int i = ty; i < 32; i += 8)
        out[(size_t)(n0 + i) * KD + k0 + tx] = f2bs(Tl[tx][i]);
}

// ---------------- fused projection GEMM (MFMA, BK=64): X(8192x512) @ [Wq|Wk|Wv|Wd] ----------------
__global__ __launch_bounds__(256) void gemm_proj(const short* __restrict__ Xbf,
    const short* __restrict__ WT,
    const float* __restrict__ bq, const float* __restrict__ bk,
    const float* __restrict__ bv, const float* __restrict__ bd,
    short* __restrict__ Qbf, short* __restrict__ KbBf, short* __restrict__ VbBf,
    short* __restrict__ DlogBf)
{
    __shared__ __align__(16) short A_s[128 * 64];   // 16 KB
    __shared__ __align__(16) short B_s[128 * 64];   // 16 KB
    const int t = threadIdx.x;
    const int n0 = blockIdx.x * 128, m0 = blockIdx.y * 128;
    const int lane = t & 63, wave = t >> 6;
    const int wm = wave >> 1, wn = wave & 1;
    const int quad = lane >> 4, r15 = lane & 15;
    const int srow = t >> 3, scol = (t & 7) * 8;    // staging: 32 rows x 64 cols per round
    f32x4 acc[4][4];
#pragma unroll
    for (int i = 0; i < 4; ++i)
#pragma unroll
        for (int j = 0; j < 4; ++j) acc[i][j] = (f32x4){0.f, 0.f, 0.f, 0.f};

    for (int kk = 0; kk < KD; kk += 64) {
#pragma unroll
        for (int r = 0; r < 4; ++r) {
            gl16(&Xbf[(size_t)(m0 + r * 32 + srow) * KD + kk + scol], &A_s[r * 2048 + t * 8]);
            gl16(&WT[(size_t)(n0 + r * 32 + srow) * KD + kk + scol],  &B_s[r * 2048 + t * 8]);
        }
        __syncthreads();
#pragma unroll
        for (int ks = 0; ks < 2; ++ks) {
            bshort8 af[4], bfr[4];
#pragma unroll
            for (int i = 0; i < 4; ++i) af[i]  = *(const bshort8*)&A_s[(wm * 64 + i * 16 + r15) * 64 + ks * 32 + quad * 8];
#pragma unroll
            for (int j = 0; j < 4; ++j) bfr[j] = *(const bshort8*)&B_s[(wn * 64 + j * 16 + r15) * 64 + ks * 32 + quad * 8];
#pragma unroll
            for (int i = 0; i < 4; ++i)
#pragma unroll
                for (int j = 0; j < 4; ++j)
                    acc[i][j] = __builtin_amdgcn_mfma_f32_16x16x32_bf16(af[i], bfr[j], acc[i][j], 0, 0, 0);
        }
        __syncthreads();
    }
    const int seg = (n0 >= 1536) ? 3 : (n0 >> 9);   // block-uniform
#pragma unroll
    for (int i = 0; i < 4; ++i)
#pragma unroll
        for (int j = 0; j < 4; ++j)
#pragma unroll
            for (int r = 0; r < 4; ++r) {
                const int gm = m0 + wm * 64 + i * 16 + quad * 4 + r;
                const int gn = n0 + wn * 64 + j * 16 + r15;
                float v = acc[i][j][r];
                if (seg == 0) {
                    v = (v + bq[gn]) * 0.125f;
                    const int bb = gm >> 12, s = gm & 4095, hh = gn >> 6, d = gn & 63;
                    Qbf[((size_t)(bb * Hn + hh) * S_LEN + s) * DHn + d] = f2bs(v);
                } else if (seg == 1) {
                    KbBf[(size_t)gm * 512 + (gn - 512)] = f2bs(v + bk[gn - 512]);
                } else if (seg == 2) {
                    VbBf[(size_t)gm * 512 + (gn - 1024)] = f2bs(v + bv[gn - 1024]);
                } else {
                    DlogBf[(size_t)gm * 1024 + (gn - 1536)] = f2bs(v + bd[gn - 1536]);
                }
            }
}

// ---------------- output GEMM (MFMA): 64x64 tiles, 1024 blocks ----------------
__global__ __launch_bounds__(256) void gemm_out(const short* __restrict__ Abf,
    const short* __restrict__ WT, const float* __restrict__ bias, float* __restrict__ outp)
{
    __shared__ __align__(16) short A_s[64 * 32];
    __shared__ __align__(16) short B_s[64 * 32];
    const int t = threadIdx.x;
    const int n0 = blockIdx.x * 64, m0 = blockIdx.y * 64;
    const int lane = t & 63, wave = t >> 6;
    const int quad = lane >> 4, r15 = lane & 15;
    const int eOff = t * 8;
    const int am = eOff >> 5, ak = eOff & 31;
    f32x4 acc[4];
#pragma unroll
    for (int j = 0; j < 4; ++j) acc[j] = (f32x4){0.f, 0.f, 0.f, 0.f};

    for (int kk = 0; kk < KD; kk += 32) {
        gl16(&Abf[(size_t)(m0 + am) * KD + kk + ak], &A_s[eOff]);
        gl16(&WT[(size_t)(n0 + am) * KD + kk + ak],  &B_s[eOff]);
        __syncthreads();
        const bshort8 af = *(const bshort8*)&A_s[(wave * 16 + r15) * 32 + quad * 8];
#pragma unroll
        for (int j = 0; j < 4; ++j) {
            const bshort8 bfr = *(const bshort8*)&B_s[(j * 16 + r15) * 32 + quad * 8];
            acc[j] = __builtin_amdgcn_mfma_f32_16x16x32_bf16(af, bfr, acc[j], 0, 0, 0);
        }
        __syncthreads();
    }
#pragma unroll
    for (int j = 0; j < 4; ++j)
#pragma unroll
        for (int r = 0; r < 4; ++r) {
            const int gm = m0 + wave * 16 + quad * 4 + r;
            const int gn = n0 + j * 16 + r15;
            outp[(size_t)gm * 512 + gn] = acc[j][r] + bias[gn];
        }
}

// ---------------- row LayerNorm over 512 (bf16 in, bf16 (B,H,S,DH) out) ----------------
__global__ __launch_bounds__(256) void ln_ip(const short* __restrict__ KbBf, const short* __restrict__ VbBf,
    const float* __restrict__ g, const float* __restrict__ beta,
    short* __restrict__ Kbf, short* __restrict__ Vbf)
{
    const short* src = blockIdx.y ? VbBf : KbBf;
    short* dst = blockIdx.y ? Vbf : Kbf;
    const int row = blockIdx.x, t = threadIdx.x;
    const size_t base = (size_t)row * 512;
    const float x0 = bs2f(src[base + t]);
    const float x1 = bs2f(src[base + t + 256]);
    float s = x0 + x1, ss = x0 * x0 + x1 * x1;
#pragma unroll
    for (int off = 32; off >= 1; off >>= 1) { s += __shfl_xor(s, off); ss += __shfl_xor(ss, off); }
    __shared__ float red[2][4];
    if ((t & 63) == 0) { red[0][t >> 6] = s; red[1][t >> 6] = ss; }
    __syncthreads();
    s = red[0][0] + red[0][1] + red[0][2] + red[0][3];
    ss = red[1][0] + red[1][1] + red[1][2] + red[1][3];
    const float mu = s * (1.f / 512.f);
    const float r = rsqrtf(ss * (1.f / 512.f) - mu * mu + 1e-5f);
    const int bb = row >> 12, sidx = row & 4095;
#pragma unroll
    for (int half = 0; half < 2; ++half) {
        const int c = t + half * 256;
        const float x = half ? x1 : x0;
        const float v = (x - mu) * r * g[c] + beta[c];
        dst[((size_t)(bb * Hn + (c >> 6)) * S_LEN + sidx) * DHn + (c & 63)] = f2bs(v);
    }
}

// ---------------- Kc/Vc stage 1 (MFMA): unnormalized exp partials + partZ ----------------
__global__ __launch_bounds__(256) void kcvc_mfma(const short* __restrict__ Dlog,
    const short* __restrict__ Kbf, const short* __restrict__ Vbf,
    short* __restrict__ partK, short* __restrict__ partV, float* __restrict__ partZ)
{
    __shared__ __align__(16) short aa[128 * 72];   // [l][s], 72-pad
    __shared__ __align__(16) short Kt[64 * 72];    // [d][s]
    __shared__ __align__(16) short Vt[64 * 72];
    __shared__ float zsh[256];
    const int t = threadIdx.x;
    const int seg = blockIdx.x, h = blockIdx.y, b = blockIdx.z;
    const int s0 = seg * 128;
    const size_t bh = (size_t)(b * Hn + h);
    const int lane = t & 63, wave = t >> 6;
    const int quad = lane >> 4, r15 = lane & 15;
    const int al = t & 127, ah = t >> 7;
    const int vj = t & 63, vd0 = (t >> 6) * 16;   // lane=j transpose: conflict-free writes
    float zacc = 0.f;
    f32x4 aK[2][4], aV[2][4];
#pragma unroll
    for (int i = 0; i < 2; ++i)
#pragma unroll
        for (int j = 0; j < 4; ++j) { aK[i][j] = (f32x4){0.f,0.f,0.f,0.f}; aV[i][j] = (f32x4){0.f,0.f,0.f,0.f}; }

    for (int c = 0; c < 2; ++c) {
        const int sc0 = s0 + c * 64;
        if (c) __syncthreads();
#pragma unroll
        for (int gch = 0; gch < 4; ++gch) {
            bshort8 o;
#pragma unroll
            for (int j = 0; j < 8; ++j) {
                const int s = sc0 + ah * 32 + gch * 8 + j;
                const float e = __expf(bs2f(Dlog[((size_t)b * S_LEN + s) * HL + h * Lc + al]));
                zacc += e;
                o[j] = f2bs(e);
            }
            *(bshort8*)&aa[al * 72 + ah * 32 + gch * 8] = o;
        }
        {
            const size_t rb = (bh * S_LEN + sc0 + vj) * DHn + vd0;
            const bshort8 k0 = *(const bshort8*)&Kbf[rb];
            const bshort8 k1 = *(const bshort8*)&Kbf[rb + 8];
            const bshort8 v0 = *(const bshort8*)&Vbf[rb];
            const bshort8 v1 = *(const bshort8*)&Vbf[rb + 8];
#pragma unroll
            for (int i = 0; i < 8; ++i) {
                Kt[(vd0 + i) * 72 + vj] = k0[i]; Kt[(vd0 + 8 + i) * 72 + vj] = k1[i];
                Vt[(vd0 + i) * 72 + vj] = v0[i]; Vt[(vd0 + 8 + i) * 72 + vj] = v1[i];
            }
        }
        __syncthreads();
#pragma unroll
        for (int ks = 0; ks < 2; ++ks) {
            const bshort8 a0 = *(const bshort8*)&aa[(wave * 32 + r15) * 72 + ks * 32 + quad * 8];
            const bshort8 a1 = *(const bshort8*)&aa[(wave * 32 + 16 + r15) * 72 + ks * 32 + quad * 8];
#pragma unroll
            for (int j = 0; j < 4; ++j) {
                const bshort8 bk = *(const bshort8*)&Kt[(j * 16 + r15) * 72 + ks * 32 + quad * 8];
                const bshort8 bv = *(const bshort8*)&Vt[(j * 16 + r15) * 72 + ks * 32 + quad * 8];
                aK[0][j] = __builtin_amdgcn_mfma_f32_16x16x32_bf16(a0, bk, aK[0][j], 0, 0, 0);
                aK[1][j] = __builtin_amdgcn_mfma_f32_16x16x32_bf16(a1, bk, aK[1][j], 0, 0, 0);
                aV[0][j] = __builtin_amdgcn_mfma_f32_16x16x32_bf16(a0, bv, aV[0][j], 0, 0, 0);
                aV[1][j] = __builtin_amdgcn_mfma_f32_16x16x32_bf16(a1, bv, aV[1][j], 0, 0, 0);
            }
        }
    }
    zsh[t] = zacc;
    __syncthreads();
    if (t < 128)
        partZ[((size_t)(bh * Lc + t)) * 32 + seg] = zsh[t] + zsh[t + 128];
#pragma unroll
    for (int i = 0; i < 2; ++i)
#pragma unroll
        for (int j = 0; j < 4; ++j)
#pragma unroll
            for (int r = 0; r < 4; ++r) {
                const int l = wave * 32 + i * 16 + quad * 4 + r;
                const int d = j * 16 + r15;
                const size_t o = (((size_t)(b * Lc + l)) * 32 + seg) * 512 + h * 64 + d;
                partK[o] = f2bs(aK[i][j][r]);
                partV[o] = f2bs(aV[i][j][r]);
            }
}

// ---------------- Kc/Vc stage 2: reduce chunks, normalize by Z, LN over 512 ----------------
__global__ __launch_bounds__(256) void kcvc_s2(const short* __restrict__ partK,
    const short* __restrict__ partV, const float* __restrict__ partZ,
    const float* __restrict__ g, const float* __restrict__ beta,
    short* __restrict__ KcBf, short* __restrict__ VcBf)
{
    const int l = blockIdx.x, b = blockIdx.y, t = threadIdx.x;
    __shared__ float zh[8];
    if (t < 8) {
        float z = 0.f;
        const size_t zb = ((size_t)((b * Hn + t) * Lc + l)) * 32;
#pragma unroll
        for (int seg = 0; seg < 32; ++seg) z += partZ[zb + seg];
        zh[t] = 1.f / z;
    }
    const size_t base = ((size_t)(b * Lc + l)) * 32 * 512;
    float k0 = 0.f, k1 = 0.f, v0 = 0.f, v1 = 0.f;
    for (int ch = 0; ch < 32; ++ch) {
        const size_t o = base + (size_t)ch * 512;
        k0 += bs2f(partK[o + t]);       k1 += bs2f(partK[o + t + 256]);
        v0 += bs2f(partV[o + t]);       v1 += bs2f(partV[o + t + 256]);
    }
    __syncthreads();
    const float z0 = zh[t >> 6], z1 = zh[(t + 256) >> 6];
    k0 *= z0; k1 *= z1; v0 *= z0; v1 *= z1;
    float sk = k0 + k1, ssk = k0 * k0 + k1 * k1;
    float sv = v0 + v1, ssv = v0 * v0 + v1 * v1;
#pragma unroll
    for (int off = 32; off >= 1; off >>= 1) {
        sk += __shfl_xor(sk, off); ssk += __shfl_xor(ssk, off);
        sv += __shfl_xor(sv, off); ssv += __shfl_xor(ssv, off);
    }
    __shared__ float red[4][4];
    if ((t & 63) == 0) {
        red[0][t >> 6] = sk; red[1][t >> 6] = ssk;
        red[2][t >> 6] = sv; red[3][t >> 6] = ssv;
    }
    __syncthreads();
    sk = red[0][0] + red[0][1] + red[0][2] + red[0][3];
    ssk = red[1][0] + red[1][1] + red[1][2] + red[1][3];
    sv = red[2][0] + red[2][1] + red[2][2] + red[2][3];
    ssv = red[3][0] + red[3][1] + red[3][2] + red[3][3];
    const float muK = sk * (1.f / 512.f);
    const float rK = rsqrtf(ssk * (1.f / 512.f) - muK * muK + 1e-5f);
    const float muV = sv * (1.f / 512.f);
    const float rV = rsqrtf(ssv * (1.f / 512.f) - muV * muV + 1e-5f);
#pragma unroll
    for (int half = 0; half < 2; ++half) {
        const int c = t + half * 256;
        const float xk = half ? k1 : k0;
        const float xv = half ? v1 : v0;
        const size_t o = ((size_t)(b * Hn + (c >> 6)) * Lc + l) * DHn + (c & 63);
        KcBf[o] = f2bs((xk - muK) * rK * g[c] + beta[c]);
        VcBf[o] = f2bs((xv - muV) * rV * g[c] + beta[c]);
    }
}

// ---------------- MFMA flash attention (no-max softmax: scores bounded, mask -> exp=0) ------
__global__ __launch_bounds__(256) void attn_mfma(
    const short* __restrict__ Qbf, const short* __restrict__ Kbf, const short* __restrict__ Vbf,
    const short* __restrict__ KcBf, const short* __restrict__ VcBf,
    const int* __restrict__ mask, short* __restrict__ C)
{
    __shared__ __align__(16) short Q_l[64 * 72];   // [q][d]
    __shared__ __align__(16) short K_l[64 * 72];   // [j][d]
    __shared__ __align__(16) short Vt_l[64 * 72];  // [d][j]
    __shared__ __align__(16) short P_l[64 * 72];   // [q][j]
    __shared__ float vb[64];
    const int t = threadIdx.x;
    const int qt = blockIdx.x, h = blockIdx.y, b = blockIdx.z;
    const int q0 = qt * 64, gg = qt >> 1;
    const size_t bh = (size_t)(b * Hn + h);
    const int lane = t & 63, wave = t >> 6;
    const int quad = lane >> 4, r15 = lane & 15;
    const int sr = t >> 2, sc = (t & 3) * 16;      // padded staging for Q/K
    const int vj = t & 63, vd0 = (t >> 6) * 16;    // lane=j V transpose

    {
        const size_t gq = (bh * S_LEN + q0 + sr) * DHn + sc;
        const bshort8 a = *(const bshort8*)&Qbf[gq];
        const bshort8 b8 = *(const bshort8*)&Qbf[gq + 8];
        *(bshort8*)&Q_l[sr * 72 + sc] = a;
        *(bshort8*)&Q_l[sr * 72 + sc + 8] = b8;
    }
    f32x4 o[4];
#pragma unroll
    for (int df = 0; df < 4; ++df) o[df] = (f32x4){0.f, 0.f, 0.f, 0.f};
    float lrow[4] = {0.f, 0.f, 0.f, 0.f};

    for (int cc = 0; cc < 6; ++cc) {
        const short* ksrc; const short* vsrc;
        int sk0 = 0;
        if (cc < 2) {
            ksrc = &KcBf[(bh * Lc + cc * 64) * DHn];
            vsrc = &VcBf[(bh * Lc + cc * 64) * DHn];
        } else {
            sk0 = gg * 128 - 64 + (cc - 2) * 64;
            if (sk0 < 0 || sk0 >= S_LEN) continue;   // 64-aligned: fully OOB -> skip (block-uniform)
            ksrc = &Kbf[(bh * S_LEN + sk0) * DHn];
            vsrc = &Vbf[(bh * S_LEN + sk0) * DHn];
        }
        __syncthreads();   // prev chunk's LDS reads done (also covers Q staging on cc==0)
        if (t < 64) {
            float v = 0.f;
            if (cc >= 2 && mask[b * S_LEN + sk0 + t] == 0) v = -1e30f;
            vb[t] = v;
        }
        {
            const bshort8 a = *(const bshort8*)&ksrc[sr * 64 + sc];
            const bshort8 b8 = *(const bshort8*)&ksrc[sr * 64 + sc + 8];
            *(bshort8*)&K_l[sr * 72 + sc] = a;
            *(bshort8*)&K_l[sr * 72 + sc + 8] = b8;
        }
        {
            const bshort8 v0 = *(const bshort8*)&vsrc[vj * 64 + vd0];
            const bshort8 v1 = *(const bshort8*)&vsrc[vj * 64 + vd0 + 8];
#pragma unroll
            for (int i = 0; i < 8; ++i) {
                Vt_l[(vd0 + i) * 72 + vj] = v0[i];
                Vt_l[(vd0 + 8 + i) * 72 + vj] = v1[i];
            }
        }
        __syncthreads();
        f32x4 c[4];
#pragma unroll
        for (int jf = 0; jf < 4; ++jf) c[jf] = (f32x4){0.f, 0.f, 0.f, 0.f};
#pragma unroll
        for (int ks = 0; ks < 2; ++ks) {
            const bshort8 aq = *(const bshort8*)&Q_l[(wave * 16 + r15) * 72 + ks * 32 + quad * 8];
#pragma unroll
            for (int jf = 0; jf < 4; ++jf) {
                const bshort8 bk = *(const bshort8*)&K_l[(jf * 16 + r15) * 72 + ks * 32 + quad * 8];
                c[jf] = __builtin_amdgcn_mfma_f32_16x16x32_bf16(aq, bk, c[jf], 0, 0, 0);
            }
        }
        float vbl[4];
#pragma unroll
        for (int jf = 0; jf < 4; ++jf) vbl[jf] = vb[jf * 16 + r15];
        float sum[4] = {0.f, 0.f, 0.f, 0.f};
#pragma unroll
        for (int jf = 0; jf < 4; ++jf)
#pragma unroll
            for (int r = 0; r < 4; ++r) {
                const float p = __expf(c[jf][r] + vbl[jf]);
                sum[r] += p;
                P_l[(wave * 16 + quad * 4 + r) * 72 + jf * 16 + r15] = f2bs(p);
            }
#pragma unroll
        for (int off = 1; off <= 8; off <<= 1)
#pragma unroll
            for (int r = 0; r < 4; ++r) sum[r] += __shfl_xor(sum[r], off);
#pragma unroll
        for (int r = 0; r < 4; ++r) lrow[r] += sum[r];
        // PV: A-frags from own wave's P rows (same-wave LDS); Vt synced above
#pragma unroll
        for (int ks = 0; ks < 2; ++ks) {
            const bshort8 ap = *(const bshort8*)&P_l[(wave * 16 + r15) * 72 + ks * 32 + quad * 8];
#pragma unroll
            for (int df = 0; df < 4; ++df) {
                const bshort8 bv = *(const bshort8*)&Vt_l[(df * 16 + r15) * 72 + ks * 32 + quad * 8];
                o[df] = __builtin_amdgcn_mfma_f32_16x16x32_bf16(ap, bv, o[df], 0, 0, 0);
            }
        }
    }
#pragma unroll
    for (int r = 0; r < 4; ++r) {
        const int q = q0 + wave * 16 + quad * 4 + r;
        const float rl = (mask[b * S_LEN + q] == 0) ? 0.f : (1.f / lrow[r]);
        const size_t ob = ((size_t)b * S_LEN + q) * 512 + h * 64;
#pragma unroll
        for (int df = 0; df < 4; ++df)
            C[ob + df * 16 + r15] = f2bs(o[df][r] * rl);
    }
}

extern "C" void kernel_launch(void* const* d_in, const int* in_sizes, int n_in,
                              void* d_out, int out_size, void* d_ws, size_t ws_size,
                              hipStream_t stream) {
    (void)in_sizes; (void)n_in; (void)out_size; (void)ws_size;
    const float* X    = (const float*)d_in[0];
    const int*   mask = (const int*)d_in[1];
    const float* Wq = (const float*)d_in[2];  const float* bq = (const float*)d_in[3];
    const float* Wk = (const float*)d_in[4];  const float* bk = (const float*)d_in[5];
    const float* Wv = (const float*)d_in[6];  const float* bv = (const float*)d_in[7];
    const float* Wo = (const float*)d_in[8];  const float* bo = (const float*)d_in[9];
    const float* lnlg = (const float*)d_in[10]; const float* lnlb = (const float*)d_in[11];
    const float* lnsg = (const float*)d_in[12]; const float* lnsb = (const float*)d_in[13];
    const float* Wd = (const float*)d_in[14]; const float* bd = (const float*)d_in[15];

    short* sw = (short*)d_ws;
    short* Qbf    = sw;                        // 4,194,304 bf16 (B,H,S,DH), pre-scaled
    short* Kbf    = Qbf + 4194304;             // 4,194,304 bf16 (B,H,S,DH), LN'd
    short* Vbf    = Kbf + 4194304;             // 4,194,304 bf16 (B,H,S,DH), LN'd
    short* KbBf   = Vbf + 4194304;             // 4,194,304 bf16 row-major pre-LN K
    short* VbBf   = KbBf + 4194304;            // 4,194,304 bf16 row-major pre-LN V
    short* DlogBf = VbBf + 4194304;            // 8,388,608 bf16
    short* Xbf    = DlogBf + 8388608;          // 4,194,304 bf16 (reused: partK, then Cbf)
    short* WTall  = Xbf + 4194304;             // 1,310,720 bf16
    short* WoT    = WTall + 1310720;           // 262,144 bf16
    short* KcBf   = WoT + 262144;              // 131,072 bf16 (B,H,L,DH)
    short* VcBf   = KcBf + 131072;             // 131,072 bf16
    short* partV  = VcBf + 131072;             // 4,194,304 bf16
    float* partZ  = (float*)(partV + 4194304); // 65,536 f32 (b,h,l,seg)
    short* partK  = Xbf;                       // reuse (Xbf dead after gemm_proj)
    short* Cbf    = Xbf;                       // reuse (partK dead after kcvc_s2)
    // total ≈ 79.7 MB

    const dim3 blk(256);
    prep_all<<<3584, blk, 0, stream>>>(X, Wq, Wk, Wv, Wd, Wo, Xbf, WTall, WoT);
    gemm_proj<<<dim3(20, 64), blk, 0, stream>>>(Xbf, WTall, bq, bk, bv, bd, Qbf, KbBf, VbBf, DlogBf);
    ln_ip<<<dim3(8192, 2), blk, 0, stream>>>(KbBf, VbBf, lnlg, lnlb, Kbf, Vbf);
    kcvc_mfma<<<dim3(32, 8, 2), blk, 0, stream>>>(DlogBf, Kbf, Vbf, partK, partV, partZ);
    kcvc_s2<<<dim3(128, 2), blk, 0, stream>>>(partK, partV, partZ, lnsg, lnsb, KcBf, VcBf);
    attn_mfma<<<dim3(64, 8, 2), blk, 0, stream>>>(Qbf, Kbf, Vbf, KcBf, VcBf, mask, Cbf);
    gemm_out<<<dim3(8, 128), blk, 0, stream>>>(Cbf, WoT, bo, (float*)d_out);
}

// Round 9
// 220.910 us; speedup vs baseline: 4.0725x; 1.0787x over previous
//
#include <hip/hip_runtime.h>
#include <hip/hip_bf16.h>

#define S_LEN 4096
#define Hn 8
#define DHn 64
#define Lc 128
#define HL 1024
#define KD 512   // inner dim of all GEMMs

typedef __attribute__((ext_vector_type(8))) short bshort8;
typedef __attribute__((ext_vector_type(4))) float f32x4;

__device__ __forceinline__ short f2bs(float f) {
    union { float f; unsigned u; } x; x.f = f;
    const unsigned r = x.u + 0x7FFFu + ((x.u >> 16) & 1u);
    return (short)(r >> 16);
}
__device__ __forceinline__ float bs2f(short s) {
    union { unsigned u; float f; } x; x.u = ((unsigned)(unsigned short)s) << 16;
    return x.f;
}

// async global(bf16 bits as short) -> LDS, 16B per lane (GEMMs only; LDS must be unpadded)
__device__ __forceinline__ void gl16(const short* g, short* l) {
    __builtin_amdgcn_global_load_lds((const __attribute__((address_space(1))) void*)g,
                                     (__attribute__((address_space(3))) void*)l, 16, 0, 0);
}

// ---------------- fused prep: X->bf16 + all weight transposes ----------------
__global__ __launch_bounds__(256) void prep_all(const float* __restrict__ X,
    const float* __restrict__ Wq, const float* __restrict__ Wk, const float* __restrict__ Wv,
    const float* __restrict__ Wd, const float* __restrict__ Wo,
    short* __restrict__ Xbf, short* __restrict__ WTall, short* __restrict__ WoT)
{
    const int t = threadIdx.x;
    int blk = blockIdx.x;
    if (blk < 2048) {
        const int i = (blk * 256 + t) * 8;
        const float4 a = *(const float4*)&X[i];
        const float4 b = *(const float4*)&X[i + 4];
        bshort8 o;
        o[0] = f2bs(a.x); o[1] = f2bs(a.y); o[2] = f2bs(a.z); o[3] = f2bs(a.w);
        o[4] = f2bs(b.x); o[5] = f2bs(b.y); o[6] = f2bs(b.z); o[7] = f2bs(b.w);
        *(bshort8*)&Xbf[i] = o;
        return;
    }
    blk -= 2048;
    const float* W; short* out; int N;
    if (blk < 256)       { W = Wq; out = WTall;              N = 512;  }
    else if (blk < 512)  { W = Wk; out = WTall + 512 * 512;  N = 512;  blk -= 256; }
    else if (blk < 768)  { W = Wv; out = WTall + 1024 * 512; N = 512;  blk -= 512; }
    else if (blk < 1280) { W = Wd; out = WTall + 1536 * 512; N = 1024; blk -= 768; }
    else                 { W = Wo; out = WoT;                N = 512;  blk -= 1280; }
    const int nb = N >> 5;
    const int n0 = (blk % nb) * 32, k0 = (blk / nb) * 32;
    __shared__ float Tl[32][33];
    const int tx = t & 31, ty = t >> 5;
#pragma unroll
    for (int i = ty; i < 32; i += 8)
        Tl[i][tx] = W[(size_t)(k0 + i) * N + n0 + tx];
    __syncthreads();
#pragma unroll
    for (int i = ty; i < 32; i += 8)
        out[(size_t)(n0 + i) * KD + k0 + tx] = f2bs(Tl[tx][i]);
}

// ---------------- fused projection GEMM (MFMA, BK=32 — round-7 proven body) ----------------
__global__ __launch_bounds__(256) void gemm_proj(const short* __restrict__ Xbf,
    const short* __restrict__ WT,
    const float* __restrict__ bq, const float* __restrict__ bk,
    const float* __restrict__ bv, const float* __restrict__ bd,
    short* __restrict__ Qbf, short* __restrict__ KbBf, short* __restrict__ VbBf,
    short* __restrict__ DlogBf)
{
    __shared__ __align__(16) short A_s[128 * 32];
    __shared__ __align__(16) short B_s[128 * 32];
    const int t = threadIdx.x;
    const int n0 = blockIdx.x * 128, m0 = blockIdx.y * 128;
    const int lane = t & 63, wave = t >> 6;
    const int wm = wave >> 1, wn = wave & 1;
    const int quad = lane >> 4, r15 = lane & 15;
    const int eOff = t * 8;
    const int am = eOff >> 5, ak = eOff & 31;
    f32x4 acc[4][4];
#pragma unroll
    for (int i = 0; i < 4; ++i)
#pragma unroll
        for (int j = 0; j < 4; ++j) acc[i][j] = (f32x4){0.f, 0.f, 0.f, 0.f};

    for (int kk = 0; kk < KD; kk += 32) {
        gl16(&Xbf[(size_t)(m0 + am) * KD + kk + ak],      &A_s[eOff]);
        gl16(&Xbf[(size_t)(m0 + 64 + am) * KD + kk + ak], &A_s[2048 + eOff]);
        gl16(&WT[(size_t)(n0 + am) * KD + kk + ak],       &B_s[eOff]);
        gl16(&WT[(size_t)(n0 + 64 + am) * KD + kk + ak],  &B_s[2048 + eOff]);
        __syncthreads();
        bshort8 af[4], bfr[4];
#pragma unroll
        for (int i = 0; i < 4; ++i) af[i]  = *(const bshort8*)&A_s[(wm * 64 + i * 16 + r15) * 32 + quad * 8];
#pragma unroll
        for (int j = 0; j < 4; ++j) bfr[j] = *(const bshort8*)&B_s[(wn * 64 + j * 16 + r15) * 32 + quad * 8];
#pragma unroll
        for (int i = 0; i < 4; ++i)
#pragma unroll
            for (int j = 0; j < 4; ++j)
                acc[i][j] = __builtin_amdgcn_mfma_f32_16x16x32_bf16(af[i], bfr[j], acc[i][j], 0, 0, 0);
        __syncthreads();
    }
    const int seg = (n0 >= 1536) ? 3 : (n0 >> 9);   // block-uniform
#pragma unroll
    for (int i = 0; i < 4; ++i)
#pragma unroll
        for (int j = 0; j < 4; ++j)
#pragma unroll
            for (int r = 0; r < 4; ++r) {
                const int gm = m0 + wm * 64 + i * 16 + quad * 4 + r;
                const int gn = n0 + wn * 64 + j * 16 + r15;
                float v = acc[i][j][r];
                if (seg == 0) {
                    v = (v + bq[gn]) * 0.125f;
                    const int bb = gm >> 12, s = gm & 4095, hh = gn >> 6, d = gn & 63;
                    Qbf[((size_t)(bb * Hn + hh) * S_LEN + s) * DHn + d] = f2bs(v);
                } else if (seg == 1) {
                    KbBf[(size_t)gm * 512 + (gn - 512)] = f2bs(v + bk[gn - 512]);
                } else if (seg == 2) {
                    VbBf[(size_t)gm * 512 + (gn - 1024)] = f2bs(v + bv[gn - 1024]);
                } else {
                    DlogBf[(size_t)gm * 1024 + (gn - 1536)] = f2bs(v + bd[gn - 1536]);
                }
            }
}

// ---------------- output GEMM (MFMA): 64x64 tiles, 1024 blocks ----------------
__global__ __launch_bounds__(256) void gemm_out(const short* __restrict__ Abf,
    const short* __restrict__ WT, const float* __restrict__ bias, float* __restrict__ outp)
{
    __shared__ __align__(16) short A_s[64 * 32];
    __shared__ __align__(16) short B_s[64 * 32];
    const int t = threadIdx.x;
    const int n0 = blockIdx.x * 64, m0 = blockIdx.y * 64;
    const int lane = t & 63, wave = t >> 6;
    const int quad = lane >> 4, r15 = lane & 15;
    const int eOff = t * 8;
    const int am = eOff >> 5, ak = eOff & 31;
    f32x4 acc[4];
#pragma unroll
    for (int j = 0; j < 4; ++j) acc[j] = (f32x4){0.f, 0.f, 0.f, 0.f};

    for (int kk = 0; kk < KD; kk += 32) {
        gl16(&Abf[(size_t)(m0 + am) * KD + kk + ak], &A_s[eOff]);
        gl16(&WT[(size_t)(n0 + am) * KD + kk + ak],  &B_s[eOff]);
        __syncthreads();
        const bshort8 af = *(const bshort8*)&A_s[(wave * 16 + r15) * 32 + quad * 8];
#pragma unroll
        for (int j = 0; j < 4; ++j) {
            const bshort8 bfr = *(const bshort8*)&B_s[(j * 16 + r15) * 32 + quad * 8];
            acc[j] = __builtin_amdgcn_mfma_f32_16x16x32_bf16(af, bfr, acc[j], 0, 0, 0);
        }
        __syncthreads();
    }
#pragma unroll
    for (int j = 0; j < 4; ++j)
#pragma unroll
        for (int r = 0; r < 4; ++r) {
            const int gm = m0 + wave * 16 + quad * 4 + r;
            const int gn = n0 + j * 16 + r15;
            outp[(size_t)gm * 512 + gn] = acc[j][r] + bias[gn];
        }
}

// ---------------- row LayerNorm over 512 (bf16 in, bf16 (B,H,S,DH) out) ----------------
__global__ __launch_bounds__(256) void ln_ip(const short* __restrict__ KbBf, const short* __restrict__ VbBf,
    const float* __restrict__ g, const float* __restrict__ beta,
    short* __restrict__ Kbf, short* __restrict__ Vbf)
{
    const short* src = blockIdx.y ? VbBf : KbBf;
    short* dst = blockIdx.y ? Vbf : Kbf;
    const int row = blockIdx.x, t = threadIdx.x;
    const size_t base = (size_t)row * 512;
    const float x0 = bs2f(src[base + t]);
    const float x1 = bs2f(src[base + t + 256]);
    float s = x0 + x1, ss = x0 * x0 + x1 * x1;
#pragma unroll
    for (int off = 32; off >= 1; off >>= 1) { s += __shfl_xor(s, off); ss += __shfl_xor(ss, off); }
    __shared__ float red[2][4];
    if ((t & 63) == 0) { red[0][t >> 6] = s; red[1][t >> 6] = ss; }
    __syncthreads();
    s = red[0][0] + red[0][1] + red[0][2] + red[0][3];
    ss = red[1][0] + red[1][1] + red[1][2] + red[1][3];
    const float mu = s * (1.f / 512.f);
    const float r = rsqrtf(ss * (1.f / 512.f) - mu * mu + 1e-5f);
    const int bb = row >> 12, sidx = row & 4095;
#pragma unroll
    for (int half = 0; half < 2; ++half) {
        const int c = t + half * 256;
        const float x = half ? x1 : x0;
        const float v = (x - mu) * r * g[c] + beta[c];
        dst[((size_t)(bb * Hn + (c >> 6)) * S_LEN + sidx) * DHn + (c & 63)] = f2bs(v);
    }
}

// ---------------- Kc/Vc stage 1 (MFMA): unnormalized exp partials + partZ ----------------
__global__ __launch_bounds__(256) void kcvc_mfma(const short* __restrict__ Dlog,
    const short* __restrict__ Kbf, const short* __restrict__ Vbf,
    short* __restrict__ partK, short* __restrict__ partV, float* __restrict__ partZ)
{
    __shared__ __align__(16) short aa[128 * 72];   // [l][s], 72-pad
    __shared__ __align__(16) short Kt[64 * 72];    // [d][s]
    __shared__ __align__(16) short Vt[64 * 72];
    __shared__ float zsh[256];
    const int t = threadIdx.x;
    const int seg = blockIdx.x, h = blockIdx.y, b = blockIdx.z;
    const int s0 = seg * 128;
    const size_t bh = (size_t)(b * Hn + h);
    const int lane = t & 63, wave = t >> 6;
    const int quad = lane >> 4, r15 = lane & 15;
    const int al = t & 127, ah = t >> 7;
    const int vj = t & 63, vd0 = (t >> 6) * 16;   // lane=j transpose: conflict-free writes
    float zacc = 0.f;
    f32x4 aK[2][4], aV[2][4];
#pragma unroll
    for (int i = 0; i < 2; ++i)
#pragma unroll
        for (int j = 0; j < 4; ++j) { aK[i][j] = (f32x4){0.f,0.f,0.f,0.f}; aV[i][j] = (f32x4){0.f,0.f,0.f,0.f}; }

    for (int c = 0; c < 2; ++c) {
        const int sc0 = s0 + c * 64;
        if (c) __syncthreads();
#pragma unroll
        for (int gch = 0; gch < 4; ++gch) {
            bshort8 o;
#pragma unroll
            for (int j = 0; j < 8; ++j) {
                const int s = sc0 + ah * 32 + gch * 8 + j;
                const float e = __expf(bs2f(Dlog[((size_t)b * S_LEN + s) * HL + h * Lc + al]));
                zacc += e;
                o[j] = f2bs(e);
            }
            *(bshort8*)&aa[al * 72 + ah * 32 + gch * 8] = o;
        }
        {
            const size_t rb = (bh * S_LEN + sc0 + vj) * DHn + vd0;
            const bshort8 k0 = *(const bshort8*)&Kbf[rb];
            const bshort8 k1 = *(const bshort8*)&Kbf[rb + 8];
            const bshort8 v0 = *(const bshort8*)&Vbf[rb];
            const bshort8 v1 = *(const bshort8*)&Vbf[rb + 8];
#pragma unroll
            for (int i = 0; i < 8; ++i) {
                Kt[(vd0 + i) * 72 + vj] = k0[i]; Kt[(vd0 + 8 + i) * 72 + vj] = k1[i];
                Vt[(vd0 + i) * 72 + vj] = v0[i]; Vt[(vd0 + 8 + i) * 72 + vj] = v1[i];
            }
        }
        __syncthreads();
#pragma unroll
        for (int ks = 0; ks < 2; ++ks) {
            const bshort8 a0 = *(const bshort8*)&aa[(wave * 32 + r15) * 72 + ks * 32 + quad * 8];
            const bshort8 a1 = *(const bshort8*)&aa[(wave * 32 + 16 + r15) * 72 + ks * 32 + quad * 8];
#pragma unroll
            for (int j = 0; j < 4; ++j) {
                const bshort8 bk = *(const bshort8*)&Kt[(j * 16 + r15) * 72 + ks * 32 + quad * 8];
                const bshort8 bv = *(const bshort8*)&Vt[(j * 16 + r15) * 72 + ks * 32 + quad * 8];
                aK[0][j] = __builtin_amdgcn_mfma_f32_16x16x32_bf16(a0, bk, aK[0][j], 0, 0, 0);
                aK[1][j] = __builtin_amdgcn_mfma_f32_16x16x32_bf16(a1, bk, aK[1][j], 0, 0, 0);
                aV[0][j] = __builtin_amdgcn_mfma_f32_16x16x32_bf16(a0, bv, aV[0][j], 0, 0, 0);
                aV[1][j] = __builtin_amdgcn_mfma_f32_16x16x32_bf16(a1, bv, aV[1][j], 0, 0, 0);
            }
        }
    }
    zsh[t] = zacc;
    __syncthreads();
    if (t < 128)
        partZ[((size_t)(bh * Lc + t)) * 32 + seg] = zsh[t] + zsh[t + 128];
#pragma unroll
    for (int i = 0; i < 2; ++i)
#pragma unroll
        for (int j = 0; j < 4; ++j)
#pragma unroll
            for (int r = 0; r < 4; ++r) {
                const int l = wave * 32 + i * 16 + quad * 4 + r;
                const int d = j * 16 + r15;
                const size_t o = (((size_t)(b * Lc + l)) * 32 + seg) * 512 + h * 64 + d;
                partK[o] = f2bs(aK[i][j][r]);
                partV[o] = f2bs(aV[i][j][r]);
            }
}

// ---------------- Kc/Vc stage 2: reduce chunks, normalize by Z, LN over 512 ----------------
__global__ __launch_bounds__(256) void kcvc_s2(const short* __restrict__ partK,
    const short* __restrict__ partV, const float* __restrict__ partZ,
    const float* __restrict__ g, const float* __restrict__ beta,
    short* __restrict__ KcBf, short* __restrict__ VcBf)
{
    const int l = blockIdx.x, b = blockIdx.y, t = threadIdx.x;
    __shared__ float zh[8];
    if (t < 8) {
        float z = 0.f;
        const size_t zb = ((size_t)((b * Hn + t) * Lc + l)) * 32;
#pragma unroll
        for (int seg = 0; seg < 32; ++seg) z += partZ[zb + seg];
        zh[t] = 1.f / z;
    }
    const size_t base = ((size_t)(b * Lc + l)) * 32 * 512;
    float k0 = 0.f, k1 = 0.f, v0 = 0.f, v1 = 0.f;
    for (int ch = 0; ch < 32; ++ch) {
        const size_t o = base + (size_t)ch * 512;
        k0 += bs2f(partK[o + t]);       k1 += bs2f(partK[o + t + 256]);
        v0 += bs2f(partV[o + t]);       v1 += bs2f(partV[o + t + 256]);
    }
    __syncthreads();
    const float z0 = zh[t >> 6], z1 = zh[(t + 256) >> 6];
    k0 *= z0; k1 *= z1; v0 *= z0; v1 *= z1;
    float sk = k0 + k1, ssk = k0 * k0 + k1 * k1;
    float sv = v0 + v1, ssv = v0 * v0 + v1 * v1;
#pragma unroll
    for (int off = 32; off >= 1; off >>= 1) {
        sk += __shfl_xor(sk, off); ssk += __shfl_xor(ssk, off);
        sv += __shfl_xor(sv, off); ssv += __shfl_xor(ssv, off);
    }
    __shared__ float red[4][4];
    if ((t & 63) == 0) {
        red[0][t >> 6] = sk; red[1][t >> 6] = ssk;
        red[2][t >> 6] = sv; red[3][t >> 6] = ssv;
    }
    __syncthreads();
    sk = red[0][0] + red[0][1] + red[0][2] + red[0][3];
    ssk = red[1][0] + red[1][1] + red[1][2] + red[1][3];
    sv = red[2][0] + red[2][1] + red[2][2] + red[2][3];
    ssv = red[3][0] + red[3][1] + red[3][2] + red[3][3];
    const float muK = sk * (1.f / 512.f);
    const float rK = rsqrtf(ssk * (1.f / 512.f) - muK * muK + 1e-5f);
    const float muV = sv * (1.f / 512.f);
    const float rV = rsqrtf(ssv * (1.f / 512.f) - muV * muV + 1e-5f);
#pragma unroll
    for (int half = 0; half < 2; ++half) {
        const int c = t + half * 256;
        const float xk = half ? k1 : k0;
        const float xv = half ? v1 : v0;
        const size_t o = ((size_t)(b * Hn + (c >> 6)) * Lc + l) * DHn + (c & 63);
        KcBf[o] = f2bs((xk - muK) * rK * g[c] + beta[c]);
        VcBf[o] = f2bs((xv - muV) * rV * g[c] + beta[c]);
    }
}

// ---------------- MFMA flash attention: 128 q-rows per block (qt == window group) ----------------
__global__ __launch_bounds__(256) void attn_mfma(
    const short* __restrict__ Qbf, const short* __restrict__ Kbf, const short* __restrict__ Vbf,
    const short* __restrict__ KcBf, const short* __restrict__ VcBf,
    const int* __restrict__ mask, short* __restrict__ C)
{
    __shared__ __align__(16) short Q_l[128 * 72];   // [q][d]
    __shared__ __align__(16) short K_l[64 * 72];    // [j][d]
    __shared__ __align__(16) short Vt_l[64 * 72];   // [d][j]
    __shared__ __align__(16) short P_l[128 * 72];   // [q][j]
    __shared__ float vb[64];
    const int t = threadIdx.x;
    const int qt = blockIdx.x, h = blockIdx.y, b = blockIdx.z;
    const int q0 = qt * 128;
    const size_t bh = (size_t)(b * Hn + h);
    const int lane = t & 63, wave = t >> 6;
    const int quad = lane >> 4, r15 = lane & 15;
    const int sr = t >> 2, sc = (t & 3) * 16;      // 64-row padded staging
    const int vj = t & 63, vd0 = (t >> 6) * 16;    // lane=j V transpose

#pragma unroll
    for (int r = 0; r < 2; ++r) {
        const int row = r * 64 + sr;
        const size_t gq = (bh * S_LEN + q0 + row) * DHn + sc;
        const bshort8 a = *(const bshort8*)&Qbf[gq];
        const bshort8 b8 = *(const bshort8*)&Qbf[gq + 8];
        *(bshort8*)&Q_l[row * 72 + sc] = a;
        *(bshort8*)&Q_l[row * 72 + sc + 8] = b8;
    }
    f32x4 o[2][4];
#pragma unroll
    for (int i = 0; i < 2; ++i)
#pragma unroll
        for (int df = 0; df < 4; ++df) o[i][df] = (f32x4){0.f, 0.f, 0.f, 0.f};
    float lrow[2][4] = {{0.f, 0.f, 0.f, 0.f}, {0.f, 0.f, 0.f, 0.f}};

    for (int cc = 0; cc < 6; ++cc) {
        const short* ksrc; const short* vsrc;
        int sk0 = 0;
        if (cc < 2) {
            ksrc = &KcBf[(bh * Lc + cc * 64) * DHn];
            vsrc = &VcBf[(bh * Lc + cc * 64) * DHn];
        } else {
            sk0 = q0 - 64 + (cc - 2) * 64;
            if (sk0 < 0 || sk0 >= S_LEN) continue;   // 64-aligned: fully OOB -> skip (block-uniform)
            ksrc = &Kbf[(bh * S_LEN + sk0) * DHn];
            vsrc = &Vbf[(bh * S_LEN + sk0) * DHn];
        }
        __syncthreads();   // prev chunk's LDS reads done (also covers Q staging on first chunk)
        if (t < 64) {
            float v = 0.f;
            if (cc >= 2 && mask[b * S_LEN + sk0 + t] == 0) v = -1e30f;
            vb[t] = v;
        }
        {
            const bshort8 a = *(const bshort8*)&ksrc[sr * 64 + sc];
            const bshort8 b8 = *(const bshort8*)&ksrc[sr * 64 + sc + 8];
            *(bshort8*)&K_l[sr * 72 + sc] = a;
            *(bshort8*)&K_l[sr * 72 + sc + 8] = b8;
        }
        {
            const bshort8 v0 = *(const bshort8*)&vsrc[vj * 64 + vd0];
            const bshort8 v1 = *(const bshort8*)&vsrc[vj * 64 + vd0 + 8];
#pragma unroll
            for (int i = 0; i < 8; ++i) {
                Vt_l[(vd0 + i) * 72 + vj] = v0[i];
                Vt_l[(vd0 + 8 + i) * 72 + vj] = v1[i];
            }
        }
        __syncthreads();
        // QK^T: wave handles q rows [wave*32, wave*32+32) = 2 frags
        f32x4 c[2][4];
#pragma unroll
        for (int i = 0; i < 2; ++i)
#pragma unroll
            for (int jf = 0; jf < 4; ++jf) c[i][jf] = (f32x4){0.f, 0.f, 0.f, 0.f};
#pragma unroll
        for (int ks = 0; ks < 2; ++ks) {
            bshort8 aq[2];
#pragma unroll
            for (int i = 0; i < 2; ++i)
                aq[i] = *(const bshort8*)&Q_l[(wave * 32 + i * 16 + r15) * 72 + ks * 32 + quad * 8];
#pragma unroll
            for (int jf = 0; jf < 4; ++jf) {
                const bshort8 bk = *(const bshort8*)&K_l[(jf * 16 + r15) * 72 + ks * 32 + quad * 8];
                c[0][jf] = __builtin_amdgcn_mfma_f32_16x16x32_bf16(aq[0], bk, c[0][jf], 0, 0, 0);
                c[1][jf] = __builtin_amdgcn_mfma_f32_16x16x32_bf16(aq[1], bk, c[1][jf], 0, 0, 0);
            }
        }
        float vbl[4];
#pragma unroll
        for (int jf = 0; jf < 4; ++jf) vbl[jf] = vb[jf * 16 + r15];
        float sum[2][4] = {{0.f, 0.f, 0.f, 0.f}, {0.f, 0.f, 0.f, 0.f}};
#pragma unroll
        for (int i = 0; i < 2; ++i)
#pragma unroll
            for (int jf = 0; jf < 4; ++jf)
#pragma unroll
                for (int r = 0; r < 4; ++r) {
                    const float p = __expf(c[i][jf][r] + vbl[jf]);
                    sum[i][r] += p;
                    P_l[(wave * 32 + i * 16 + quad * 4 + r) * 72 + jf * 16 + r15] = f2bs(p);
                }
#pragma unroll
        for (int off = 1; off <= 8; off <<= 1)
#pragma unroll
            for (int i = 0; i < 2; ++i)
#pragma unroll
                for (int r = 0; r < 4; ++r) sum[i][r] += __shfl_xor(sum[i][r], off);
#pragma unroll
        for (int i = 0; i < 2; ++i)
#pragma unroll
            for (int r = 0; r < 4; ++r) lrow[i][r] += sum[i][r];
        // PV: A-frags from own wave's P rows (same-wave LDS); Vt synced above
#pragma unroll
        for (int ks = 0; ks < 2; ++ks) {
            bshort8 ap[2];
#pragma unroll
            for (int i = 0; i < 2; ++i)
                ap[i] = *(const bshort8*)&P_l[(wave * 32 + i * 16 + r15) * 72 + ks * 32 + quad * 8];
#pragma unroll
            for (int df = 0; df < 4; ++df) {
                const bshort8 bv = *(const bshort8*)&Vt_l[(df * 16 + r15) * 72 + ks * 32 + quad * 8];
                o[0][df] = __builtin_amdgcn_mfma_f32_16x16x32_bf16(ap[0], bv, o[0][df], 0, 0, 0);
                o[1][df] = __builtin_amdgcn_mfma_f32_16x16x32_bf16(ap[1], bv, o[1][df], 0, 0, 0);
            }
        }
    }
#pragma unroll
    for (int i = 0; i < 2; ++i)
#pragma unroll
        for (int r = 0; r < 4; ++r) {
            const int q = q0 + wave * 32 + i * 16 + quad * 4 + r;
            const float rl = (mask[b * S_LEN + q] == 0) ? 0.f : (1.f / lrow[i][r]);
            const size_t ob = ((size_t)b * S_LEN + q) * 512 + h * 64;
#pragma unroll
            for (int df = 0; df < 4; ++df)
                C[ob + df * 16 + r15] = f2bs(o[i][df][r] * rl);
        }
}

extern "C" void kernel_launch(void* const* d_in, const int* in_sizes, int n_in,
                              void* d_out, int out_size, void* d_ws, size_t ws_size,
                              hipStream_t stream) {
    (void)in_sizes; (void)n_in; (void)out_size; (void)ws_size;
    const float* X    = (const float*)d_in[0];
    const int*   mask = (const int*)d_in[1];
    const float* Wq = (const float*)d_in[2];  const float* bq = (const float*)d_in[3];
    const float* Wk = (const float*)d_in[4];  const float* bk = (const float*)d_in[5];
    const float* Wv = (const float*)d_in[6];  const float* bv = (const float*)d_in[7];
    const float* Wo = (const float*)d_in[8];  const float* bo = (const float*)d_in[9];
    const float* lnlg = (const float*)d_in[10]; const float* lnlb = (const float*)d_in[11];
    const float* lnsg = (const float*)d_in[12]; const float* lnsb = (const float*)d_in[13];
    const float* Wd = (const float*)d_in[14]; const float* bd = (const float*)d_in[15];

    short* sw = (short*)d_ws;
    short* Qbf    = sw;                        // 4,194,304 bf16 (B,H,S,DH), pre-scaled
    short* Kbf    = Qbf + 4194304;             // 4,194,304 bf16 (B,H,S,DH), LN'd
    short* Vbf    = Kbf + 4194304;             // 4,194,304 bf16 (B,H,S,DH), LN'd
    short* KbBf   = Vbf + 4194304;             // 4,194,304 bf16 row-major pre-LN K
    short* VbBf   = KbBf + 4194304;            // 4,194,304 bf16 row-major pre-LN V
    short* DlogBf = VbBf + 4194304;            // 8,388,608 bf16
    short* Xbf    = DlogBf + 8388608;          // 4,194,304 bf16 (reused: partK, then Cbf)
    short* WTall  = Xbf + 4194304;             // 1,310,720 bf16
    short* WoT    = WTall + 1310720;           // 262,144 bf16
    short* KcBf   = WoT + 262144;              // 131,072 bf16 (B,H,L,DH)
    short* VcBf   = KcBf + 131072;             // 131,072 bf16
    short* partV  = VcBf + 131072;             // 4,194,304 bf16
    float* partZ  = (float*)(partV + 4194304); // 65,536 f32 (b,h,l,seg)
    short* partK  = Xbf;                       // reuse (Xbf dead after gemm_proj)
    short* Cbf    = Xbf;                       // reuse (partK dead after kcvc_s2)
    // total ≈ 79.7 MB

    const dim3 blk(256);
    prep_all<<<3584, blk, 0, stream>>>(X, Wq, Wk, Wv, Wd, Wo, Xbf, WTall, WoT);
    gemm_proj<<<dim3(20, 64), blk, 0, stream>>>(Xbf, WTall, bq, bk, bv, bd, Qbf, KbBf, VbBf, DlogBf);
    ln_ip<<<dim3(8192, 2), blk, 0, stream>>>(KbBf, VbBf, lnlg, lnlb, Kbf, Vbf);
    kcvc_mfma<<<dim3(32, 8, 2), blk, 0, stream>>>(DlogBf, Kbf, Vbf, partK, partV, partZ);
    kcvc_s2<<<dim3(128, 2), blk, 0, stream>>>(partK, partV, partZ, lnsg, lnsb, KcBf, VcBf);
    attn_mfma<<<dim3(32, 8, 2), blk, 0, stream>>>(Qbf, Kbf, Vbf, KcBf, VcBf, mask, Cbf);
    gemm_out<<<dim3(8, 128), blk, 0, stream>>>(Cbf, WoT, bo, (float*)d_out);
}

// Round 10
// 210.713 us; speedup vs baseline: 4.2696x; 1.0484x over previous
//
#include <hip/hip_runtime.h>
#include <hip/hip_bf16.h>

#define S_LEN 4096
#define Hn 8
#define DHn 64
#define Lc 128
#define HL 1024
#define KD 512   // inner dim of all GEMMs

typedef __attribute__((ext_vector_type(8))) short bshort8;
typedef __attribute__((ext_vector_type(4))) float f32x4;

__device__ __forceinline__ short f2bs(float f) {
    union { float f; unsigned u; } x; x.f = f;
    const unsigned r = x.u + 0x7FFFu + ((x.u >> 16) & 1u);
    return (short)(r >> 16);
}
__device__ __forceinline__ float bs2f(short s) {
    union { unsigned u; float f; } x; x.u = ((unsigned)(unsigned short)s) << 16;
    return x.f;
}

// async global(bf16 bits as short) -> LDS, 16B per lane (GEMMs only; LDS must be unpadded)
__device__ __forceinline__ void gl16(const short* g, short* l) {
    __builtin_amdgcn_global_load_lds((const __attribute__((address_space(1))) void*)g,
                                     (__attribute__((address_space(3))) void*)l, 16, 0, 0);
}

// ---------------- fused prep: X->bf16 + all weight transposes ----------------
__global__ __launch_bounds__(256) void prep_all(const float* __restrict__ X,
    const float* __restrict__ Wq, const float* __restrict__ Wk, const float* __restrict__ Wv,
    const float* __restrict__ Wd, const float* __restrict__ Wo,
    short* __restrict__ Xbf, short* __restrict__ WTall, short* __restrict__ WoT)
{
    const int t = threadIdx.x;
    int blk = blockIdx.x;
    if (blk < 2048) {
        const int i = (blk * 256 + t) * 8;
        const float4 a = *(const float4*)&X[i];
        const float4 b = *(const float4*)&X[i + 4];
        bshort8 o;
        o[0] = f2bs(a.x); o[1] = f2bs(a.y); o[2] = f2bs(a.z); o[3] = f2bs(a.w);
        o[4] = f2bs(b.x); o[5] = f2bs(b.y); o[6] = f2bs(b.z); o[7] = f2bs(b.w);
        *(bshort8*)&Xbf[i] = o;
        return;
    }
    blk -= 2048;
    const float* W; short* out; int N;
    if (blk < 256)       { W = Wq; out = WTall;              N = 512;  }
    else if (blk < 512)  { W = Wk; out = WTall + 512 * 512;  N = 512;  blk -= 256; }
    else if (blk < 768)  { W = Wv; out = WTall + 1024 * 512; N = 512;  blk -= 512; }
    else if (blk < 1280) { W = Wd; out = WTall + 1536 * 512; N = 1024; blk -= 768; }
    else                 { W = Wo; out = WoT;                N = 512;  blk -= 1280; }
    const int nb = N >> 5;
    const int n0 = (blk % nb) * 32, k0 = (blk / nb) * 32;
    __shared__ float Tl[32][33];
    const int tx = t & 31, ty = t >> 5;
#pragma unroll
    for (int i = ty; i < 32; i += 8)
        Tl[i][tx] = W[(size_t)(k0 + i) * N + n0 + tx];
    __syncthreads();
#pragma unroll
    for (int i = ty; i < 32; i += 8)
        out[(size_t)(n0 + i) * KD + k0 + tx] = f2bs(Tl[tx][i]);
}

// ---------------- fused projection GEMM (MFMA, BK=32, XCD-swizzled) ----------------
// swizzle: id%8 (likely XCD) owns m-tiles [x*8, x*8+8) across all 20 n-tiles,
// so each XCD's X working set is 1 MB (fits 4 MB L2) instead of all 8.4 MB.
__global__ __launch_bounds__(256) void gemm_proj(const short* __restrict__ Xbf,
    const short* __restrict__ WT,
    const float* __restrict__ bq, const float* __restrict__ bk,
    const float* __restrict__ bv, const float* __restrict__ bd,
    short* __restrict__ Qbf, short* __restrict__ KbBf, short* __restrict__ VbBf,
    short* __restrict__ DlogBf)
{
    __shared__ __align__(16) short A_s[128 * 32];
    __shared__ __align__(16) short B_s[128 * 32];
    const int t = threadIdx.x;
    const int id = blockIdx.x;
    const int x8 = id & 7, j8 = id >> 3;          // 1280 blocks total
    const int m0 = (x8 * 8 + (j8 & 7)) * 128;     // m-tile 0..63
    const int n0 = (j8 >> 3) * 128;               // n-tile 0..19
    const int lane = t & 63, wave = t >> 6;
    const int wm = wave >> 1, wn = wave & 1;
    const int quad = lane >> 4, r15 = lane & 15;
    const int eOff = t * 8;
    const int am = eOff >> 5, ak = eOff & 31;
    f32x4 acc[4][4];
#pragma unroll
    for (int i = 0; i < 4; ++i)
#pragma unroll
        for (int j = 0; j < 4; ++j) acc[i][j] = (f32x4){0.f, 0.f, 0.f, 0.f};

    for (int kk = 0; kk < KD; kk += 32) {
        gl16(&Xbf[(size_t)(m0 + am) * KD + kk + ak],      &A_s[eOff]);
        gl16(&Xbf[(size_t)(m0 + 64 + am) * KD + kk + ak], &A_s[2048 + eOff]);
        gl16(&WT[(size_t)(n0 + am) * KD + kk + ak],       &B_s[eOff]);
        gl16(&WT[(size_t)(n0 + 64 + am) * KD + kk + ak],  &B_s[2048 + eOff]);
        __syncthreads();
        bshort8 af[4], bfr[4];
#pragma unroll
        for (int i = 0; i < 4; ++i) af[i]  = *(const bshort8*)&A_s[(wm * 64 + i * 16 + r15) * 32 + quad * 8];
#pragma unroll
        for (int j = 0; j < 4; ++j) bfr[j] = *(const bshort8*)&B_s[(wn * 64 + j * 16 + r15) * 32 + quad * 8];
#pragma unroll
        for (int i = 0; i < 4; ++i)
#pragma unroll
            for (int j = 0; j < 4; ++j)
                acc[i][j] = __builtin_amdgcn_mfma_f32_16x16x32_bf16(af[i], bfr[j], acc[i][j], 0, 0, 0);
        __syncthreads();
    }
    const int seg = (n0 >= 1536) ? 3 : (n0 >> 9);   // block-uniform
#pragma unroll
    for (int i = 0; i < 4; ++i)
#pragma unroll
        for (int j = 0; j < 4; ++j)
#pragma unroll
            for (int r = 0; r < 4; ++r) {
                const int gm = m0 + wm * 64 + i * 16 + quad * 4 + r;
                const int gn = n0 + wn * 64 + j * 16 + r15;
                float v = acc[i][j][r];
                if (seg == 0) {
                    v = (v + bq[gn]) * 0.125f;
                    const int bb = gm >> 12, s = gm & 4095, hh = gn >> 6, d = gn & 63;
                    Qbf[((size_t)(bb * Hn + hh) * S_LEN + s) * DHn + d] = f2bs(v);
                } else if (seg == 1) {
                    KbBf[(size_t)gm * 512 + (gn - 512)] = f2bs(v + bk[gn - 512]);
                } else if (seg == 2) {
                    VbBf[(size_t)gm * 512 + (gn - 1024)] = f2bs(v + bv[gn - 1024]);
                } else {
                    DlogBf[(size_t)gm * 1024 + (gn - 1536)] = f2bs(v + bd[gn - 1536]);
                }
            }
}

// ---------------- output GEMM (MFMA): 64m x 128n tiles, 512 blocks, swizzled ----------------
__global__ __launch_bounds__(256) void gemm_out(const short* __restrict__ Abf,
    const short* __restrict__ WT, const float* __restrict__ bias, float* __restrict__ outp)
{
    __shared__ __align__(16) short A_s[64 * 32];    // 4 KB
    __shared__ __align__(16) short B_s[128 * 32];   // 8 KB
    const int t = threadIdx.x;
    const int id = blockIdx.x;
    const int x8 = id & 7, j8 = id >> 3;            // 512 blocks
    const int m0 = (x8 * 16 + (j8 & 15)) * 64;      // m-tile 0..127
    const int n0 = (j8 >> 4) * 128;                 // n-tile 0..3
    const int lane = t & 63, wave = t >> 6;
    const int quad = lane >> 4, r15 = lane & 15;
    const int eOff = t * 8;
    const int am = eOff >> 5, ak = eOff & 31;
    f32x4 acc[8];
#pragma unroll
    for (int j = 0; j < 8; ++j) acc[j] = (f32x4){0.f, 0.f, 0.f, 0.f};

    for (int kk = 0; kk < KD; kk += 32) {
        gl16(&Abf[(size_t)(m0 + am) * KD + kk + ak],      &A_s[eOff]);
        gl16(&WT[(size_t)(n0 + am) * KD + kk + ak],       &B_s[eOff]);
        gl16(&WT[(size_t)(n0 + 64 + am) * KD + kk + ak],  &B_s[2048 + eOff]);
        __syncthreads();
        const bshort8 af = *(const bshort8*)&A_s[(wave * 16 + r15) * 32 + quad * 8];
#pragma unroll
        for (int j = 0; j < 8; ++j) {
            const bshort8 bfr = *(const bshort8*)&B_s[(j * 16 + r15) * 32 + quad * 8];
            acc[j] = __builtin_amdgcn_mfma_f32_16x16x32_bf16(af, bfr, acc[j], 0, 0, 0);
        }
        __syncthreads();
    }
#pragma unroll
    for (int j = 0; j < 8; ++j)
#pragma unroll
        for (int r = 0; r < 4; ++r) {
            const int gm = m0 + wave * 16 + quad * 4 + r;
            const int gn = n0 + j * 16 + r15;
            outp[(size_t)gm * 512 + gn] = acc[j][r] + bias[gn];
        }
}

// ---------------- row LayerNorm over 512 (bf16 in, bf16 (B,H,S,DH) out) ----------------
__global__ __launch_bounds__(256) void ln_ip(const short* __restrict__ KbBf, const short* __restrict__ VbBf,
    const float* __restrict__ g, const float* __restrict__ beta,
    short* __restrict__ Kbf, short* __restrict__ Vbf)
{
    const short* src = blockIdx.y ? VbBf : KbBf;
    short* dst = blockIdx.y ? Vbf : Kbf;
    const int row = blockIdx.x, t = threadIdx.x;
    const size_t base = (size_t)row * 512;
    const float x0 = bs2f(src[base + t]);
    const float x1 = bs2f(src[base + t + 256]);
    float s = x0 + x1, ss = x0 * x0 + x1 * x1;
#pragma unroll
    for (int off = 32; off >= 1; off >>= 1) { s += __shfl_xor(s, off); ss += __shfl_xor(ss, off); }
    __shared__ float red[2][4];
    if ((t & 63) == 0) { red[0][t >> 6] = s; red[1][t >> 6] = ss; }
    __syncthreads();
    s = red[0][0] + red[0][1] + red[0][2] + red[0][3];
    ss = red[1][0] + red[1][1] + red[1][2] + red[1][3];
    const float mu = s * (1.f / 512.f);
    const float r = rsqrtf(ss * (1.f / 512.f) - mu * mu + 1e-5f);
    const int bb = row >> 12, sidx = row & 4095;
#pragma unroll
    for (int half = 0; half < 2; ++half) {
        const int c = t + half * 256;
        const float x = half ? x1 : x0;
        const float v = (x - mu) * r * g[c] + beta[c];
        dst[((size_t)(bb * Hn + (c >> 6)) * S_LEN + sidx) * DHn + (c & 63)] = f2bs(v);
    }
}

// ---------------- Kc/Vc stage 1 (MFMA): unnormalized exp partials + partZ ----------------
__global__ __launch_bounds__(256) void kcvc_mfma(const short* __restrict__ Dlog,
    const short* __restrict__ Kbf, const short* __restrict__ Vbf,
    short* __restrict__ partK, short* __restrict__ partV, float* __restrict__ partZ)
{
    __shared__ __align__(16) short aa[128 * 72];   // [l][s], 72-pad
    __shared__ __align__(16) short Kt[64 * 72];    // [d][s]
    __shared__ __align__(16) short Vt[64 * 72];
    __shared__ float zsh[256];
    const int t = threadIdx.x;
    const int seg = blockIdx.x, h = blockIdx.y, b = blockIdx.z;
    const int s0 = seg * 128;
    const size_t bh = (size_t)(b * Hn + h);
    const int lane = t & 63, wave = t >> 6;
    const int quad = lane >> 4, r15 = lane & 15;
    const int al = t & 127, ah = t >> 7;
    const int vj = t & 63, vd0 = (t >> 6) * 16;   // lane=j transpose: conflict-free writes
    float zacc = 0.f;
    f32x4 aK[2][4], aV[2][4];
#pragma unroll
    for (int i = 0; i < 2; ++i)
#pragma unroll
        for (int j = 0; j < 4; ++j) { aK[i][j] = (f32x4){0.f,0.f,0.f,0.f}; aV[i][j] = (f32x4){0.f,0.f,0.f,0.f}; }

    for (int c = 0; c < 2; ++c) {
        const int sc0 = s0 + c * 64;
        if (c) __syncthreads();
#pragma unroll
        for (int gch = 0; gch < 4; ++gch) {
            bshort8 o;
#pragma unroll
            for (int j = 0; j < 8; ++j) {
                const int s = sc0 + ah * 32 + gch * 8 + j;
                const float e = __expf(bs2f(Dlog[((size_t)b * S_LEN + s) * HL + h * Lc + al]));
                zacc += e;
                o[j] = f2bs(e);
            }
            *(bshort8*)&aa[al * 72 + ah * 32 + gch * 8] = o;
        }
        {
            const size_t rb = (bh * S_LEN + sc0 + vj) * DHn + vd0;
            const bshort8 k0 = *(const bshort8*)&Kbf[rb];
            const bshort8 k1 = *(const bshort8*)&Kbf[rb + 8];
            const bshort8 v0 = *(const bshort8*)&Vbf[rb];
            const bshort8 v1 = *(const bshort8*)&Vbf[rb + 8];
#pragma unroll
            for (int i = 0; i < 8; ++i) {
                Kt[(vd0 + i) * 72 + vj] = k0[i]; Kt[(vd0 + 8 + i) * 72 + vj] = k1[i];
                Vt[(vd0 + i) * 72 + vj] = v0[i]; Vt[(vd0 + 8 + i) * 72 + vj] = v1[i];
            }
        }
        __syncthreads();
#pragma unroll
        for (int ks = 0; ks < 2; ++ks) {
            const bshort8 a0 = *(const bshort8*)&aa[(wave * 32 + r15) * 72 + ks * 32 + quad * 8];
            const bshort8 a1 = *(const bshort8*)&aa[(wave * 32 + 16 + r15) * 72 + ks * 32 + quad * 8];
#pragma unroll
            for (int j = 0; j < 4; ++j) {
                const bshort8 bk = *(const bshort8*)&Kt[(j * 16 + r15) * 72 + ks * 32 + quad * 8];
                const bshort8 bv = *(const bshort8*)&Vt[(j * 16 + r15) * 72 + ks * 32 + quad * 8];
                aK[0][j] = __builtin_amdgcn_mfma_f32_16x16x32_bf16(a0, bk, aK[0][j], 0, 0, 0);
                aK[1][j] = __builtin_amdgcn_mfma_f32_16x16x32_bf16(a1, bk, aK[1][j], 0, 0, 0);
                aV[0][j] = __builtin_amdgcn_mfma_f32_16x16x32_bf16(a0, bv, aV[0][j], 0, 0, 0);
                aV[1][j] = __builtin_amdgcn_mfma_f32_16x16x32_bf16(a1, bv, aV[1][j], 0, 0, 0);
            }
        }
    }
    zsh[t] = zacc;
    __syncthreads();
    if (t < 128)
        partZ[((size_t)(bh * Lc + t)) * 32 + seg] = zsh[t] + zsh[t + 128];
#pragma unroll
    for (int i = 0; i < 2; ++i)
#pragma unroll
        for (int j = 0; j < 4; ++j)
#pragma unroll
            for (int r = 0; r < 4; ++r) {
                const int l = wave * 32 + i * 16 + quad * 4 + r;
                const int d = j * 16 + r15;
                const size_t o = (((size_t)(b * Lc + l)) * 32 + seg) * 512 + h * 64 + d;
                partK[o] = f2bs(aK[i][j][r]);
                partV[o] = f2bs(aV[i][j][r]);
            }
}

// ---------------- Kc/Vc stage 2: K and V handled by separate blocks (2x parallelism) ------
__global__ __launch_bounds__(256) void kcvc_s2(const short* __restrict__ partK,
    const short* __restrict__ partV, const float* __restrict__ partZ,
    const float* __restrict__ g, const float* __restrict__ beta,
    short* __restrict__ KcBf, short* __restrict__ VcBf)
{
    const int l = blockIdx.x, b = blockIdx.y, t = threadIdx.x;
    const short* part = blockIdx.z ? partV : partK;
    short* dst = blockIdx.z ? VcBf : KcBf;
    __shared__ float zh[8];
    if (t < 8) {
        float z = 0.f;
        const size_t zb = ((size_t)((b * Hn + t) * Lc + l)) * 32;
#pragma unroll
        for (int seg = 0; seg < 32; ++seg) z += partZ[zb + seg];
        zh[t] = 1.f / z;
    }
    const size_t base = ((size_t)(b * Lc + l)) * 32 * 512;
    float k0 = 0.f, k1 = 0.f;
    for (int ch = 0; ch < 32; ++ch) {
        const size_t o = base + (size_t)ch * 512;
        k0 += bs2f(part[o + t]);
        k1 += bs2f(part[o + t + 256]);
    }
    __syncthreads();
    const float z0 = zh[t >> 6], z1 = zh[(t + 256) >> 6];
    k0 *= z0; k1 *= z1;
    float sk = k0 + k1, ssk = k0 * k0 + k1 * k1;
#pragma unroll
    for (int off = 32; off >= 1; off >>= 1) {
        sk += __shfl_xor(sk, off); ssk += __shfl_xor(ssk, off);
    }
    __shared__ float red[2][4];
    if ((t & 63) == 0) { red[0][t >> 6] = sk; red[1][t >> 6] = ssk; }
    __syncthreads();
    sk = red[0][0] + red[0][1] + red[0][2] + red[0][3];
    ssk = red[1][0] + red[1][1] + red[1][2] + red[1][3];
    const float mu = sk * (1.f / 512.f);
    const float r = rsqrtf(ssk * (1.f / 512.f) - mu * mu + 1e-5f);
#pragma unroll
    for (int half = 0; half < 2; ++half) {
        const int c = t + half * 256;
        const float xk = half ? k1 : k0;
        const size_t o = ((size_t)(b * Hn + (c >> 6)) * Lc + l) * DHn + (c & 63);
        dst[o] = f2bs((xk - mu) * r * g[c] + beta[c]);
    }
}

// ---------------- MFMA flash attention: 128 q-rows per block (qt == window group) ----------------
__global__ __launch_bounds__(256) void attn_mfma(
    const short* __restrict__ Qbf, const short* __restrict__ Kbf, const short* __restrict__ Vbf,
    const short* __restrict__ KcBf, const short* __restrict__ VcBf,
    const int* __restrict__ mask, short* __restrict__ C)
{
    __shared__ __align__(16) short Q_l[128 * 72];   // [q][d]
    __shared__ __align__(16) short K_l[64 * 72];    // [j][d]
    __shared__ __align__(16) short Vt_l[64 * 72];   // [d][j]
    __shared__ __align__(16) short P_l[128 * 72];   // [q][j]
    __shared__ float vb[64];
    const int t = threadIdx.x;
    const int qt = blockIdx.x, h = blockIdx.y, b = blockIdx.z;
    const int q0 = qt * 128;
    const size_t bh = (size_t)(b * Hn + h);
    const int lane = t & 63, wave = t >> 6;
    const int quad = lane >> 4, r15 = lane & 15;
    const int sr = t >> 2, sc = (t & 3) * 16;      // 64-row padded staging
    const int vj = t & 63, vd0 = (t >> 6) * 16;    // lane=j V transpose

#pragma unroll
    for (int r = 0; r < 2; ++r) {
        const int row = r * 64 + sr;
        const size_t gq = (bh * S_LEN + q0 + row) * DHn + sc;
        const bshort8 a = *(const bshort8*)&Qbf[gq];
        const bshort8 b8 = *(const bshort8*)&Qbf[gq + 8];
        *(bshort8*)&Q_l[row * 72 + sc] = a;
        *(bshort8*)&Q_l[row * 72 + sc + 8] = b8;
    }
    f32x4 o[2][4];
#pragma unroll
    for (int i = 0; i < 2; ++i)
#pragma unroll
        for (int df = 0; df < 4; ++df) o[i][df] = (f32x4){0.f, 0.f, 0.f, 0.f};
    float lrow[2][4] = {{0.f, 0.f, 0.f, 0.f}, {0.f, 0.f, 0.f, 0.f}};

    for (int cc = 0; cc < 6; ++cc) {
        const short* ksrc; const short* vsrc;
        int sk0 = 0;
        if (cc < 2) {
            ksrc = &KcBf[(bh * Lc + cc * 64) * DHn];
            vsrc = &VcBf[(bh * Lc + cc * 64) * DHn];
        } else {
            sk0 = q0 - 64 + (cc - 2) * 64;
            if (sk0 < 0 || sk0 >= S_LEN) continue;   // 64-aligned: fully OOB -> skip (block-uniform)
            ksrc = &Kbf[(bh * S_LEN + sk0) * DHn];
            vsrc = &Vbf[(bh * S_LEN + sk0) * DHn];
        }
        __syncthreads();   // prev chunk's LDS reads done (also covers Q staging on first chunk)
        if (t < 64) {
            float v = 0.f;
            if (cc >= 2 && mask[b * S_LEN + sk0 + t] == 0) v = -1e30f;
            vb[t] = v;
        }
        {
            const bshort8 a = *(const bshort8*)&ksrc[sr * 64 + sc];
            const bshort8 b8 = *(const bshort8*)&ksrc[sr * 64 + sc + 8];
            *(bshort8*)&K_l[sr * 72 + sc] = a;
            *(bshort8*)&K_l[sr * 72 + sc + 8] = b8;
        }
        {
            const bshort8 v0 = *(const bshort8*)&vsrc[vj * 64 + vd0];
            const bshort8 v1 = *(const bshort8*)&vsrc[vj * 64 + vd0 + 8];
#pragma unroll
            for (int i = 0; i < 8; ++i) {
                Vt_l[(vd0 + i) * 72 + vj] = v0[i];
                Vt_l[(vd0 + 8 + i) * 72 + vj] = v1[i];
            }
        }
        __syncthreads();
        // QK^T: wave handles q rows [wave*32, wave*32+32) = 2 frags
        f32x4 c[2][4];
#pragma unroll
        for (int i = 0; i < 2; ++i)
#pragma unroll
            for (int jf = 0; jf < 4; ++jf) c[i][jf] = (f32x4){0.f, 0.f, 0.f, 0.f};
#pragma unroll
        for (int ks = 0; ks < 2; ++ks) {
            bshort8 aq[2];
#pragma unroll
            for (int i = 0; i < 2; ++i)
                aq[i] = *(const bshort8*)&Q_l[(wave * 32 + i * 16 + r15) * 72 + ks * 32 + quad * 8];
#pragma unroll
            for (int jf = 0; jf < 4; ++jf) {
                const bshort8 bk = *(const bshort8*)&K_l[(jf * 16 + r15) * 72 + ks * 32 + quad * 8];
                c[0][jf] = __builtin_amdgcn_mfma_f32_16x16x32_bf16(aq[0], bk, c[0][jf], 0, 0, 0);
                c[1][jf] = __builtin_amdgcn_mfma_f32_16x16x32_bf16(aq[1], bk, c[1][jf], 0, 0, 0);
            }
        }
        float vbl[4];
#pragma unroll
        for (int jf = 0; jf < 4; ++jf) vbl[jf] = vb[jf * 16 + r15];
        float sum[2][4] = {{0.f, 0.f, 0.f, 0.f}, {0.f, 0.f, 0.f, 0.f}};
#pragma unroll
        for (int i = 0; i < 2; ++i)
#pragma unroll
            for (int jf = 0; jf < 4; ++jf)
#pragma unroll
                for (int r = 0; r < 4; ++r) {
                    const float p = __expf(c[i][jf][r] + vbl[jf]);
                    sum[i][r] += p;
                    P_l[(wave * 32 + i * 16 + quad * 4 + r) * 72 + jf * 16 + r15] = f2bs(p);
                }
#pragma unroll
        for (int off = 1; off <= 8; off <<= 1)
#pragma unroll
            for (int i = 0; i < 2; ++i)
#pragma unroll
                for (int r = 0; r < 4; ++r) sum[i][r] += __shfl_xor(sum[i][r], off);
#pragma unroll
        for (int i = 0; i < 2; ++i)
#pragma unroll
            for (int r = 0; r < 4; ++r) lrow[i][r] += sum[i][r];
        // PV: A-frags from own wave's P rows (same-wave LDS); Vt synced above
#pragma unroll
        for (int ks = 0; ks < 2; ++ks) {
            bshort8 ap[2];
#pragma unroll
            for (int i = 0; i < 2; ++i)
                ap[i] = *(const bshort8*)&P_l[(wave * 32 + i * 16 + r15) * 72 + ks * 32 + quad * 8];
#pragma unroll
            for (int df = 0; df < 4; ++df) {
                const bshort8 bv = *(const bshort8*)&Vt_l[(df * 16 + r15) * 72 + ks * 32 + quad * 8];
                o[0][df] = __builtin_amdgcn_mfma_f32_16x16x32_bf16(ap[0], bv, o[0][df], 0, 0, 0);
                o[1][df] = __builtin_amdgcn_mfma_f32_16x16x32_bf16(ap[1], bv, o[1][df], 0, 0, 0);
            }
        }
    }
#pragma unroll
    for (int i = 0; i < 2; ++i)
#pragma unroll
        for (int r = 0; r < 4; ++r) {
            const int q = q0 + wave * 32 + i * 16 + quad * 4 + r;
            const float rl = (mask[b * S_LEN + q] == 0) ? 0.f : (1.f / lrow[i][r]);
            const size_t ob = ((size_t)b * S_LEN + q) * 512 + h * 64;
#pragma unroll
            for (int df = 0; df < 4; ++df)
                C[ob + df * 16 + r15] = f2bs(o[i][df][r] * rl);
        }
}

extern "C" void kernel_launch(void* const* d_in, const int* in_sizes, int n_in,
                              void* d_out, int out_size, void* d_ws, size_t ws_size,
                              hipStream_t stream) {
    (void)in_sizes; (void)n_in; (void)out_size; (void)ws_size;
    const float* X    = (const float*)d_in[0];
    const int*   mask = (const int*)d_in[1];
    const float* Wq = (const float*)d_in[2];  const float* bq = (const float*)d_in[3];
    const float* Wk = (const float*)d_in[4];  const float* bk = (const float*)d_in[5];
    const float* Wv = (const float*)d_in[6];  const float* bv = (const float*)d_in[7];
    const float* Wo = (const float*)d_in[8];  const float* bo = (const float*)d_in[9];
    const float* lnlg = (const float*)d_in[10]; const float* lnlb = (const float*)d_in[11];
    const float* lnsg = (const float*)d_in[12]; const float* lnsb = (const float*)d_in[13];
    const float* Wd = (const float*)d_in[14]; const float* bd = (const float*)d_in[15];

    short* sw = (short*)d_ws;
    short* Qbf    = sw;                        // 4,194,304 bf16 (B,H,S,DH), pre-scaled
    short* Kbf    = Qbf + 4194304;             // 4,194,304 bf16 (B,H,S,DH), LN'd
    short* Vbf    = Kbf + 4194304;             // 4,194,304 bf16 (B,H,S,DH), LN'd
    short* KbBf   = Vbf + 4194304;             // 4,194,304 bf16 row-major pre-LN K
    short* VbBf   = KbBf + 4194304;            // 4,194,304 bf16 row-major pre-LN V
    short* DlogBf = VbBf + 4194304;            // 8,388,608 bf16
    short* Xbf    = DlogBf + 8388608;          // 4,194,304 bf16 (reused: partK, then Cbf)
    short* WTall  = Xbf + 4194304;             // 1,310,720 bf16
    short* WoT    = WTall + 1310720;           // 262,144 bf16
    short* KcBf   = WoT + 262144;              // 131,072 bf16 (B,H,L,DH)
    short* VcBf   = KcBf + 131072;             // 131,072 bf16
    short* partV  = VcBf + 131072;             // 4,194,304 bf16
    float* partZ  = (float*)(partV + 4194304); // 65,536 f32 (b,h,l,seg)
    short* partK  = Xbf;                       // reuse (Xbf dead after gemm_proj)
    short* Cbf    = Xbf;                       // reuse (partK dead after kcvc_s2)
    // total ≈ 79.7 MB

    const dim3 blk(256);
    prep_all<<<3584, blk, 0, stream>>>(X, Wq, Wk, Wv, Wd, Wo, Xbf, WTall, WoT);
    gemm_proj<<<1280, blk, 0, stream>>>(Xbf, WTall, bq, bk, bv, bd, Qbf, KbBf, VbBf, DlogBf);
    ln_ip<<<dim3(8192, 2), blk, 0, stream>>>(KbBf, VbBf, lnlg, lnlb, Kbf, Vbf);
    kcvc_mfma<<<dim3(32, 8, 2), blk, 0, stream>>>(DlogBf, Kbf, Vbf, partK, partV, partZ);
    kcvc_s2<<<dim3(128, 2, 2), blk, 0, stream>>>(partK, partV, partZ, lnsg, lnsb, KcBf, VcBf);
    attn_mfma<<<dim3(32, 8, 2), blk, 0, stream>>>(Qbf, Kbf, Vbf, KcBf, VcBf, mask, Cbf);
    gemm_out<<<512, blk, 0, stream>>>(Cbf, WoT, bo, (float*)d_out);
}